// Round 5
// baseline (673.209 us; speedup 1.0000x reference)
//
#include <hip/hip_runtime.h>
#include <hip/hip_bf16.h>

#define B_ 8
#define N_ 1024
#define K_ 20
#define BN_ (B_*N_)

#define BN_SCALE 0.9999950000374997f

typedef __attribute__((ext_vector_type(8))) short short8;
typedef __attribute__((ext_vector_type(4))) float f32x4;

__device__ __forceinline__ float US2F(unsigned short u) {
    union { unsigned u; float f; } c; c.u = ((unsigned)u) << 16; return c.f;
}
__device__ __forceinline__ unsigned short F2BF(float f) {   // RNE fp32->bf16
    union { float f; unsigned u; } c; c.f = f;
    unsigned r = c.u + 0x7FFF + ((c.u >> 16) & 1);
    return (unsigned short)(r >> 16);
}

// async global->LDS 16B DMA: LDS dest = wave-uniform base + lane*16 (linear);
// global source is per-lane (pre-swizzled there when a swizzled layout is wanted).
__device__ __forceinline__ void ldsld16(const unsigned short* g, unsigned short* l) {
    __builtin_amdgcn_global_load_lds(
        (const __attribute__((address_space(1))) void*)g,
        (__attribute__((address_space(3))) void*)l, 16, 0, 0);
}

// ---------------------------------------------------------------- dtype detect
__global__ void k_detect(const unsigned short* g1, const unsigned short* g2,
                         const unsigned short* g3, const unsigned short* g4,
                         const unsigned short* g5, const unsigned short* g6,
                         const unsigned short* g7, int* flag) {
    const unsigned short* gs[7] = {g1, g2, g3, g4, g5, g6, g7};
    int cnt = 0;
    for (int i = 0; i < 7; i++) {
        float v = US2F(gs[i][0]);
        if (v > 0.5f && v < 1.5f) cnt++;
    }
    *flag = (cnt >= 4) ? 1 : 0;   // 1 = bf16 inputs, 0 = fp32 inputs
}

// ---------------------------------------------------------------- prep
// mode 0: fp32 copy (I==1 -> contiguous).  mode 2: bf16 copy.
// mode 3: edge pair -> bf16 (2O, C).  mode 4: zero-fill fp32 (dst only).
struct TPar { const void* src; void* dst; int O, I, blk0, mode; };
struct TList { TPar p[44]; };

__global__ __launch_bounds__(256) void k_prep(TList tl, int nent, const int* flag) {
    const int isbf = *flag;
    int blk = blockIdx.x;
    int wi = 0;
    for (int j = nent - 1; j >= 0; j--) { if (blk >= tl.p[j].blk0) { wi = j; break; } }
    const TPar p = tl.p[wi];
    int e = (blk - p.blk0) * 256 + threadIdx.x;
    int n = p.O * p.I;
    if (e >= n) return;
    if (p.mode == 4) { ((float*)p.dst)[e] = 0.f; return; }
    int o = e / p.I, i = e - o * p.I;
    float v = isbf ? US2F(((const unsigned short*)p.src)[e])
                   : ((const float*)p.src)[e];
    if (p.mode == 0) {
        ((float*)p.dst)[(size_t)i * p.O + o] = v;
    } else if (p.mode == 2) {
        ((unsigned short*)p.dst)[e] = F2BF(v);
    } else {
        const int C = p.I >> 1;
        if (i < C) ((unsigned short*)p.dst)[(size_t)o * C + i] = F2BF(v);
        else       ((unsigned short*)p.dst)[(size_t)(p.O + o) * C + (i - C)] = F2BF(v);
    }
}

// ---------------------------------------------------------------- LDS-tiled transpose
// (O,I) row-major -> (I,O).  32x32 tiles, coalesced read AND write.
struct TrP { const void* src; float* dst; int O, I, bx, blk0; };

__global__ __launch_bounds__(256) void k_tr(TrP p0, TrP p1, TrP p2, const int* flag) {
    const int isbf = *flag;
    TrP p = p0;
    int blk = blockIdx.x;
    if (blk >= p2.blk0) p = p2; else if (blk >= p1.blk0) p = p1;
    blk -= p.blk0;
    const int tx = threadIdx.x & 31, ty = threadIdx.x >> 5;   // 32 x 8
    const int bi = blk % p.bx, bo = blk / p.bx;
    const int i0 = bi * 32, o0 = bo * 32;
    __shared__ float s[32][33];
    #pragma unroll
    for (int r = 0; r < 4; r++) {
        const int o = o0 + ty + r * 8, i = i0 + tx;
        if (o < p.O && i < p.I) {
            const size_t e = (size_t)o * p.I + i;
            s[ty + r * 8][tx] = isbf ? US2F(((const unsigned short*)p.src)[e])
                                     : ((const float*)p.src)[e];
        }
    }
    __syncthreads();
    #pragma unroll
    for (int r = 0; r < 4; r++) {
        const int i = i0 + ty + r * 8, o = o0 + tx;
        if (i < p.I && o < p.O) p.dst[(size_t)i * p.O + o] = s[tx][ty + r * 8];
    }
}

// ---------------------------------------------------------------- kNN split + norms (fused)
// split blocks: x (fp32) -> augmented bf16 rows (exact-split): xa=[hi,lo,hi,lo],
// xb=[hi,hi,lo,lo], zero-padded to KP.  Trailing 32 blocks: xx[i] = |x_i|^2.
template<int C, int KP>
__global__ __launch_bounds__(256) void k_split(const float* __restrict__ x,
                                               unsigned short* __restrict__ xa,
                                               unsigned short* __restrict__ xb,
                                               float* __restrict__ xx) {
    constexpr int NB = (BN_ * KP) / 256;
    if (blockIdx.x >= NB) {   // norms
        const int i = (blockIdx.x - NB) * 256 + threadIdx.x;
        if (i >= BN_) return;
        const float* p = x + (size_t)i * C;
        float s = 0.f;
        #pragma unroll
        for (int c = 0; c < C; c++) s += p[c] * p[c];
        xx[i] = s;
        return;
    }
    const int e = blockIdx.x * 256 + threadIdx.x;
    const int i = e / KP, p = e - i * KP;
    unsigned short va = 0, vb = 0;
    if (p < 4 * C) {
        const int seg = p / C, c = p - seg * C;
        const float v = x[(size_t)i * C + c];
        const unsigned short h = F2BF(v);
        const unsigned short l = F2BF(v - US2F(h));
        va = (seg & 1) ? l : h;           // hi,lo,hi,lo
        vb = (seg < 2) ? h : l;           // hi,hi,lo,lo
    }
    xa[e] = va;
    xb[e] = vb;
}

// ---------------------------------------------------------------- fused kNN (MFMA + top-20):
// One block = 32 rows x ALL 1024 cols of one batch; scores never leave the CU.
// Per col-tile (256 cols): MFMA over KP (same k-order as the old k_pdm ->
// bit-identical scores), then keys (22-bit value | 10-bit 1023-j, identical to
// old k_sel) written to LDS (stride 1033: write groups land on distinct banks).
// Selection = old k_sel extraction loop verbatim, 4 rows/wave, keys from LDS.
// Grid (32,1,8) = 256 blocks = 1 block/CU (LDS 147 KB), 8 waves.
template<int KP>
__global__ __launch_bounds__(512) void k_knn(const unsigned short* __restrict__ xa,
                                             const unsigned short* __restrict__ xb,
                                             const float* __restrict__ xx,
                                             int* __restrict__ idx) {
    constexpr int TM = 32, TC = 256;
    const int b = blockIdx.z;
    const int rb = blockIdx.x * TM;
    const unsigned short* Ab = xa + (size_t)b * N_ * KP;
    const unsigned short* Bb = xb + (size_t)b * N_ * KP;
    const float* xxb = xx + (size_t)b * N_;
    const int t = threadIdx.x;
    const int w = t >> 6, lane = t & 63;
    __shared__ __align__(16) unsigned short As[TM * 32];
    __shared__ __align__(16) unsigned short Bs[TC * 32];
    __shared__ unsigned sc[TM * 1033];
    const int wr = (w & 1) * 16, wc = (w >> 1) * 64;   // 2x4 wave layout
    const int fr = lane & 15, q = lane >> 4;
    const int cr = (lane >> 4) * 4, cc = lane & 15;

    for (int ct = 0; ct < N_ / TC; ct++) {
        const int cb = ct * TC;
        f32x4 acc[4] = {};
        for (int k0 = 0; k0 < KP; k0 += 32) {
            // stage A: 32 rows x 32 k = 128 x 16B (waves 0,1; wave-uniform branch)
            if (w < 2) {
                const int m = t >> 2, gs = (t & 3) ^ ((m >> 1) & 3);
                ldsld16(&Ab[(size_t)(rb + m) * KP + k0 + gs * 8], &As[w * 512]);
            }
            // stage B: 256 rows x 32 k = 1024 x 16B (all 8 waves, 2 rounds)
            #pragma unroll
            for (int R = 0; R < 2; R++) {
                const int G = t + R * 512;
                const int n = G >> 2, gs = (G & 3) ^ ((n >> 1) & 3);
                ldsld16(&Bb[(size_t)(cb + n) * KP + k0 + gs * 8], &Bs[w * 512 + R * 4096]);
            }
            __syncthreads();   // drains vmcnt -> staging visible
            short8 af;
            {
                const int r = wr + fr;
                af = *reinterpret_cast<const short8*>(&As[r * 32 + ((q ^ ((r >> 1) & 3)) << 3)]);
            }
            short8 bfr[4];
            #pragma unroll
            for (int ni = 0; ni < 4; ni++) {
                const int r = wc + ni * 16 + fr;
                bfr[ni] = *reinterpret_cast<const short8*>(&Bs[r * 32 + ((q ^ ((r >> 1) & 3)) << 3)]);
            }
            #pragma unroll
            for (int ni = 0; ni < 4; ni++)
                acc[ni] = __builtin_amdgcn_mfma_f32_16x16x32_bf16(af, bfr[ni], acc[ni], 0, 0, 0);
            __syncthreads();   // reads done before next-stage overwrite
        }
        // keys -> LDS (pd = 2*dot - xx[col]; same truncation as old k_sel)
        #pragma unroll
        for (int ni = 0; ni < 4; ni++) {
            const int col = cb + wc + ni * 16 + cc;
            const float xv = xxb[col];
            #pragma unroll
            for (int r = 0; r < 4; r++) {
                const int row = wr + cr + r;
                float v = 2.f * acc[ni][r] - xv;
                unsigned bits = __float_as_uint(v);
                bits = (bits & 0x80000000u) ? ~bits : (bits | 0x80000000u);
                sc[row * 1033 + col] = (bits & 0xFFFFFC00u) | (unsigned)(N_ - 1 - col);
            }
        }
    }
    __syncthreads();
    // selection: wave w -> rows w*4 .. w*4+3 (old k_sel loop, keys from LDS)
    for (int rr = 0; rr < 4; rr++) {
        const int row = w * 4 + rr;
        unsigned key[16];
        #pragma unroll
        for (int qq = 0; qq < 16; qq++)
            key[qq] = sc[row * 1033 + qq * 64 + lane];
        int myj = 0;
        for (int kk = 0; kk < K_; kk++) {
            unsigned m = key[0];
            #pragma unroll
            for (int u = 1; u < 16; u++) m = key[u] > m ? key[u] : m;
            #pragma unroll
            for (int s = 1; s < 64; s <<= 1) {
                unsigned o = (unsigned)__shfl_xor((int)m, s, 64);
                m = o > m ? o : m;
            }
            const int j = N_ - 1 - (int)(m & 1023u);
            if (lane == kk) myj = j;
            #pragma unroll
            for (int u = 0; u < 16; u++)
                if (key[u] == m) key[u] = 0u;      // below any plausible real key
        }
        if (lane < K_) idx[(size_t)(b * N_ + rb + row) * K_ + lane] = myj;
    }
}

// ---------------------------------------------------------------- MFMA bf16 GEMM
// C[8192][NC] = A[8192][KD] @ Bw^T.  KD%32==0: global_load_lds dwordx4 into
// linear [T][32] LDS, source-side 16B-granule XOR swizzle, 2-phase dbuf.
// CATA: A is the virtual concat [x1b|x2b|x3b|x4b] (KD=512); per-k0 source
// select (region boundaries 64/128/256 are multiples of the 32-col k-step).
// POOL: no C write; fused column max+sum over rows via wave reduce + atomics
// (pmaxu = ordered-uint max, psum = f32 add), for the global pooling head.
template<int KD, int NC, int TM, int TN, bool CATA = false, bool POOL = false>
__global__ __launch_bounds__(256) void k_gemmb(const unsigned short* __restrict__ A,
                                               const unsigned short* __restrict__ A2,
                                               const unsigned short* __restrict__ A3,
                                               const unsigned short* __restrict__ A4,
                                               const unsigned short* __restrict__ Bw,
                                               const float* __restrict__ bias,
                                               const float* __restrict__ resid,
                                               float* __restrict__ Cout,
                                               int scale_cols, float qs,
                                               const float* __restrict__ gamma,
                                               const float* __restrict__ beta,
                                               unsigned short* __restrict__ obf,
                                               unsigned* __restrict__ pmaxu,
                                               float* __restrict__ psum) {
    const int t = threadIdx.x;
    const int rb = blockIdx.x * TM, cb = blockIdx.y * TN;
    const int w = t >> 6, lane = t & 63;
    constexpr int QR = TM / 2, QC = TN / 2;
    constexpr int MR = QR / 16, NR = QC / 16;
    const int wr = (w & 1) * QR, wc = (w >> 1) * QC;
    const int fr = lane & 15, q = lane >> 4, fq = q * 8;
    f32x4 acc[MR][NR] = {};
    if constexpr (KD % 32 == 0) {
        __shared__ __align__(16) unsigned short As[2][TM * 32];
        __shared__ __align__(16) unsigned short Bs[2][TN * 32];
        auto STAGE = [&](int buf, int k0) {
            const unsigned short* Asrc = A; int AC = KD, ac0 = k0;
            if constexpr (CATA) {
                if (k0 >= 256)      { Asrc = A4; AC = 256; ac0 = k0 - 256; }
                else if (k0 >= 128) { Asrc = A3; AC = 128; ac0 = k0 - 128; }
                else if (k0 >= 64)  { Asrc = A2; AC = 64;  ac0 = k0 - 64; }
                else                { Asrc = A;  AC = 64;  ac0 = k0; }
            }
            constexpr int AT = TM * 4;
            #pragma unroll
            for (int R = 0; R < (AT + 255) / 256; R++) {
                const int G = t + R * 256;
                if (AT >= (R + 1) * 256 || G < AT) {
                    const int m = G >> 2, gs = (G & 3) ^ ((m >> 1) & 3);
                    ldsld16(&Asrc[(size_t)(rb + m) * AC + ac0 + gs * 8], &As[buf][w * 512 + R * 2048]);
                }
            }
            constexpr int BT = TN * 4;
            #pragma unroll
            for (int R = 0; R < (BT + 255) / 256; R++) {
                const int G = t + R * 256;
                if (BT >= (R + 1) * 256 || G < BT) {
                    const int n = G >> 2, gs = (G & 3) ^ ((n >> 1) & 3);
                    ldsld16(&Bw[(size_t)(cb + n) * KD + k0 + gs * 8], &Bs[buf][w * 512 + R * 2048]);
                }
            }
        };
        constexpr int NT = KD / 32;
        STAGE(0, 0);
        asm volatile("s_waitcnt vmcnt(0)" ::: "memory");
        __builtin_amdgcn_s_barrier();
        int cur = 0;
        for (int ts = 0; ts < NT; ++ts) {
            if (ts + 1 < NT) STAGE(cur ^ 1, (ts + 1) * 32);
            short8 af[MR], bfr[NR];
            #pragma unroll
            for (int mi = 0; mi < MR; mi++) {
                const int r = wr + mi * 16 + fr;
                af[mi] = *reinterpret_cast<const short8*>(&As[cur][r * 32 + ((q ^ ((r >> 1) & 3)) << 3)]);
            }
            #pragma unroll
            for (int ni = 0; ni < NR; ni++) {
                const int r = wc + ni * 16 + fr;
                bfr[ni] = *reinterpret_cast<const short8*>(&Bs[cur][r * 32 + ((q ^ ((r >> 1) & 3)) << 3)]);
            }
            #pragma unroll
            for (int mi = 0; mi < MR; mi++) {
                #pragma unroll
                for (int ni = 0; ni < NR; ni++)
                    acc[mi][ni] = __builtin_amdgcn_mfma_f32_16x16x32_bf16(af[mi], bfr[ni], acc[mi][ni], 0, 0, 0);
            }
            asm volatile("s_waitcnt vmcnt(0)" ::: "memory");
            __builtin_amdgcn_s_barrier();
            cur ^= 1;
        }
    } else {
        // fallback (KD=3): reg-staged, padded LDS, scalar guarded loads
        __shared__ __align__(16) unsigned short As[TM * 40];
        __shared__ __align__(16) unsigned short Bs[TN * 40];
        for (int k0 = 0; k0 < KD; k0 += 32) {
            __syncthreads();
            #pragma unroll
            for (int u = t; u < TM * 4; u += 256) {
                const int m = u >> 2, c = (u & 3) * 8;
                #pragma unroll
                for (int j = 0; j < 8; j++) {
                    const int kk = k0 + c + j;
                    As[m * 40 + c + j] = (kk < KD) ? A[(size_t)(rb + m) * KD + kk] : (unsigned short)0;
                }
            }
            #pragma unroll
            for (int u = t; u < TN * 4; u += 256) {
                const int n = u >> 2, c = (u & 3) * 8;
                const int gn = cb + n;
                if (gn < NC) {
                    #pragma unroll
                    for (int j = 0; j < 8; j++) {
                        const int kk = k0 + c + j;
                        Bs[n * 40 + c + j] = (kk < KD) ? Bw[(size_t)gn * KD + kk] : (unsigned short)0;
                    }
                } else {
                    short8 z = {};
                    *reinterpret_cast<short8*>(&Bs[n * 40 + c]) = z;
                }
            }
            __syncthreads();
            short8 af[MR], bfr[NR];
            #pragma unroll
            for (int mi = 0; mi < MR; mi++)
                af[mi] = *reinterpret_cast<const short8*>(&As[(wr + mi * 16 + fr) * 40 + fq]);
            #pragma unroll
            for (int ni = 0; ni < NR; ni++)
                bfr[ni] = *reinterpret_cast<const short8*>(&Bs[(wc + ni * 16 + fr) * 40 + fq]);
            #pragma unroll
            for (int mi = 0; mi < MR; mi++) {
                #pragma unroll
                for (int ni = 0; ni < NR; ni++)
                    acc[mi][ni] = __builtin_amdgcn_mfma_f32_16x16x32_bf16(af[mi], bfr[ni], acc[mi][ni], 0, 0, 0);
            }
        }
    }
    const int cr = (lane >> 4) * 4, cc = lane & 15;
    if constexpr (POOL) {
        const int bidx = rb >> 10;
        #pragma unroll
        for (int ni = 0; ni < NR; ni++) {
            const int col = cb + wc + ni * 16 + cc;
            const float gm = gamma[col] * BN_SCALE, bt = beta[col];
            float sm = 0.f, mxv = -3e38f;
            #pragma unroll
            for (int mi = 0; mi < MR; mi++) {
                #pragma unroll
                for (int r = 0; r < 4; r++) {
                    float v = acc[mi][ni][r] * gm + bt;
                    v = v >= 0.f ? v : 0.2f * v;
                    sm += v; mxv = fmaxf(mxv, v);
                }
            }
            sm += __shfl_xor(sm, 16, 64);
            sm += __shfl_xor(sm, 32, 64);
            mxv = fmaxf(mxv, __shfl_xor(mxv, 16, 64));
            mxv = fmaxf(mxv, __shfl_xor(mxv, 32, 64));
            if (lane < 16) {
                atomicAdd(&psum[bidx * 1024 + col], sm);
                unsigned tb = __float_as_uint(mxv);
                tb = (tb & 0x80000000u) ? ~tb : (tb | 0x80000000u);
                atomicMax(&pmaxu[bidx * 1024 + col], tb);
            }
        }
    } else {
        #pragma unroll
        for (int mi = 0; mi < MR; mi++) {
            #pragma unroll
            for (int ni = 0; ni < NR; ni++) {
                #pragma unroll
                for (int r = 0; r < 4; r++) {
                    const int row = rb + wr + mi * 16 + cr + r;
                    const int col = cb + wc + ni * 16 + cc;
                    if (col < NC) {
                        float v = acc[mi][ni][r] + (bias ? bias[col] : 0.f);
                        if (col < scale_cols) v *= qs;
                        if (resid) v += resid[(size_t)row * NC + col];
                        if (gamma) {
                            v = v * (gamma[col] * BN_SCALE) + beta[col];
                            v = v >= 0.f ? v : 0.2f * v;
                        }
                        Cout[(size_t)row * NC + col] = v;
                        if (obf) obf[(size_t)row * NC + col] = F2BF(v);
                    }
                }
            }
        }
    }
}

// ---------------------------------------------------------------- EdgeConv epilogue (fp32 out + bf16 copy)
template<int CO>
__global__ __launch_bounds__(256) void k_edgemax(const float* __restrict__ yz,
                                                 const int* __restrict__ idx,
                                                 const float* __restrict__ g,
                                                 const float* __restrict__ bb,
                                                 float* __restrict__ out,
                                                 unsigned short* __restrict__ outb) {
    constexpr int TPP = CO / 4;
    constexpr int PPB = 256 / TPP;
    const int t = threadIdx.x;
    const int p = t / TPP;
    const int cw = (t % TPP) * 4;
    const int i0 = blockIdx.x * PPB;
    const int bbase = (i0 >> 10) << 10;
    __shared__ int sidx[PPB][K_];
    for (int u = t; u < PPB * K_; u += 256) {
        int pp = u / K_, kk = u - pp * K_;
        sidx[pp][kk] = idx[(size_t)(i0 + pp) * K_ + kk];
    }
    __syncthreads();
    const int ig = i0 + p;
    float4 m = {-3e38f, -3e38f, -3e38f, -3e38f};
    #pragma unroll 4
    for (int k = 0; k < K_; k++) {
        const int jg = bbase + sidx[p][k];
        const float4 yv = *reinterpret_cast<const float4*>(&yz[(size_t)jg * 2 * CO + cw]);
        m.x = fmaxf(m.x, yv.x); m.y = fmaxf(m.y, yv.y);
        m.z = fmaxf(m.z, yv.z); m.w = fmaxf(m.w, yv.w);
    }
    const float4 yi = *reinterpret_cast<const float4*>(&yz[(size_t)ig * 2 * CO + cw]);
    const float4 zi = *reinterpret_cast<const float4*>(&yz[(size_t)ig * 2 * CO + CO + cw]);
    const float4 gv = *reinterpret_cast<const float4*>(&g[cw]);
    const float4 bv = *reinterpret_cast<const float4*>(&bb[cw]);
    float vals[4] = {m.x - yi.x + zi.x, m.y - yi.y + zi.y,
                     m.z - yi.z + zi.z, m.w - yi.w + zi.w};
    float gs[4] = {gv.x, gv.y, gv.z, gv.w};
    float bs[4] = {bv.x, bv.y, bv.z, bv.w};
    float4 o;
    float* op = &o.x;
    #pragma unroll
    for (int j = 0; j < 4; j++) {
        float h = vals[j] * (gs[j] * BN_SCALE) + bs[j];
        op[j] = h >= 0.f ? h : 0.2f * h;
    }
    *reinterpret_cast<float4*>(&out[(size_t)ig * CO + cw]) = o;
    #pragma unroll
    for (int j = 0; j < 4; j++) outb[(size_t)ig * CO + cw + j] = F2BF(op[j]);
}

// ---------------------------------------------------------------- attention (fp32 math, bf16 out)
template<int E>
__global__ __launch_bounds__(256) void k_attn(const float* __restrict__ qkv,
                                              unsigned short* __restrict__ o) {
    constexpr int H = 4, D = E / H, L = 8;
    const int n = blockIdx.x;
    const int t = threadIdx.x;
    const int h = t >> 6, lane = t & 63;
    __shared__ float sq[L][3 * E];
    __shared__ float so[L][E];
    for (int u = t; u < L * 3 * E; u += 256) {
        int l = u / (3 * E), r = u - l * (3 * E);
        sq[l][r] = qkv[(size_t)(l * N_ + n) * (3 * E) + r];
    }
    __syncthreads();
    const int l = lane >> 3, m = lane & 7;
    float s = 0.f;
    #pragma unroll 8
    for (int dd = 0; dd < D; dd++)
        s += sq[l][h * D + dd] * sq[m][E + h * D + dd];
    float mx = s;
    #pragma unroll
    for (int st = 1; st < 8; st <<= 1) mx = fmaxf(mx, __shfl_xor(mx, st, 64));
    float e = expf(s - mx);
    float sum = e;
    #pragma unroll
    for (int st = 1; st < 8; st <<= 1) sum += __shfl_xor(sum, st, 64);
    const float p = e / sum;
    float pm[8];
    #pragma unroll
    for (int mm = 0; mm < 8; mm++) pm[mm] = __shfl(p, (lane & 56) | mm, 64);
    #pragma unroll
    for (int j = 0; j < D / 8; j++) {
        const int dd = m + 8 * j;
        float a = 0.f;
        #pragma unroll
        for (int mm = 0; mm < 8; mm++) a += pm[mm] * sq[mm][2 * E + h * D + dd];
        so[l][h * D + dd] = a;
    }
    __syncthreads();
    for (int u = t; u < L * E; u += 256) {
        int l2 = u / E, e2 = u - l2 * E;
        o[(size_t)(l2 * N_ + n) * E + e2] = F2BF(so[l2][e2]);
    }
}

// ---------------------------------------------------------------- FC head
// fc1 reads the pooled feat inline from pmaxu/psum (pool2 folded in).
__global__ __launch_bounds__(256) void k_fc1(const unsigned* __restrict__ pmaxu,
                                             const float* __restrict__ psum,
                                             const float* __restrict__ l1wT,
                                             const float* __restrict__ g6, const float* __restrict__ b6,
                                             float* __restrict__ f1) {
    int oc = blockIdx.x, b = blockIdx.y, t = threadIdx.x;
    __shared__ float fin[2048];
    __shared__ float ps[4][64];
    for (int u = t; u < 2048; u += 256) {
        float v;
        if (u < 1024) {
            unsigned tb = pmaxu[b * 1024 + u];
            unsigned bits = (tb & 0x80000000u) ? (tb & 0x7FFFFFFFu) : ~tb;
            v = __uint_as_float(bits);
        } else {
            v = psum[b * 1024 + (u - 1024)] * (1.f / 1024.f);
        }
        fin[u] = v;
    }
    __syncthreads();
    int ol = t & 63, kc = t >> 6;
    int o = oc * 64 + ol;
    float acc = 0.f;
    for (int c = kc * 512; c < kc * 512 + 512; c++) acc += fin[c] * l1wT[(size_t)c * 512 + o];
    ps[kc][ol] = acc;
    __syncthreads();
    if (t < 64) {
        int oo = oc * 64 + t;
        float a = ps[0][t] + ps[1][t] + ps[2][t] + ps[3][t];
        float h = a * (g6[oo] * BN_SCALE) + b6[oo];
        f1[b * 512 + oo] = h >= 0.f ? h : 0.2f * h;
    }
}

// fc2 + fc3 fused (one block per batch; f2 lives in LDS only)
__global__ __launch_bounds__(256) void k_fc23(const float* __restrict__ f1, const float* __restrict__ l2wT,
                                              const float* __restrict__ l2b,
                                              const float* __restrict__ g7, const float* __restrict__ b7,
                                              const float* __restrict__ l3wT, const float* __restrict__ l3b,
                                              void* __restrict__ out, const int* __restrict__ flag) {
    int b = blockIdx.x, t = threadIdx.x;
    __shared__ float fin[512];
    __shared__ float f2s[256];
    for (int u = t; u < 512; u += 256) fin[u] = f1[b * 512 + u];
    __syncthreads();
    {
        float acc = 0.f;
        for (int c = 0; c < 512; c++) acc += fin[c] * l2wT[(size_t)c * 256 + t];
        acc += l2b[t];
        float h = acc * (g7[t] * BN_SCALE) + b7[t];
        f2s[t] = h >= 0.f ? h : 0.2f * h;
    }
    __syncthreads();
    if (t < 40) {
        float acc = 0.f;
        for (int c = 0; c < 256; c++) acc += f2s[c] * l3wT[(size_t)c * 40 + t];
        acc += l3b[t];
        if (*flag) ((__hip_bfloat16*)out)[b * 40 + t] = __float2bfloat16(acc);
        else       ((float*)out)[b * 40 + t] = acc;
    }
}

// ================================================================ host
extern "C" void kernel_launch(void* const* d_in, const int* in_sizes, int n_in,
                              void* d_out, int out_size, void* d_ws, size_t ws_size,
                              hipStream_t stream) {
    auto us = [&](int i) { return (const unsigned short*)d_in[i]; };

    float* ws = (float*)d_ws;
    size_t off = 0;
    auto A = [&](size_t n) { float* p = ws + off; off += (n + 3) & ~(size_t)3; return p; };
    auto AU = [&](size_t n) { return (unsigned short*)A((n + 1) / 2); };
    float* xf0  = A((size_t)BN_ * 3);
    float* x1   = A((size_t)BN_ * 64);
    float* x2   = A((size_t)BN_ * 64);
    float* x3   = A((size_t)BN_ * 128);
    float* x4   = A((size_t)BN_ * 256);
    float* f1   = A(8 * 512);
    float* xx   = A(BN_);
    int*   idx  = (int*)A((size_t)BN_ * K_);
    int*   flag = (int*)A(4);
    float* qkvw = A((size_t)BN_ * 768);   // qkv / yz / knn-split scratch
    // bf16 activation copies
    unsigned short* xf0b = AU((size_t)BN_ * 3);
    unsigned short* x1b  = AU((size_t)BN_ * 64);
    unsigned short* x2b  = AU((size_t)BN_ * 64);
    unsigned short* x3b  = AU((size_t)BN_ * 128);
    unsigned short* x4b  = AU((size_t)BN_ * 256);
    unsigned short* owb  = AU((size_t)BN_ * 256);
    // pooled reductions (conv5 fused epilogue) -- contiguous, zeroed by k_prep
    unsigned* pmaxu = (unsigned*)A(8 * 1024);
    float*    psum  = A(8 * 1024);
    // bf16 weights (n,k) layouts
    unsigned short* w1yzb = AU(128 * 3);
    unsigned short* w2yzb = AU(128 * 64);
    unsigned short* w3yzb = AU(256 * 64);
    unsigned short* w4yzb = AU(512 * 128);
    unsigned short* a1wib = AU(192 * 64);  unsigned short* a1wob = AU(64 * 64);
    unsigned short* a2wib = AU(192 * 64);  unsigned short* a2wob = AU(64 * 64);
    unsigned short* a3wib = AU(384 * 128); unsigned short* a3wob = AU(128 * 128);
    unsigned short* a4wib = AU(768 * 256); unsigned short* a4wob = AU(256 * 256);
    unsigned short* w5b   = AU(1024 * 512);
    // fp32 fc weights (transposed)
    float* l1wT  = A(2048 * 512);
    float* l2wT  = A(512 * 256);
    float* l3wT  = A(256 * 40);
    // converted vectors (fp32)
    float* g1f = A(64);   float* b1f = A(64);
    float* g2f = A(64);   float* b2f = A(64);
    float* g3f = A(128);  float* b3f = A(128);
    float* g4f = A(256);  float* b4f = A(256);
    float* bi1 = A(192);  float* bo1 = A(64);
    float* bi2 = A(192);  float* bo2 = A(64);
    float* bi3 = A(384);  float* bo3 = A(128);
    float* bi4 = A(768);  float* bo4 = A(256);
    float* g5f = A(1024); float* b5f = A(1024);
    float* g6f = A(512);  float* b6f = A(512);
    float* l2bf = A(256);
    float* g7f = A(256);  float* b7f = A(256);
    float* l3bf = A(40);

    // knn split buffers alias qkvw (dead during the kNN phase of each layer)
    unsigned short* xa = (unsigned short*)qkvw;
    unsigned short* xb = (unsigned short*)qkvw + (size_t)BN_ * 512;

    k_detect<<<1, 1, 0, stream>>>(us(2), us(5), us(8), us(11), us(30), us(33), us(37), flag);

    TList tl; int nb = 0; int k = 0;
    auto add = [&](int i, void* dst, int O, int I, int mode) {
        tl.p[k].src = d_in[i]; tl.p[k].dst = dst; tl.p[k].O = O; tl.p[k].I = I;
        tl.p[k].blk0 = nb; tl.p[k].mode = mode;
        nb += (O * I + 255) / 256; k++;
    };
    add(0,  xf0,   BN_ * 3, 1, 0);
    add(0,  xf0b,  BN_ * 3, 1, 2);
    add(0,  pmaxu, 16384, 1, 4);      // zero pmaxu+psum (contiguous)
    add(1,  w1yzb, 64, 6, 3);
    add(4,  w2yzb, 64, 128, 3);
    add(7,  w3yzb, 128, 128, 3);
    add(10, w4yzb, 256, 256, 3);
    add(13, a1wib, 192, 64, 2);
    add(15, a1wob, 64, 64, 2);
    add(17, a2wib, 192, 64, 2);
    add(19, a2wob, 64, 64, 2);
    add(21, a3wib, 384, 128, 2);
    add(23, a3wob, 128, 128, 2);
    add(25, a4wib, 768, 256, 2);
    add(27, a4wob, 256, 256, 2);
    add(29, w5b,   1024, 512, 2);
    add(2,  g1f, 64, 1, 0);   add(3,  b1f, 64, 1, 0);
    add(5,  g2f, 64, 1, 0);   add(6,  b2f, 64, 1, 0);
    add(8,  g3f, 128, 1, 0);  add(9,  b3f, 128, 1, 0);
    add(11, g4f, 256, 1, 0);  add(12, b4f, 256, 1, 0);
    add(14, bi1, 192, 1, 0);  add(16, bo1, 64, 1, 0);
    add(18, bi2, 192, 1, 0);  add(20, bo2, 64, 1, 0);
    add(22, bi3, 384, 1, 0);  add(24, bo3, 128, 1, 0);
    add(26, bi4, 768, 1, 0);  add(28, bo4, 256, 1, 0);
    add(30, g5f, 1024, 1, 0); add(31, b5f, 1024, 1, 0);
    add(33, g6f, 512, 1, 0);  add(34, b6f, 512, 1, 0);
    add(36, l2bf, 256, 1, 0);
    add(37, g7f, 256, 1, 0);  add(38, b7f, 256, 1, 0);
    add(40, l3bf, 40, 1, 0);
    k_prep<<<nb, 256, 0, stream>>>(tl, k, flag);

    // LDS-tiled transposes for the big fp32 FC weights (coalesced both sides)
    TrP tp1{d_in[32], l1wT, 512, 2048, 2048 / 32, 0};
    TrP tp2{d_in[35], l2wT, 256, 512,  512 / 32,  (2048 / 32) * (512 / 32)};
    TrP tp3{d_in[39], l3wT, 40,  256,  256 / 32,  tp2.blk0 + (512 / 32) * (256 / 32)};
    const int trblocks = tp3.blk0 + (256 / 32) * ((40 + 31) / 32);
    k_tr<<<trblocks, 256, 0, stream>>>(tp1, tp2, tp3, flag);

    float* yzb = qkvw;                 // fp32 yz scratch (after kNN phase)
    const dim3 knng(N_ / 32, 1, 8);    // 256 blocks = 1/CU
    const unsigned short* N0 = nullptr;
    unsigned* NU = nullptr; float* NF = nullptr;

    // layer 1  (C=3 -> 64)
    k_split<3, 32><<<(BN_ * 32) / 256 + 32, 256, 0, stream>>>(xf0, xa, xb, xx);
    k_knn<32><<<knng, 512, 0, stream>>>(xa, xb, xx, idx);
    k_gemmb<3, 128, 64, 64><<<dim3(128, 2), 256, 0, stream>>>(xf0b, N0, N0, N0, w1yzb, nullptr, nullptr, yzb, 0, 1.f, nullptr, nullptr, nullptr, NU, NF);
    k_edgemax<64><<<BN_ / 16, 256, 0, stream>>>(yzb, idx, g1f, b1f, x1, x1b);
    k_gemmb<64, 192, 64, 64><<<dim3(128, 3), 256, 0, stream>>>(x1b, N0, N0, N0, a1wib, bi1, nullptr, qkvw, 64, 0.25f, nullptr, nullptr, nullptr, NU, NF);
    k_attn<64><<<N_, 256, 0, stream>>>(qkvw, owb);
    k_gemmb<64, 64, 64, 64><<<dim3(128, 1), 256, 0, stream>>>(owb, N0, N0, N0, a1wob, bo1, x1, x1, 0, 1.f, nullptr, nullptr, x1b, NU, NF);

    // layer 2  (C=64 -> 64)
    k_split<64, 256><<<(BN_ * 256) / 256 + 32, 256, 0, stream>>>(x1, xa, xb, xx);
    k_knn<256><<<knng, 512, 0, stream>>>(xa, xb, xx, idx);
    k_gemmb<64, 128, 64, 64><<<dim3(128, 2), 256, 0, stream>>>(x1b, N0, N0, N0, w2yzb, nullptr, nullptr, yzb, 0, 1.f, nullptr, nullptr, nullptr, NU, NF);
    k_edgemax<64><<<BN_ / 16, 256, 0, stream>>>(yzb, idx, g2f, b2f, x2, x2b);
    k_gemmb<64, 192, 64, 64><<<dim3(128, 3), 256, 0, stream>>>(x2b, N0, N0, N0, a2wib, bi2, nullptr, qkvw, 64, 0.25f, nullptr, nullptr, nullptr, NU, NF);
    k_attn<64><<<N_, 256, 0, stream>>>(qkvw, owb);
    k_gemmb<64, 64, 64, 64><<<dim3(128, 1), 256, 0, stream>>>(owb, N0, N0, N0, a2wob, bo2, x2, x2, 0, 1.f, nullptr, nullptr, x2b, NU, NF);

    // layer 3  (C=64 -> 128)
    k_split<64, 256><<<(BN_ * 256) / 256 + 32, 256, 0, stream>>>(x2, xa, xb, xx);
    k_knn<256><<<knng, 512, 0, stream>>>(xa, xb, xx, idx);
    k_gemmb<64, 256, 64, 64><<<dim3(128, 4), 256, 0, stream>>>(x2b, N0, N0, N0, w3yzb, nullptr, nullptr, yzb, 0, 1.f, nullptr, nullptr, nullptr, NU, NF);
    k_edgemax<128><<<BN_ / 8, 256, 0, stream>>>(yzb, idx, g3f, b3f, x3, x3b);
    k_gemmb<128, 384, 64, 128><<<dim3(128, 3), 256, 0, stream>>>(x3b, N0, N0, N0, a3wib, bi3, nullptr, qkvw, 128, 0.17677669529663687f, nullptr, nullptr, nullptr, NU, NF);
    k_attn<128><<<N_, 256, 0, stream>>>(qkvw, owb);
    k_gemmb<128, 128, 64, 64><<<dim3(128, 2), 256, 0, stream>>>(owb, N0, N0, N0, a3wob, bo3, x3, x3, 0, 1.f, nullptr, nullptr, x3b, NU, NF);

    // layer 4  (C=128 -> 256)
    k_split<128, 512><<<(BN_ * 512) / 256 + 32, 256, 0, stream>>>(x3, xa, xb, xx);
    k_knn<512><<<knng, 512, 0, stream>>>(xa, xb, xx, idx);
    k_gemmb<128, 512, 128, 128><<<dim3(64, 4), 256, 0, stream>>>(x3b, N0, N0, N0, w4yzb, nullptr, nullptr, yzb, 0, 1.f, nullptr, nullptr, nullptr, NU, NF);
    k_edgemax<256><<<BN_ / 4, 256, 0, stream>>>(yzb, idx, g4f, b4f, x4, x4b);
    k_gemmb<256, 768, 128, 128><<<dim3(64, 6), 256, 0, stream>>>(x4b, N0, N0, N0, a4wib, bi4, nullptr, qkvw, 256, 0.125f, nullptr, nullptr, nullptr, NU, NF);
    k_attn<256><<<N_, 256, 0, stream>>>(qkvw, owb);
    k_gemmb<256, 256, 64, 128><<<dim3(128, 2), 256, 0, stream>>>(owb, N0, N0, N0, a4wob, bo4, x4, x4, 0, 1.f, nullptr, nullptr, x4b, NU, NF);

    // head: conv5 with fused concat-A and fused pooling epilogue
    k_gemmb<512, 1024, 128, 128, true, true><<<dim3(64, 8), 256, 0, stream>>>(
        x1b, x2b, x3b, x4b, w5b, nullptr, nullptr, nullptr, 0, 1.f, g5f, b5f, nullptr, pmaxu, psum);
    k_fc1<<<dim3(8, 8), 256, 0, stream>>>(pmaxu, psum, l1wT, g6f, b6f, f1);
    k_fc23<<<8, 256, 0, stream>>>(f1, l2wT, l2bf, g7f, b7f, l3wT, l3bf, d_out, flag);
}

// Round 6
// 643.617 us; speedup vs baseline: 1.0460x; 1.0460x over previous
//
#include <hip/hip_runtime.h>
#include <hip/hip_bf16.h>

#define B_ 8
#define N_ 1024
#define K_ 20
#define BN_ (B_*N_)

#define BN_SCALE 0.9999950000374997f

typedef __attribute__((ext_vector_type(8))) short short8;
typedef __attribute__((ext_vector_type(4))) float f32x4;

__device__ __forceinline__ float US2F(unsigned short u) {
    union { unsigned u; float f; } c; c.u = ((unsigned)u) << 16; return c.f;
}
__device__ __forceinline__ unsigned short F2BF(float f) {   // RNE fp32->bf16
    union { float f; unsigned u; } c; c.f = f;
    unsigned r = c.u + 0x7FFF + ((c.u >> 16) & 1);
    return (unsigned short)(r >> 16);
}

// async global->LDS 16B DMA: LDS dest = wave-uniform base + lane*16 (linear);
// global source is per-lane (pre-swizzled there when a swizzled layout is wanted).
__device__ __forceinline__ void ldsld16(const unsigned short* g, unsigned short* l) {
    __builtin_amdgcn_global_load_lds(
        (const __attribute__((address_space(1))) void*)g,
        (__attribute__((address_space(3))) void*)l, 16, 0, 0);
}

// ---------------------------------------------------------------- dtype detect
__global__ void k_detect(const unsigned short* g1, const unsigned short* g2,
                         const unsigned short* g3, const unsigned short* g4,
                         const unsigned short* g5, const unsigned short* g6,
                         const unsigned short* g7, int* flag) {
    const unsigned short* gs[7] = {g1, g2, g3, g4, g5, g6, g7};
    int cnt = 0;
    for (int i = 0; i < 7; i++) {
        float v = US2F(gs[i][0]);
        if (v > 0.5f && v < 1.5f) cnt++;
    }
    *flag = (cnt >= 4) ? 1 : 0;   // 1 = bf16 inputs, 0 = fp32 inputs
}

// ---------------------------------------------------------------- prep
// mode 0: fp32 copy (I==1 -> contiguous).  mode 2: bf16 copy.
// mode 3: edge pair -> bf16 (2O, C).  mode 4: zero-fill fp32 (dst only).
struct TPar { const void* src; void* dst; int O, I, blk0, mode; };
struct TList { TPar p[44]; };

__global__ __launch_bounds__(256) void k_prep(TList tl, int nent, const int* flag) {
    const int isbf = *flag;
    int blk = blockIdx.x;
    int wi = 0;
    for (int j = nent - 1; j >= 0; j--) { if (blk >= tl.p[j].blk0) { wi = j; break; } }
    const TPar p = tl.p[wi];
    int e = (blk - p.blk0) * 256 + threadIdx.x;
    int n = p.O * p.I;
    if (e >= n) return;
    if (p.mode == 4) { ((float*)p.dst)[e] = 0.f; return; }
    int o = e / p.I, i = e - o * p.I;
    float v = isbf ? US2F(((const unsigned short*)p.src)[e])
                   : ((const float*)p.src)[e];
    if (p.mode == 0) {
        ((float*)p.dst)[(size_t)i * p.O + o] = v;
    } else if (p.mode == 2) {
        ((unsigned short*)p.dst)[e] = F2BF(v);
    } else {
        const int C = p.I >> 1;
        if (i < C) ((unsigned short*)p.dst)[(size_t)o * C + i] = F2BF(v);
        else       ((unsigned short*)p.dst)[(size_t)(p.O + o) * C + (i - C)] = F2BF(v);
    }
}

// ---------------------------------------------------------------- LDS-tiled transpose
// (O,I) row-major -> (I,O).  32x32 tiles, coalesced read AND write.
struct TrP { const void* src; float* dst; int O, I, bx, blk0; };

__global__ __launch_bounds__(256) void k_tr(TrP p0, TrP p1, TrP p2, const int* flag) {
    const int isbf = *flag;
    TrP p = p0;
    int blk = blockIdx.x;
    if (blk >= p2.blk0) p = p2; else if (blk >= p1.blk0) p = p1;
    blk -= p.blk0;
    const int tx = threadIdx.x & 31, ty = threadIdx.x >> 5;   // 32 x 8
    const int bi = blk % p.bx, bo = blk / p.bx;
    const int i0 = bi * 32, o0 = bo * 32;
    __shared__ float s[32][33];
    #pragma unroll
    for (int r = 0; r < 4; r++) {
        const int o = o0 + ty + r * 8, i = i0 + tx;
        if (o < p.O && i < p.I) {
            const size_t e = (size_t)o * p.I + i;
            s[ty + r * 8][tx] = isbf ? US2F(((const unsigned short*)p.src)[e])
                                     : ((const float*)p.src)[e];
        }
    }
    __syncthreads();
    #pragma unroll
    for (int r = 0; r < 4; r++) {
        const int i = i0 + ty + r * 8, o = o0 + tx;
        if (i < p.I && o < p.O) p.dst[(size_t)i * p.O + o] = s[tx][ty + r * 8];
    }
}

// ---------------------------------------------------------------- kNN split + norms (fused)
// split blocks: x (fp32) -> augmented bf16 rows (exact-split): xa=[hi,lo,hi,lo],
// xb=[hi,hi,lo,lo], zero-padded to KP.  Trailing 32 blocks: xx[i] = |x_i|^2.
template<int C, int KP>
__global__ __launch_bounds__(256) void k_split(const float* __restrict__ x,
                                               unsigned short* __restrict__ xa,
                                               unsigned short* __restrict__ xb,
                                               float* __restrict__ xx) {
    constexpr int NB = (BN_ * KP) / 256;
    if (blockIdx.x >= NB) {   // norms
        const int i = (blockIdx.x - NB) * 256 + threadIdx.x;
        if (i >= BN_) return;
        const float* p = x + (size_t)i * C;
        float s = 0.f;
        #pragma unroll
        for (int c = 0; c < C; c++) s += p[c] * p[c];
        xx[i] = s;
        return;
    }
    const int e = blockIdx.x * 256 + threadIdx.x;
    const int i = e / KP, p = e - i * KP;
    unsigned short va = 0, vb = 0;
    if (p < 4 * C) {
        const int seg = p / C, c = p - seg * C;
        const float v = x[(size_t)i * C + c];
        const unsigned short h = F2BF(v);
        const unsigned short l = F2BF(v - US2F(h));
        va = (seg & 1) ? l : h;           // hi,lo,hi,lo
        vb = (seg < 2) ? h : l;           // hi,hi,lo,lo
    }
    xa[e] = va;
    xb[e] = vb;
}

// ---------------------------------------------------------------- fused kNN (MFMA + top-20):
// One block = 32 rows x ALL 1024 cols of one batch; scores never leave the CU.
// Per col-tile (256 cols): MFMA over KP (same k-order as the old k_pdm ->
// bit-identical scores), then keys (22-bit value | 10-bit 1023-j, identical to
// old k_sel) written to LDS.  Selection: wave w owns rows w*4..w*4+3, all 4
// rows INTERLEAVED (ILP-4) -- R5 ran them sequentially, exposing the 20-round
// shfl/max dependency chain 4x with only 8 waves/CU of TLP; that made k_knn
// 78.8us flat across KP (selection-dominated).  4 independent chains hide the
// shfl latency; results bit-identical.
template<int KP>
__global__ __launch_bounds__(512) void k_knn(const unsigned short* __restrict__ xa,
                                             const unsigned short* __restrict__ xb,
                                             const float* __restrict__ xx,
                                             int* __restrict__ idx) {
    constexpr int TM = 32, TC = 256;
    const int b = blockIdx.z;
    const int rb = blockIdx.x * TM;
    const unsigned short* Ab = xa + (size_t)b * N_ * KP;
    const unsigned short* Bb = xb + (size_t)b * N_ * KP;
    const float* xxb = xx + (size_t)b * N_;
    const int t = threadIdx.x;
    const int w = t >> 6, lane = t & 63;
    __shared__ __align__(16) unsigned short As[TM * 32];
    __shared__ __align__(16) unsigned short Bs[TC * 32];
    __shared__ unsigned sc[TM * 1033];
    const int wr = (w & 1) * 16, wc = (w >> 1) * 64;   // 2x4 wave layout
    const int fr = lane & 15, q = lane >> 4;
    const int cr = (lane >> 4) * 4, cc = lane & 15;

    for (int ct = 0; ct < N_ / TC; ct++) {
        const int cb = ct * TC;
        f32x4 acc[4] = {};
        for (int k0 = 0; k0 < KP; k0 += 32) {
            // stage A: 32 rows x 32 k = 128 x 16B (waves 0,1; wave-uniform branch)
            if (w < 2) {
                const int m = t >> 2, gs = (t & 3) ^ ((m >> 1) & 3);
                ldsld16(&Ab[(size_t)(rb + m) * KP + k0 + gs * 8], &As[w * 512]);
            }
            // stage B: 256 rows x 32 k = 1024 x 16B (all 8 waves, 2 rounds)
            #pragma unroll
            for (int R = 0; R < 2; R++) {
                const int G = t + R * 512;
                const int n = G >> 2, gs = (G & 3) ^ ((n >> 1) & 3);
                ldsld16(&Bb[(size_t)(cb + n) * KP + k0 + gs * 8], &Bs[w * 512 + R * 4096]);
            }
            __syncthreads();   // drains vmcnt -> staging visible
            short8 af;
            {
                const int r = wr + fr;
                af = *reinterpret_cast<const short8*>(&As[r * 32 + ((q ^ ((r >> 1) & 3)) << 3)]);
            }
            short8 bfr[4];
            #pragma unroll
            for (int ni = 0; ni < 4; ni++) {
                const int r = wc + ni * 16 + fr;
                bfr[ni] = *reinterpret_cast<const short8*>(&Bs[r * 32 + ((q ^ ((r >> 1) & 3)) << 3)]);
            }
            #pragma unroll
            for (int ni = 0; ni < 4; ni++)
                acc[ni] = __builtin_amdgcn_mfma_f32_16x16x32_bf16(af, bfr[ni], acc[ni], 0, 0, 0);
            __syncthreads();   // reads done before next-stage overwrite
        }
        // keys -> LDS (pd = 2*dot - xx[col]; same truncation as old k_sel)
        #pragma unroll
        for (int ni = 0; ni < 4; ni++) {
            const int col = cb + wc + ni * 16 + cc;
            const float xv = xxb[col];
            #pragma unroll
            for (int r = 0; r < 4; r++) {
                const int row = wr + cr + r;
                float v = 2.f * acc[ni][r] - xv;
                unsigned bits = __float_as_uint(v);
                bits = (bits & 0x80000000u) ? ~bits : (bits | 0x80000000u);
                sc[row * 1033 + col] = (bits & 0xFFFFFC00u) | (unsigned)(N_ - 1 - col);
            }
        }
    }
    __syncthreads();
    // selection: rows w*4..w*4+3 interleaved (4 independent dependency chains)
    unsigned key[4][16];
    #pragma unroll
    for (int rr = 0; rr < 4; rr++) {
        #pragma unroll
        for (int qq = 0; qq < 16; qq++)
            key[rr][qq] = sc[(w * 4 + rr) * 1033 + qq * 64 + lane];
    }
    int myj[4] = {0, 0, 0, 0};
    for (int kk = 0; kk < K_; kk++) {
        unsigned m[4];
        #pragma unroll
        for (int rr = 0; rr < 4; rr++) {
            m[rr] = key[rr][0];
            #pragma unroll
            for (int u = 1; u < 16; u++) m[rr] = key[rr][u] > m[rr] ? key[rr][u] : m[rr];
        }
        #pragma unroll
        for (int s = 1; s < 64; s <<= 1) {
            #pragma unroll
            for (int rr = 0; rr < 4; rr++) {
                unsigned o = (unsigned)__shfl_xor((int)m[rr], s, 64);
                m[rr] = o > m[rr] ? o : m[rr];
            }
        }
        #pragma unroll
        for (int rr = 0; rr < 4; rr++) {
            const int j = N_ - 1 - (int)(m[rr] & 1023u);
            if (lane == kk) myj[rr] = j;
            #pragma unroll
            for (int u = 0; u < 16; u++)
                if (key[rr][u] == m[rr]) key[rr][u] = 0u;   // below any real key
        }
    }
    if (lane < K_) {
        #pragma unroll
        for (int rr = 0; rr < 4; rr++)
            idx[(size_t)(b * N_ + rb + w * 4 + rr) * K_ + lane] = myj[rr];
    }
}

// ---------------------------------------------------------------- MFMA bf16 GEMM
// C[8192][NC] = A[8192][KD] @ Bw^T.  KD%32==0: global_load_lds dwordx4 into
// linear [T][32] LDS, source-side 16B-granule XOR swizzle, 2-phase dbuf.
// CATA: A is the virtual concat [x1b|x2b|x3b|x4b] (KD=512); per-k0 source
// select (region boundaries 64/128/256 are multiples of the 32-col k-step).
// POOL: no C write; fused column max+sum over rows via wave reduce + atomics
// (pmaxu = ordered-uint max, psum = f32 add), for the global pooling head.
template<int KD, int NC, int TM, int TN, bool CATA = false, bool POOL = false>
__global__ __launch_bounds__(256) void k_gemmb(const unsigned short* __restrict__ A,
                                               const unsigned short* __restrict__ A2,
                                               const unsigned short* __restrict__ A3,
                                               const unsigned short* __restrict__ A4,
                                               const unsigned short* __restrict__ Bw,
                                               const float* __restrict__ bias,
                                               const float* __restrict__ resid,
                                               float* __restrict__ Cout,
                                               int scale_cols, float qs,
                                               const float* __restrict__ gamma,
                                               const float* __restrict__ beta,
                                               unsigned short* __restrict__ obf,
                                               unsigned* __restrict__ pmaxu,
                                               float* __restrict__ psum) {
    const int t = threadIdx.x;
    const int rb = blockIdx.x * TM, cb = blockIdx.y * TN;
    const int w = t >> 6, lane = t & 63;
    constexpr int QR = TM / 2, QC = TN / 2;
    constexpr int MR = QR / 16, NR = QC / 16;
    const int wr = (w & 1) * QR, wc = (w >> 1) * QC;
    const int fr = lane & 15, q = lane >> 4, fq = q * 8;
    f32x4 acc[MR][NR] = {};
    if constexpr (KD % 32 == 0) {
        __shared__ __align__(16) unsigned short As[2][TM * 32];
        __shared__ __align__(16) unsigned short Bs[2][TN * 32];
        auto STAGE = [&](int buf, int k0) {
            const unsigned short* Asrc = A; int AC = KD, ac0 = k0;
            if constexpr (CATA) {
                if (k0 >= 256)      { Asrc = A4; AC = 256; ac0 = k0 - 256; }
                else if (k0 >= 128) { Asrc = A3; AC = 128; ac0 = k0 - 128; }
                else if (k0 >= 64)  { Asrc = A2; AC = 64;  ac0 = k0 - 64; }
                else                { Asrc = A;  AC = 64;  ac0 = k0; }
            }
            constexpr int AT = TM * 4;
            #pragma unroll
            for (int R = 0; R < (AT + 255) / 256; R++) {
                const int G = t + R * 256;
                if (AT >= (R + 1) * 256 || G < AT) {
                    const int m = G >> 2, gs = (G & 3) ^ ((m >> 1) & 3);
                    ldsld16(&Asrc[(size_t)(rb + m) * AC + ac0 + gs * 8], &As[buf][w * 512 + R * 2048]);
                }
            }
            constexpr int BT = TN * 4;
            #pragma unroll
            for (int R = 0; R < (BT + 255) / 256; R++) {
                const int G = t + R * 256;
                if (BT >= (R + 1) * 256 || G < BT) {
                    const int n = G >> 2, gs = (G & 3) ^ ((n >> 1) & 3);
                    ldsld16(&Bw[(size_t)(cb + n) * KD + k0 + gs * 8], &Bs[buf][w * 512 + R * 2048]);
                }
            }
        };
        constexpr int NT = KD / 32;
        STAGE(0, 0);
        asm volatile("s_waitcnt vmcnt(0)" ::: "memory");
        __builtin_amdgcn_s_barrier();
        int cur = 0;
        for (int ts = 0; ts < NT; ++ts) {
            if (ts + 1 < NT) STAGE(cur ^ 1, (ts + 1) * 32);
            short8 af[MR], bfr[NR];
            #pragma unroll
            for (int mi = 0; mi < MR; mi++) {
                const int r = wr + mi * 16 + fr;
                af[mi] = *reinterpret_cast<const short8*>(&As[cur][r * 32 + ((q ^ ((r >> 1) & 3)) << 3)]);
            }
            #pragma unroll
            for (int ni = 0; ni < NR; ni++) {
                const int r = wc + ni * 16 + fr;
                bfr[ni] = *reinterpret_cast<const short8*>(&Bs[cur][r * 32 + ((q ^ ((r >> 1) & 3)) << 3)]);
            }
            #pragma unroll
            for (int mi = 0; mi < MR; mi++) {
                #pragma unroll
                for (int ni = 0; ni < NR; ni++)
                    acc[mi][ni] = __builtin_amdgcn_mfma_f32_16x16x32_bf16(af[mi], bfr[ni], acc[mi][ni], 0, 0, 0);
            }
            asm volatile("s_waitcnt vmcnt(0)" ::: "memory");
            __builtin_amdgcn_s_barrier();
            cur ^= 1;
        }
    } else {
        // fallback (KD=3): reg-staged, padded LDS, scalar guarded loads
        __shared__ __align__(16) unsigned short As[TM * 40];
        __shared__ __align__(16) unsigned short Bs[TN * 40];
        for (int k0 = 0; k0 < KD; k0 += 32) {
            __syncthreads();
            #pragma unroll
            for (int u = t; u < TM * 4; u += 256) {
                const int m = u >> 2, c = (u & 3) * 8;
                #pragma unroll
                for (int j = 0; j < 8; j++) {
                    const int kk = k0 + c + j;
                    As[m * 40 + c + j] = (kk < KD) ? A[(size_t)(rb + m) * KD + kk] : (unsigned short)0;
                }
            }
            #pragma unroll
            for (int u = t; u < TN * 4; u += 256) {
                const int n = u >> 2, c = (u & 3) * 8;
                const int gn = cb + n;
                if (gn < NC) {
                    #pragma unroll
                    for (int j = 0; j < 8; j++) {
                        const int kk = k0 + c + j;
                        Bs[n * 40 + c + j] = (kk < KD) ? Bw[(size_t)gn * KD + kk] : (unsigned short)0;
                    }
                } else {
                    short8 z = {};
                    *reinterpret_cast<short8*>(&Bs[n * 40 + c]) = z;
                }
            }
            __syncthreads();
            short8 af[MR], bfr[NR];
            #pragma unroll
            for (int mi = 0; mi < MR; mi++)
                af[mi] = *reinterpret_cast<const short8*>(&As[(wr + mi * 16 + fr) * 40 + fq]);
            #pragma unroll
            for (int ni = 0; ni < NR; ni++)
                bfr[ni] = *reinterpret_cast<const short8*>(&Bs[(wc + ni * 16 + fr) * 40 + fq]);
            #pragma unroll
            for (int mi = 0; mi < MR; mi++) {
                #pragma unroll
                for (int ni = 0; ni < NR; ni++)
                    acc[mi][ni] = __builtin_amdgcn_mfma_f32_16x16x32_bf16(af[mi], bfr[ni], acc[mi][ni], 0, 0, 0);
            }
        }
    }
    const int cr = (lane >> 4) * 4, cc = lane & 15;
    if constexpr (POOL) {
        const int bidx = rb >> 10;
        #pragma unroll
        for (int ni = 0; ni < NR; ni++) {
            const int col = cb + wc + ni * 16 + cc;
            const float gm = gamma[col] * BN_SCALE, bt = beta[col];
            float sm = 0.f, mxv = -3e38f;
            #pragma unroll
            for (int mi = 0; mi < MR; mi++) {
                #pragma unroll
                for (int r = 0; r < 4; r++) {
                    float v = acc[mi][ni][r] * gm + bt;
                    v = v >= 0.f ? v : 0.2f * v;
                    sm += v; mxv = fmaxf(mxv, v);
                }
            }
            sm += __shfl_xor(sm, 16, 64);
            sm += __shfl_xor(sm, 32, 64);
            mxv = fmaxf(mxv, __shfl_xor(mxv, 16, 64));
            mxv = fmaxf(mxv, __shfl_xor(mxv, 32, 64));
            if (lane < 16) {
                atomicAdd(&psum[bidx * 1024 + col], sm);
                unsigned tb = __float_as_uint(mxv);
                tb = (tb & 0x80000000u) ? ~tb : (tb | 0x80000000u);
                atomicMax(&pmaxu[bidx * 1024 + col], tb);
            }
        }
    } else {
        #pragma unroll
        for (int mi = 0; mi < MR; mi++) {
            #pragma unroll
            for (int ni = 0; ni < NR; ni++) {
                #pragma unroll
                for (int r = 0; r < 4; r++) {
                    const int row = rb + wr + mi * 16 + cr + r;
                    const int col = cb + wc + ni * 16 + cc;
                    if (col < NC) {
                        float v = acc[mi][ni][r] + (bias ? bias[col] : 0.f);
                        if (col < scale_cols) v *= qs;
                        if (resid) v += resid[(size_t)row * NC + col];
                        if (gamma) {
                            v = v * (gamma[col] * BN_SCALE) + beta[col];
                            v = v >= 0.f ? v : 0.2f * v;
                        }
                        Cout[(size_t)row * NC + col] = v;
                        if (obf) obf[(size_t)row * NC + col] = F2BF(v);
                    }
                }
            }
        }
    }
}

// ---------------------------------------------------------------- EdgeConv epilogue (fp32 out + bf16 copy)
template<int CO>
__global__ __launch_bounds__(256) void k_edgemax(const float* __restrict__ yz,
                                                 const int* __restrict__ idx,
                                                 const float* __restrict__ g,
                                                 const float* __restrict__ bb,
                                                 float* __restrict__ out,
                                                 unsigned short* __restrict__ outb) {
    constexpr int TPP = CO / 4;
    constexpr int PPB = 256 / TPP;
    const int t = threadIdx.x;
    const int p = t / TPP;
    const int cw = (t % TPP) * 4;
    const int i0 = blockIdx.x * PPB;
    const int bbase = (i0 >> 10) << 10;
    __shared__ int sidx[PPB][K_];
    for (int u = t; u < PPB * K_; u += 256) {
        int pp = u / K_, kk = u - pp * K_;
        sidx[pp][kk] = idx[(size_t)(i0 + pp) * K_ + kk];
    }
    __syncthreads();
    const int ig = i0 + p;
    float4 m = {-3e38f, -3e38f, -3e38f, -3e38f};
    #pragma unroll 4
    for (int k = 0; k < K_; k++) {
        const int jg = bbase + sidx[p][k];
        const float4 yv = *reinterpret_cast<const float4*>(&yz[(size_t)jg * 2 * CO + cw]);
        m.x = fmaxf(m.x, yv.x); m.y = fmaxf(m.y, yv.y);
        m.z = fmaxf(m.z, yv.z); m.w = fmaxf(m.w, yv.w);
    }
    const float4 yi = *reinterpret_cast<const float4*>(&yz[(size_t)ig * 2 * CO + cw]);
    const float4 zi = *reinterpret_cast<const float4*>(&yz[(size_t)ig * 2 * CO + CO + cw]);
    const float4 gv = *reinterpret_cast<const float4*>(&g[cw]);
    const float4 bv = *reinterpret_cast<const float4*>(&bb[cw]);
    float vals[4] = {m.x - yi.x + zi.x, m.y - yi.y + zi.y,
                     m.z - yi.z + zi.z, m.w - yi.w + zi.w};
    float gs[4] = {gv.x, gv.y, gv.z, gv.w};
    float bs[4] = {bv.x, bv.y, bv.z, bv.w};
    float4 o;
    float* op = &o.x;
    #pragma unroll
    for (int j = 0; j < 4; j++) {
        float h = vals[j] * (gs[j] * BN_SCALE) + bs[j];
        op[j] = h >= 0.f ? h : 0.2f * h;
    }
    *reinterpret_cast<float4*>(&out[(size_t)ig * CO + cw]) = o;
    #pragma unroll
    for (int j = 0; j < 4; j++) outb[(size_t)ig * CO + cw + j] = F2BF(op[j]);
}

// ---------------------------------------------------------------- attention (fp32 math, bf16 out)
template<int E>
__global__ __launch_bounds__(256) void k_attn(const float* __restrict__ qkv,
                                              unsigned short* __restrict__ o) {
    constexpr int H = 4, D = E / H, L = 8;
    const int n = blockIdx.x;
    const int t = threadIdx.x;
    const int h = t >> 6, lane = t & 63;
    __shared__ float sq[L][3 * E];
    __shared__ float so[L][E];
    for (int u = t; u < L * 3 * E; u += 256) {
        int l = u / (3 * E), r = u - l * (3 * E);
        sq[l][r] = qkv[(size_t)(l * N_ + n) * (3 * E) + r];
    }
    __syncthreads();
    const int l = lane >> 3, m = lane & 7;
    float s = 0.f;
    #pragma unroll 8
    for (int dd = 0; dd < D; dd++)
        s += sq[l][h * D + dd] * sq[m][E + h * D + dd];
    float mx = s;
    #pragma unroll
    for (int st = 1; st < 8; st <<= 1) mx = fmaxf(mx, __shfl_xor(mx, st, 64));
    float e = expf(s - mx);
    float sum = e;
    #pragma unroll
    for (int st = 1; st < 8; st <<= 1) sum += __shfl_xor(sum, st, 64);
    const float p = e / sum;
    float pm[8];
    #pragma unroll
    for (int mm = 0; mm < 8; mm++) pm[mm] = __shfl(p, (lane & 56) | mm, 64);
    #pragma unroll
    for (int j = 0; j < D / 8; j++) {
        const int dd = m + 8 * j;
        float a = 0.f;
        #pragma unroll
        for (int mm = 0; mm < 8; mm++) a += pm[mm] * sq[mm][2 * E + h * D + dd];
        so[l][h * D + dd] = a;
    }
    __syncthreads();
    for (int u = t; u < L * E; u += 256) {
        int l2 = u / E, e2 = u - l2 * E;
        o[(size_t)(l2 * N_ + n) * E + e2] = F2BF(so[l2][e2]);
    }
}

// ---------------------------------------------------------------- FC head
// fc1 reads the pooled feat inline from pmaxu/psum (pool2 folded in).
__global__ __launch_bounds__(256) void k_fc1(const unsigned* __restrict__ pmaxu,
                                             const float* __restrict__ psum,
                                             const float* __restrict__ l1wT,
                                             const float* __restrict__ g6, const float* __restrict__ b6,
                                             float* __restrict__ f1) {
    int oc = blockIdx.x, b = blockIdx.y, t = threadIdx.x;
    __shared__ float fin[2048];
    __shared__ float ps[4][64];
    for (int u = t; u < 2048; u += 256) {
        float v;
        if (u < 1024) {
            unsigned tb = pmaxu[b * 1024 + u];
            unsigned bits = (tb & 0x80000000u) ? (tb & 0x7FFFFFFFu) : ~tb;
            v = __uint_as_float(bits);
        } else {
            v = psum[b * 1024 + (u - 1024)] * (1.f / 1024.f);
        }
        fin[u] = v;
    }
    __syncthreads();
    int ol = t & 63, kc = t >> 6;
    int o = oc * 64 + ol;
    float acc = 0.f;
    for (int c = kc * 512; c < kc * 512 + 512; c++) acc += fin[c] * l1wT[(size_t)c * 512 + o];
    ps[kc][ol] = acc;
    __syncthreads();
    if (t < 64) {
        int oo = oc * 64 + t;
        float a = ps[0][t] + ps[1][t] + ps[2][t] + ps[3][t];
        float h = a * (g6[oo] * BN_SCALE) + b6[oo];
        f1[b * 512 + oo] = h >= 0.f ? h : 0.2f * h;
    }
}

// fc2 + fc3 fused (one block per batch; f2 lives in LDS only)
__global__ __launch_bounds__(256) void k_fc23(const float* __restrict__ f1, const float* __restrict__ l2wT,
                                              const float* __restrict__ l2b,
                                              const float* __restrict__ g7, const float* __restrict__ b7,
                                              const float* __restrict__ l3wT, const float* __restrict__ l3b,
                                              void* __restrict__ out, const int* __restrict__ flag) {
    int b = blockIdx.x, t = threadIdx.x;
    __shared__ float fin[512];
    __shared__ float f2s[256];
    for (int u = t; u < 512; u += 256) fin[u] = f1[b * 512 + u];
    __syncthreads();
    {
        float acc = 0.f;
        for (int c = 0; c < 512; c++) acc += fin[c] * l2wT[(size_t)c * 256 + t];
        acc += l2b[t];
        float h = acc * (g7[t] * BN_SCALE) + b7[t];
        f2s[t] = h >= 0.f ? h : 0.2f * h;
    }
    __syncthreads();
    if (t < 40) {
        float acc = 0.f;
        for (int c = 0; c < 256; c++) acc += f2s[c] * l3wT[(size_t)c * 40 + t];
        acc += l3b[t];
        if (*flag) ((__hip_bfloat16*)out)[b * 40 + t] = __float2bfloat16(acc);
        else       ((float*)out)[b * 40 + t] = acc;
    }
}

// ================================================================ host
extern "C" void kernel_launch(void* const* d_in, const int* in_sizes, int n_in,
                              void* d_out, int out_size, void* d_ws, size_t ws_size,
                              hipStream_t stream) {
    auto us = [&](int i) { return (const unsigned short*)d_in[i]; };

    float* ws = (float*)d_ws;
    size_t off = 0;
    auto A = [&](size_t n) { float* p = ws + off; off += (n + 3) & ~(size_t)3; return p; };
    auto AU = [&](size_t n) { return (unsigned short*)A((n + 1) / 2); };
    float* xf0  = A((size_t)BN_ * 3);
    float* x1   = A((size_t)BN_ * 64);
    float* x2   = A((size_t)BN_ * 64);
    float* x3   = A((size_t)BN_ * 128);
    float* x4   = A((size_t)BN_ * 256);
    float* f1   = A(8 * 512);
    float* xx   = A(BN_);
    int*   idx  = (int*)A((size_t)BN_ * K_);
    int*   flag = (int*)A(4);
    float* qkvw = A((size_t)BN_ * 768);   // qkv / yz / knn-split scratch
    // bf16 activation copies
    unsigned short* xf0b = AU((size_t)BN_ * 3);
    unsigned short* x1b  = AU((size_t)BN_ * 64);
    unsigned short* x2b  = AU((size_t)BN_ * 64);
    unsigned short* x3b  = AU((size_t)BN_ * 128);
    unsigned short* x4b  = AU((size_t)BN_ * 256);
    unsigned short* owb  = AU((size_t)BN_ * 256);
    // pooled reductions (conv5 fused epilogue) -- contiguous, zeroed by k_prep
    unsigned* pmaxu = (unsigned*)A(8 * 1024);
    float*    psum  = A(8 * 1024);
    // bf16 weights (n,k) layouts
    unsigned short* w1yzb = AU(128 * 3);
    unsigned short* w2yzb = AU(128 * 64);
    unsigned short* w3yzb = AU(256 * 64);
    unsigned short* w4yzb = AU(512 * 128);
    unsigned short* a1wib = AU(192 * 64);  unsigned short* a1wob = AU(64 * 64);
    unsigned short* a2wib = AU(192 * 64);  unsigned short* a2wob = AU(64 * 64);
    unsigned short* a3wib = AU(384 * 128); unsigned short* a3wob = AU(128 * 128);
    unsigned short* a4wib = AU(768 * 256); unsigned short* a4wob = AU(256 * 256);
    unsigned short* w5b   = AU(1024 * 512);
    // fp32 fc weights (transposed)
    float* l1wT  = A(2048 * 512);
    float* l2wT  = A(512 * 256);
    float* l3wT  = A(256 * 40);
    // converted vectors (fp32)
    float* g1f = A(64);   float* b1f = A(64);
    float* g2f = A(64);   float* b2f = A(64);
    float* g3f = A(128);  float* b3f = A(128);
    float* g4f = A(256);  float* b4f = A(256);
    float* bi1 = A(192);  float* bo1 = A(64);
    float* bi2 = A(192);  float* bo2 = A(64);
    float* bi3 = A(384);  float* bo3 = A(128);
    float* bi4 = A(768);  float* bo4 = A(256);
    float* g5f = A(1024); float* b5f = A(1024);
    float* g6f = A(512);  float* b6f = A(512);
    float* l2bf = A(256);
    float* g7f = A(256);  float* b7f = A(256);
    float* l3bf = A(40);

    // knn split buffers alias qkvw (dead during the kNN phase of each layer)
    unsigned short* xa = (unsigned short*)qkvw;
    unsigned short* xb = (unsigned short*)qkvw + (size_t)BN_ * 512;

    k_detect<<<1, 1, 0, stream>>>(us(2), us(5), us(8), us(11), us(30), us(33), us(37), flag);

    TList tl; int nb = 0; int k = 0;
    auto add = [&](int i, void* dst, int O, int I, int mode) {
        tl.p[k].src = d_in[i]; tl.p[k].dst = dst; tl.p[k].O = O; tl.p[k].I = I;
        tl.p[k].blk0 = nb; tl.p[k].mode = mode;
        nb += (O * I + 255) / 256; k++;
    };
    add(0,  xf0,   BN_ * 3, 1, 0);
    add(0,  xf0b,  BN_ * 3, 1, 2);
    add(0,  pmaxu, 16384, 1, 4);      // zero pmaxu+psum (contiguous)
    add(1,  w1yzb, 64, 6, 3);
    add(4,  w2yzb, 64, 128, 3);
    add(7,  w3yzb, 128, 128, 3);
    add(10, w4yzb, 256, 256, 3);
    add(13, a1wib, 192, 64, 2);
    add(15, a1wob, 64, 64, 2);
    add(17, a2wib, 192, 64, 2);
    add(19, a2wob, 64, 64, 2);
    add(21, a3wib, 384, 128, 2);
    add(23, a3wob, 128, 128, 2);
    add(25, a4wib, 768, 256, 2);
    add(27, a4wob, 256, 256, 2);
    add(29, w5b,   1024, 512, 2);
    add(2,  g1f, 64, 1, 0);   add(3,  b1f, 64, 1, 0);
    add(5,  g2f, 64, 1, 0);   add(6,  b2f, 64, 1, 0);
    add(8,  g3f, 128, 1, 0);  add(9,  b3f, 128, 1, 0);
    add(11, g4f, 256, 1, 0);  add(12, b4f, 256, 1, 0);
    add(14, bi1, 192, 1, 0);  add(16, bo1, 64, 1, 0);
    add(18, bi2, 192, 1, 0);  add(20, bo2, 64, 1, 0);
    add(22, bi3, 384, 1, 0);  add(24, bo3, 128, 1, 0);
    add(26, bi4, 768, 1, 0);  add(28, bo4, 256, 1, 0);
    add(30, g5f, 1024, 1, 0); add(31, b5f, 1024, 1, 0);
    add(33, g6f, 512, 1, 0);  add(34, b6f, 512, 1, 0);
    add(36, l2bf, 256, 1, 0);
    add(37, g7f, 256, 1, 0);  add(38, b7f, 256, 1, 0);
    add(40, l3bf, 40, 1, 0);
    k_prep<<<nb, 256, 0, stream>>>(tl, k, flag);

    // LDS-tiled transposes for the big fp32 FC weights (coalesced both sides)
    TrP tp1{d_in[32], l1wT, 512, 2048, 2048 / 32, 0};
    TrP tp2{d_in[35], l2wT, 256, 512,  512 / 32,  (2048 / 32) * (512 / 32)};
    TrP tp3{d_in[39], l3wT, 40,  256,  256 / 32,  tp2.blk0 + (512 / 32) * (256 / 32)};
    const int trblocks = tp3.blk0 + (256 / 32) * ((40 + 31) / 32);
    k_tr<<<trblocks, 256, 0, stream>>>(tp1, tp2, tp3, flag);

    float* yzb = qkvw;                 // fp32 yz scratch (after kNN phase)
    const dim3 knng(N_ / 32, 1, 8);    // 256 blocks = 1/CU
    const unsigned short* N0 = nullptr;
    unsigned* NU = nullptr; float* NF = nullptr;

    // layer 1  (C=3 -> 64)
    k_split<3, 32><<<(BN_ * 32) / 256 + 32, 256, 0, stream>>>(xf0, xa, xb, xx);
    k_knn<32><<<knng, 512, 0, stream>>>(xa, xb, xx, idx);
    k_gemmb<3, 128, 64, 64><<<dim3(128, 2), 256, 0, stream>>>(xf0b, N0, N0, N0, w1yzb, nullptr, nullptr, yzb, 0, 1.f, nullptr, nullptr, nullptr, NU, NF);
    k_edgemax<64><<<BN_ / 16, 256, 0, stream>>>(yzb, idx, g1f, b1f, x1, x1b);
    k_gemmb<64, 192, 64, 64><<<dim3(128, 3), 256, 0, stream>>>(x1b, N0, N0, N0, a1wib, bi1, nullptr, qkvw, 64, 0.25f, nullptr, nullptr, nullptr, NU, NF);
    k_attn<64><<<N_, 256, 0, stream>>>(qkvw, owb);
    k_gemmb<64, 64, 64, 64><<<dim3(128, 1), 256, 0, stream>>>(owb, N0, N0, N0, a1wob, bo1, x1, x1, 0, 1.f, nullptr, nullptr, x1b, NU, NF);

    // layer 2  (C=64 -> 64)
    k_split<64, 256><<<(BN_ * 256) / 256 + 32, 256, 0, stream>>>(x1, xa, xb, xx);
    k_knn<256><<<knng, 512, 0, stream>>>(xa, xb, xx, idx);
    k_gemmb<64, 128, 64, 64><<<dim3(128, 2), 256, 0, stream>>>(x1b, N0, N0, N0, w2yzb, nullptr, nullptr, yzb, 0, 1.f, nullptr, nullptr, nullptr, NU, NF);
    k_edgemax<64><<<BN_ / 16, 256, 0, stream>>>(yzb, idx, g2f, b2f, x2, x2b);
    k_gemmb<64, 192, 64, 64><<<dim3(128, 3), 256, 0, stream>>>(x2b, N0, N0, N0, a2wib, bi2, nullptr, qkvw, 64, 0.25f, nullptr, nullptr, nullptr, NU, NF);
    k_attn<64><<<N_, 256, 0, stream>>>(qkvw, owb);
    k_gemmb<64, 64, 64, 64><<<dim3(128, 1), 256, 0, stream>>>(owb, N0, N0, N0, a2wob, bo2, x2, x2, 0, 1.f, nullptr, nullptr, x2b, NU, NF);

    // layer 3  (C=64 -> 128)
    k_split<64, 256><<<(BN_ * 256) / 256 + 32, 256, 0, stream>>>(x2, xa, xb, xx);
    k_knn<256><<<knng, 512, 0, stream>>>(xa, xb, xx, idx);
    k_gemmb<64, 256, 64, 64><<<dim3(128, 4), 256, 0, stream>>>(x2b, N0, N0, N0, w3yzb, nullptr, nullptr, yzb, 0, 1.f, nullptr, nullptr, nullptr, NU, NF);
    k_edgemax<128><<<BN_ / 8, 256, 0, stream>>>(yzb, idx, g3f, b3f, x3, x3b);
    k_gemmb<128, 384, 64, 128><<<dim3(128, 3), 256, 0, stream>>>(x3b, N0, N0, N0, a3wib, bi3, nullptr, qkvw, 128, 0.17677669529663687f, nullptr, nullptr, nullptr, NU, NF);
    k_attn<128><<<N_, 256, 0, stream>>>(qkvw, owb);
    k_gemmb<128, 128, 64, 64><<<dim3(128, 2), 256, 0, stream>>>(owb, N0, N0, N0, a3wob, bo3, x3, x3, 0, 1.f, nullptr, nullptr, x3b, NU, NF);

    // layer 4  (C=128 -> 256)
    k_split<128, 512><<<(BN_ * 512) / 256 + 32, 256, 0, stream>>>(x3, xa, xb, xx);
    k_knn<512><<<knng, 512, 0, stream>>>(xa, xb, xx, idx);
    k_gemmb<128, 512, 128, 128><<<dim3(64, 4), 256, 0, stream>>>(x3b, N0, N0, N0, w4yzb, nullptr, nullptr, yzb, 0, 1.f, nullptr, nullptr, nullptr, NU, NF);
    k_edgemax<256><<<BN_ / 4, 256, 0, stream>>>(yzb, idx, g4f, b4f, x4, x4b);
    k_gemmb<256, 768, 128, 128><<<dim3(64, 6), 256, 0, stream>>>(x4b, N0, N0, N0, a4wib, bi4, nullptr, qkvw, 256, 0.125f, nullptr, nullptr, nullptr, NU, NF);
    k_attn<256><<<N_, 256, 0, stream>>>(qkvw, owb);
    k_gemmb<256, 256, 64, 128><<<dim3(128, 2), 256, 0, stream>>>(owb, N0, N0, N0, a4wob, bo4, x4, x4, 0, 1.f, nullptr, nullptr, x4b, NU, NF);

    // head: conv5 with fused concat-A and fused pooling epilogue
    k_gemmb<512, 1024, 128, 128, true, true><<<dim3(64, 8), 256, 0, stream>>>(
        x1b, x2b, x3b, x4b, w5b, nullptr, nullptr, nullptr, 0, 1.f, g5f, b5f, nullptr, pmaxu, psum);
    k_fc1<<<dim3(8, 8), 256, 0, stream>>>(pmaxu, psum, l1wT, g6f, b6f, f1);
    k_fc23<<<8, 256, 0, stream>>>(f1, l2wT, l2bf, g7f, b7f, l3wT, l3bf, d_out, flag);
}

// Round 7
// 597.733 us; speedup vs baseline: 1.1263x; 1.0768x over previous
//
#include <hip/hip_runtime.h>
#include <hip/hip_bf16.h>

#define B_ 8
#define N_ 1024
#define K_ 20
#define BN_ (B_*N_)

#define BN_SCALE 0.9999950000374997f

typedef __attribute__((ext_vector_type(8))) short short8;
typedef __attribute__((ext_vector_type(4))) float f32x4;

__device__ __forceinline__ float US2F(unsigned short u) {
    union { unsigned u; float f; } c; c.u = ((unsigned)u) << 16; return c.f;
}
__device__ __forceinline__ unsigned short F2BF(float f) {   // RNE fp32->bf16
    union { float f; unsigned u; } c; c.f = f;
    unsigned r = c.u + 0x7FFF + ((c.u >> 16) & 1);
    return (unsigned short)(r >> 16);
}

// async global->LDS 16B DMA: LDS dest = wave-uniform base + lane*16 (linear);
// global source is per-lane (pre-swizzled there when a swizzled layout is wanted).
__device__ __forceinline__ void ldsld16(const unsigned short* g, unsigned short* l) {
    __builtin_amdgcn_global_load_lds(
        (const __attribute__((address_space(1))) void*)g,
        (__attribute__((address_space(3))) void*)l, 16, 0, 0);
}

// ---------------------------------------------------------------- dtype detect
__global__ void k_detect(const unsigned short* g1, const unsigned short* g2,
                         const unsigned short* g3, const unsigned short* g4,
                         const unsigned short* g5, const unsigned short* g6,
                         const unsigned short* g7, int* flag) {
    const unsigned short* gs[7] = {g1, g2, g3, g4, g5, g6, g7};
    int cnt = 0;
    for (int i = 0; i < 7; i++) {
        float v = US2F(gs[i][0]);
        if (v > 0.5f && v < 1.5f) cnt++;
    }
    *flag = (cnt >= 4) ? 1 : 0;   // 1 = bf16 inputs, 0 = fp32 inputs
}

// ---------------------------------------------------------------- prep
// mode 0: fp32 copy (I==1 -> contiguous).  mode 2: bf16 copy.
// mode 3: edge pair -> bf16 (2O, C).  mode 4: zero-fill fp32 (dst only).
struct TPar { const void* src; void* dst; int O, I, blk0, mode; };
struct TList { TPar p[44]; };

__global__ __launch_bounds__(256) void k_prep(TList tl, int nent, const int* flag) {
    const int isbf = *flag;
    int blk = blockIdx.x;
    int wi = 0;
    for (int j = nent - 1; j >= 0; j--) { if (blk >= tl.p[j].blk0) { wi = j; break; } }
    const TPar p = tl.p[wi];
    int e = (blk - p.blk0) * 256 + threadIdx.x;
    int n = p.O * p.I;
    if (e >= n) return;
    if (p.mode == 4) { ((float*)p.dst)[e] = 0.f; return; }
    int o = e / p.I, i = e - o * p.I;
    float v = isbf ? US2F(((const unsigned short*)p.src)[e])
                   : ((const float*)p.src)[e];
    if (p.mode == 0) {
        ((float*)p.dst)[(size_t)i * p.O + o] = v;
    } else if (p.mode == 2) {
        ((unsigned short*)p.dst)[e] = F2BF(v);
    } else {
        const int C = p.I >> 1;
        if (i < C) ((unsigned short*)p.dst)[(size_t)o * C + i] = F2BF(v);
        else       ((unsigned short*)p.dst)[(size_t)(p.O + o) * C + (i - C)] = F2BF(v);
    }
}

// ---------------------------------------------------------------- LDS-tiled transpose
// (O,I) row-major -> (I,O).  32x32 tiles, coalesced read AND write.
struct TrP { const void* src; float* dst; int O, I, bx, blk0; };

__global__ __launch_bounds__(256) void k_tr(TrP p0, TrP p1, TrP p2, const int* flag) {
    const int isbf = *flag;
    TrP p = p0;
    int blk = blockIdx.x;
    if (blk >= p2.blk0) p = p2; else if (blk >= p1.blk0) p = p1;
    blk -= p.blk0;
    const int tx = threadIdx.x & 31, ty = threadIdx.x >> 5;   // 32 x 8
    const int bi = blk % p.bx, bo = blk / p.bx;
    const int i0 = bi * 32, o0 = bo * 32;
    __shared__ float s[32][33];
    #pragma unroll
    for (int r = 0; r < 4; r++) {
        const int o = o0 + ty + r * 8, i = i0 + tx;
        if (o < p.O && i < p.I) {
            const size_t e = (size_t)o * p.I + i;
            s[ty + r * 8][tx] = isbf ? US2F(((const unsigned short*)p.src)[e])
                                     : ((const float*)p.src)[e];
        }
    }
    __syncthreads();
    #pragma unroll
    for (int r = 0; r < 4; r++) {
        const int i = i0 + ty + r * 8, o = o0 + tx;
        if (i < p.I && o < p.O) p.dst[(size_t)i * p.O + o] = s[tx][ty + r * 8];
    }
}

// ---------------------------------------------------------------- kNN split + norms (fused)
// split blocks: x (fp32) -> augmented bf16 rows (exact-split): xa=[hi,lo,hi,lo],
// xb=[hi,hi,lo,lo], zero-padded to KP.  Trailing 32 blocks: xx[i] = |x_i|^2.
template<int C, int KP>
__global__ __launch_bounds__(256) void k_split(const float* __restrict__ x,
                                               unsigned short* __restrict__ xa,
                                               unsigned short* __restrict__ xb,
                                               float* __restrict__ xx) {
    constexpr int NB = (BN_ * KP) / 256;
    if (blockIdx.x >= NB) {   // norms
        const int i = (blockIdx.x - NB) * 256 + threadIdx.x;
        if (i >= BN_) return;
        const float* p = x + (size_t)i * C;
        float s = 0.f;
        #pragma unroll
        for (int c = 0; c < C; c++) s += p[c] * p[c];
        xx[i] = s;
        return;
    }
    const int e = blockIdx.x * 256 + threadIdx.x;
    const int i = e / KP, p = e - i * KP;
    unsigned short va = 0, vb = 0;
    if (p < 4 * C) {
        const int seg = p / C, c = p - seg * C;
        const float v = x[(size_t)i * C + c];
        const unsigned short h = F2BF(v);
        const unsigned short l = F2BF(v - US2F(h));
        va = (seg & 1) ? l : h;           // hi,lo,hi,lo
        vb = (seg < 2) ? h : l;           // hi,hi,lo,lo
    }
    xa[e] = va;
    xb[e] = vb;
}

// ---------------------------------------------------------------- kNN phase 1 (MFMA):
// pd[b][i][j] = 2*dot(xa_i, xb_j) - xx_j.  128x128 tile, 4 waves x 64x64
// quadrant.  global_load_lds dwordx4 into linear [128][32] LDS; 16B-granule
// XOR swizzle applied on the GLOBAL source; 2-phase double-buffer.
// NOTE (R5/R6 post-mortem): the fused pdm+sel k_knn (scores kept in 151 KB
// LDS, 1 block/CU) measured 70-79 us/layer vs ~this path's total -- the
// selection phase needs k_sel's 32-waves/CU TLP.  Keep the two-kernel form.
template<int KP, int TM, int TN>
__global__ __launch_bounds__(256) void k_pdm(const unsigned short* __restrict__ xa,
                                             const unsigned short* __restrict__ xb,
                                             const float* __restrict__ xx,
                                             float* __restrict__ pd) {
    const int b = blockIdx.z;
    const int rb = blockIdx.x * TM, cb = blockIdx.y * TN;
    const unsigned short* Ab = xa + (size_t)b * N_ * KP;
    const unsigned short* Bb = xb + (size_t)b * N_ * KP;
    const float* xxb = xx + (size_t)b * N_;
    const int t = threadIdx.x;
    __shared__ __align__(16) unsigned short As[2][TM * 32];
    __shared__ __align__(16) unsigned short Bs[2][TN * 32];
    const int w = t >> 6, lane = t & 63;
    constexpr int QR = TM / 2, QC = TN / 2;
    constexpr int MR = QR / 16, NR = QC / 16;
    const int wr = (w & 1) * QR, wc = (w >> 1) * QC;
    const int fr = lane & 15, q = lane >> 4;
    f32x4 acc[MR][NR] = {};

    auto STAGE = [&](int buf, int k0) {
        constexpr int AT = TM * 4;
        #pragma unroll
        for (int R = 0; R < (AT + 255) / 256; R++) {
            const int G = t + R * 256;
            if (AT >= (R + 1) * 256 || G < AT) {
                const int m = G >> 2, gs = (G & 3) ^ ((m >> 1) & 3);
                ldsld16(&Ab[(size_t)(rb + m) * KP + k0 + gs * 8], &As[buf][w * 512 + R * 2048]);
            }
        }
        constexpr int BT = TN * 4;
        #pragma unroll
        for (int R = 0; R < (BT + 255) / 256; R++) {
            const int G = t + R * 256;
            if (BT >= (R + 1) * 256 || G < BT) {
                const int n = G >> 2, gs = (G & 3) ^ ((n >> 1) & 3);
                ldsld16(&Bb[(size_t)(cb + n) * KP + k0 + gs * 8], &Bs[buf][w * 512 + R * 2048]);
            }
        }
    };

    constexpr int NT = KP / 32;
    STAGE(0, 0);
    asm volatile("s_waitcnt vmcnt(0)" ::: "memory");
    __builtin_amdgcn_s_barrier();
    int cur = 0;
    for (int ts = 0; ts < NT; ++ts) {
        if (ts + 1 < NT) STAGE(cur ^ 1, (ts + 1) * 32);
        short8 af[MR], bfr[NR];
        #pragma unroll
        for (int mi = 0; mi < MR; mi++) {
            const int r = wr + mi * 16 + fr;
            af[mi] = *reinterpret_cast<const short8*>(&As[cur][r * 32 + ((q ^ ((r >> 1) & 3)) << 3)]);
        }
        #pragma unroll
        for (int ni = 0; ni < NR; ni++) {
            const int r = wc + ni * 16 + fr;
            bfr[ni] = *reinterpret_cast<const short8*>(&Bs[cur][r * 32 + ((q ^ ((r >> 1) & 3)) << 3)]);
        }
        #pragma unroll
        for (int mi = 0; mi < MR; mi++) {
            #pragma unroll
            for (int ni = 0; ni < NR; ni++)
                acc[mi][ni] = __builtin_amdgcn_mfma_f32_16x16x32_bf16(af[mi], bfr[ni], acc[mi][ni], 0, 0, 0);
        }
        asm volatile("s_waitcnt vmcnt(0)" ::: "memory");
        __builtin_amdgcn_s_barrier();
        cur ^= 1;
    }
    float* pdb = pd + (size_t)b * N_ * N_;
    const int cr = (lane >> 4) * 4, cc = lane & 15;
    #pragma unroll
    for (int mi = 0; mi < MR; mi++) {
        #pragma unroll
        for (int ni = 0; ni < NR; ni++) {
            #pragma unroll
            for (int r = 0; r < 4; r++) {
                const int row = rb + wr + mi * 16 + cr + r;
                const int col = cb + wc + ni * 16 + cc;
                pdb[(size_t)row * N_ + col] = 2.f * acc[mi][ni][r] - xxb[col];
            }
        }
    }
}

// ---------------------------------------------------------------- kNN phase 2
// 32-bit key top-20: key = (ordered_bits & ~1023) | (1023 - j). Single-op
// v_max_u32 rounds.  Value compare precision 2^-14 rel.  2048 blocks ->
// 32 waves/CU: the serial 20-round chain is TLP-hidden (why this beats the
// fused-in-knn selection).
__global__ __launch_bounds__(256) void k_sel(const float* __restrict__ pd,
                                             int* __restrict__ idx) {
    const int w = threadIdx.x >> 6, lane = threadIdx.x & 63;
    const int i = blockIdx.x * 4 + w;          // 0..8191
    const int b = i >> 10;
    const float* row = pd + (size_t)b * N_ * N_ + (size_t)(i & 1023) * N_;
    unsigned key[16];
    #pragma unroll
    for (int q = 0; q < 16; q++) {
        const int j = q * 64 + lane;
        unsigned bits = __float_as_uint(row[j]);
        bits = (bits & 0x80000000u) ? ~bits : (bits | 0x80000000u);
        key[q] = (bits & 0xFFFFFC00u) | (unsigned)(N_ - 1 - j);
    }
    int myj = 0;
    for (int kk = 0; kk < K_; kk++) {
        unsigned m = key[0];
        #pragma unroll
        for (int u = 1; u < 16; u++) m = key[u] > m ? key[u] : m;
        #pragma unroll
        for (int s = 1; s < 64; s <<= 1) {
            unsigned o = (unsigned)__shfl_xor((int)m, s, 64);
            m = o > m ? o : m;
        }
        const int j = N_ - 1 - (int)(m & 1023u);
        if (lane == kk) myj = j;
        #pragma unroll
        for (int u = 0; u < 16; u++)
            if (key[u] == m) key[u] = 0u;      // below any plausible real key
    }
    if (lane < K_) idx[(size_t)i * K_ + lane] = myj;
}

// ---------------------------------------------------------------- MFMA bf16 GEMM
// C[8192][NC] = A[8192][KD] @ Bw^T.  KD%32==0: global_load_lds dwordx4 into
// linear [T][32] LDS, source-side 16B-granule XOR swizzle, 2-phase dbuf.
// CATA: A is the virtual concat [x1b|x2b|x3b|x4b] (KD=512); per-k0 source
// select (region boundaries 64/128/256 are multiples of the 32-col k-step).
// POOL: no C write; fused column max+sum over rows via wave reduce + atomics
// (pmaxu = ordered-uint max, psum = f32 add), for the global pooling head.
template<int KD, int NC, int TM, int TN, bool CATA = false, bool POOL = false>
__global__ __launch_bounds__(256) void k_gemmb(const unsigned short* __restrict__ A,
                                               const unsigned short* __restrict__ A2,
                                               const unsigned short* __restrict__ A3,
                                               const unsigned short* __restrict__ A4,
                                               const unsigned short* __restrict__ Bw,
                                               const float* __restrict__ bias,
                                               const float* __restrict__ resid,
                                               float* __restrict__ Cout,
                                               int scale_cols, float qs,
                                               const float* __restrict__ gamma,
                                               const float* __restrict__ beta,
                                               unsigned short* __restrict__ obf,
                                               unsigned* __restrict__ pmaxu,
                                               float* __restrict__ psum) {
    const int t = threadIdx.x;
    const int rb = blockIdx.x * TM, cb = blockIdx.y * TN;
    const int w = t >> 6, lane = t & 63;
    constexpr int QR = TM / 2, QC = TN / 2;
    constexpr int MR = QR / 16, NR = QC / 16;
    const int wr = (w & 1) * QR, wc = (w >> 1) * QC;
    const int fr = lane & 15, q = lane >> 4, fq = q * 8;
    f32x4 acc[MR][NR] = {};
    if constexpr (KD % 32 == 0) {
        __shared__ __align__(16) unsigned short As[2][TM * 32];
        __shared__ __align__(16) unsigned short Bs[2][TN * 32];
        auto STAGE = [&](int buf, int k0) {
            const unsigned short* Asrc = A; int AC = KD, ac0 = k0;
            if constexpr (CATA) {
                if (k0 >= 256)      { Asrc = A4; AC = 256; ac0 = k0 - 256; }
                else if (k0 >= 128) { Asrc = A3; AC = 128; ac0 = k0 - 128; }
                else if (k0 >= 64)  { Asrc = A2; AC = 64;  ac0 = k0 - 64; }
                else                { Asrc = A;  AC = 64;  ac0 = k0; }
            }
            constexpr int AT = TM * 4;
            #pragma unroll
            for (int R = 0; R < (AT + 255) / 256; R++) {
                const int G = t + R * 256;
                if (AT >= (R + 1) * 256 || G < AT) {
                    const int m = G >> 2, gs = (G & 3) ^ ((m >> 1) & 3);
                    ldsld16(&Asrc[(size_t)(rb + m) * AC + ac0 + gs * 8], &As[buf][w * 512 + R * 2048]);
                }
            }
            constexpr int BT = TN * 4;
            #pragma unroll
            for (int R = 0; R < (BT + 255) / 256; R++) {
                const int G = t + R * 256;
                if (BT >= (R + 1) * 256 || G < BT) {
                    const int n = G >> 2, gs = (G & 3) ^ ((n >> 1) & 3);
                    ldsld16(&Bw[(size_t)(cb + n) * KD + k0 + gs * 8], &Bs[buf][w * 512 + R * 2048]);
                }
            }
        };
        constexpr int NT = KD / 32;
        STAGE(0, 0);
        asm volatile("s_waitcnt vmcnt(0)" ::: "memory");
        __builtin_amdgcn_s_barrier();
        int cur = 0;
        for (int ts = 0; ts < NT; ++ts) {
            if (ts + 1 < NT) STAGE(cur ^ 1, (ts + 1) * 32);
            short8 af[MR], bfr[NR];
            #pragma unroll
            for (int mi = 0; mi < MR; mi++) {
                const int r = wr + mi * 16 + fr;
                af[mi] = *reinterpret_cast<const short8*>(&As[cur][r * 32 + ((q ^ ((r >> 1) & 3)) << 3)]);
            }
            #pragma unroll
            for (int ni = 0; ni < NR; ni++) {
                const int r = wc + ni * 16 + fr;
                bfr[ni] = *reinterpret_cast<const short8*>(&Bs[cur][r * 32 + ((q ^ ((r >> 1) & 3)) << 3)]);
            }
            #pragma unroll
            for (int mi = 0; mi < MR; mi++) {
                #pragma unroll
                for (int ni = 0; ni < NR; ni++)
                    acc[mi][ni] = __builtin_amdgcn_mfma_f32_16x16x32_bf16(af[mi], bfr[ni], acc[mi][ni], 0, 0, 0);
            }
            asm volatile("s_waitcnt vmcnt(0)" ::: "memory");
            __builtin_amdgcn_s_barrier();
            cur ^= 1;
        }
    } else {
        // fallback (KD=3): reg-staged, padded LDS, scalar guarded loads
        __shared__ __align__(16) unsigned short As[TM * 40];
        __shared__ __align__(16) unsigned short Bs[TN * 40];
        for (int k0 = 0; k0 < KD; k0 += 32) {
            __syncthreads();
            #pragma unroll
            for (int u = t; u < TM * 4; u += 256) {
                const int m = u >> 2, c = (u & 3) * 8;
                #pragma unroll
                for (int j = 0; j < 8; j++) {
                    const int kk = k0 + c + j;
                    As[m * 40 + c + j] = (kk < KD) ? A[(size_t)(rb + m) * KD + kk] : (unsigned short)0;
                }
            }
            #pragma unroll
            for (int u = t; u < TN * 4; u += 256) {
                const int n = u >> 2, c = (u & 3) * 8;
                const int gn = cb + n;
                if (gn < NC) {
                    #pragma unroll
                    for (int j = 0; j < 8; j++) {
                        const int kk = k0 + c + j;
                        Bs[n * 40 + c + j] = (kk < KD) ? Bw[(size_t)gn * KD + kk] : (unsigned short)0;
                    }
                } else {
                    short8 z = {};
                    *reinterpret_cast<short8*>(&Bs[n * 40 + c]) = z;
                }
            }
            __syncthreads();
            short8 af[MR], bfr[NR];
            #pragma unroll
            for (int mi = 0; mi < MR; mi++)
                af[mi] = *reinterpret_cast<const short8*>(&As[(wr + mi * 16 + fr) * 40 + fq]);
            #pragma unroll
            for (int ni = 0; ni < NR; ni++)
                bfr[ni] = *reinterpret_cast<const short8*>(&Bs[(wc + ni * 16 + fr) * 40 + fq]);
            #pragma unroll
            for (int mi = 0; mi < MR; mi++) {
                #pragma unroll
                for (int ni = 0; ni < NR; ni++)
                    acc[mi][ni] = __builtin_amdgcn_mfma_f32_16x16x32_bf16(af[mi], bfr[ni], acc[mi][ni], 0, 0, 0);
            }
        }
    }
    const int cr = (lane >> 4) * 4, cc = lane & 15;
    if constexpr (POOL) {
        const int bidx = rb >> 10;
        #pragma unroll
        for (int ni = 0; ni < NR; ni++) {
            const int col = cb + wc + ni * 16 + cc;
            const float gm = gamma[col] * BN_SCALE, bt = beta[col];
            float sm = 0.f, mxv = -3e38f;
            #pragma unroll
            for (int mi = 0; mi < MR; mi++) {
                #pragma unroll
                for (int r = 0; r < 4; r++) {
                    float v = acc[mi][ni][r] * gm + bt;
                    v = v >= 0.f ? v : 0.2f * v;
                    sm += v; mxv = fmaxf(mxv, v);
                }
            }
            sm += __shfl_xor(sm, 16, 64);
            sm += __shfl_xor(sm, 32, 64);
            mxv = fmaxf(mxv, __shfl_xor(mxv, 16, 64));
            mxv = fmaxf(mxv, __shfl_xor(mxv, 32, 64));
            if (lane < 16) {
                atomicAdd(&psum[bidx * 1024 + col], sm);
                unsigned tb = __float_as_uint(mxv);
                tb = (tb & 0x80000000u) ? ~tb : (tb | 0x80000000u);
                atomicMax(&pmaxu[bidx * 1024 + col], tb);
            }
        }
    } else {
        #pragma unroll
        for (int mi = 0; mi < MR; mi++) {
            #pragma unroll
            for (int ni = 0; ni < NR; ni++) {
                #pragma unroll
                for (int r = 0; r < 4; r++) {
                    const int row = rb + wr + mi * 16 + cr + r;
                    const int col = cb + wc + ni * 16 + cc;
                    if (col < NC) {
                        float v = acc[mi][ni][r] + (bias ? bias[col] : 0.f);
                        if (col < scale_cols) v *= qs;
                        if (resid) v += resid[(size_t)row * NC + col];
                        if (gamma) {
                            v = v * (gamma[col] * BN_SCALE) + beta[col];
                            v = v >= 0.f ? v : 0.2f * v;
                        }
                        Cout[(size_t)row * NC + col] = v;
                        if (obf) obf[(size_t)row * NC + col] = F2BF(v);
                    }
                }
            }
        }
    }
}

// ---------------------------------------------------------------- EdgeConv epilogue (fp32 out + bf16 copy)
template<int CO>
__global__ __launch_bounds__(256) void k_edgemax(const float* __restrict__ yz,
                                                 const int* __restrict__ idx,
                                                 const float* __restrict__ g,
                                                 const float* __restrict__ bb,
                                                 float* __restrict__ out,
                                                 unsigned short* __restrict__ outb) {
    constexpr int TPP = CO / 4;
    constexpr int PPB = 256 / TPP;
    const int t = threadIdx.x;
    const int p = t / TPP;
    const int cw = (t % TPP) * 4;
    const int i0 = blockIdx.x * PPB;
    const int bbase = (i0 >> 10) << 10;
    __shared__ int sidx[PPB][K_];
    for (int u = t; u < PPB * K_; u += 256) {
        int pp = u / K_, kk = u - pp * K_;
        sidx[pp][kk] = idx[(size_t)(i0 + pp) * K_ + kk];
    }
    __syncthreads();
    const int ig = i0 + p;
    float4 m = {-3e38f, -3e38f, -3e38f, -3e38f};
    #pragma unroll 4
    for (int k = 0; k < K_; k++) {
        const int jg = bbase + sidx[p][k];
        const float4 yv = *reinterpret_cast<const float4*>(&yz[(size_t)jg * 2 * CO + cw]);
        m.x = fmaxf(m.x, yv.x); m.y = fmaxf(m.y, yv.y);
        m.z = fmaxf(m.z, yv.z); m.w = fmaxf(m.w, yv.w);
    }
    const float4 yi = *reinterpret_cast<const float4*>(&yz[(size_t)ig * 2 * CO + cw]);
    const float4 zi = *reinterpret_cast<const float4*>(&yz[(size_t)ig * 2 * CO + CO + cw]);
    const float4 gv = *reinterpret_cast<const float4*>(&g[cw]);
    const float4 bv = *reinterpret_cast<const float4*>(&bb[cw]);
    float vals[4] = {m.x - yi.x + zi.x, m.y - yi.y + zi.y,
                     m.z - yi.z + zi.z, m.w - yi.w + zi.w};
    float gs[4] = {gv.x, gv.y, gv.z, gv.w};
    float bs[4] = {bv.x, bv.y, bv.z, bv.w};
    float4 o;
    float* op = &o.x;
    #pragma unroll
    for (int j = 0; j < 4; j++) {
        float h = vals[j] * (gs[j] * BN_SCALE) + bs[j];
        op[j] = h >= 0.f ? h : 0.2f * h;
    }
    *reinterpret_cast<float4*>(&out[(size_t)ig * CO + cw]) = o;
    #pragma unroll
    for (int j = 0; j < 4; j++) outb[(size_t)ig * CO + cw + j] = F2BF(op[j]);
}

// ---------------------------------------------------------------- attention (fp32 math, bf16 out)
template<int E>
__global__ __launch_bounds__(256) void k_attn(const float* __restrict__ qkv,
                                              unsigned short* __restrict__ o) {
    constexpr int H = 4, D = E / H, L = 8;
    const int n = blockIdx.x;
    const int t = threadIdx.x;
    const int h = t >> 6, lane = t & 63;
    __shared__ float sq[L][3 * E];
    __shared__ float so[L][E];
    for (int u = t; u < L * 3 * E; u += 256) {
        int l = u / (3 * E), r = u - l * (3 * E);
        sq[l][r] = qkv[(size_t)(l * N_ + n) * (3 * E) + r];
    }
    __syncthreads();
    const int l = lane >> 3, m = lane & 7;
    float s = 0.f;
    #pragma unroll 8
    for (int dd = 0; dd < D; dd++)
        s += sq[l][h * D + dd] * sq[m][E + h * D + dd];
    float mx = s;
    #pragma unroll
    for (int st = 1; st < 8; st <<= 1) mx = fmaxf(mx, __shfl_xor(mx, st, 64));
    float e = expf(s - mx);
    float sum = e;
    #pragma unroll
    for (int st = 1; st < 8; st <<= 1) sum += __shfl_xor(sum, st, 64);
    const float p = e / sum;
    float pm[8];
    #pragma unroll
    for (int mm = 0; mm < 8; mm++) pm[mm] = __shfl(p, (lane & 56) | mm, 64);
    #pragma unroll
    for (int j = 0; j < D / 8; j++) {
        const int dd = m + 8 * j;
        float a = 0.f;
        #pragma unroll
        for (int mm = 0; mm < 8; mm++) a += pm[mm] * sq[mm][2 * E + h * D + dd];
        so[l][h * D + dd] = a;
    }
    __syncthreads();
    for (int u = t; u < L * E; u += 256) {
        int l2 = u / E, e2 = u - l2 * E;
        o[(size_t)(l2 * N_ + n) * E + e2] = F2BF(so[l2][e2]);
    }
}

// ---------------------------------------------------------------- FC head
// fc1 reads the pooled feat inline from pmaxu/psum (pool2 folded in).
__global__ __launch_bounds__(256) void k_fc1(const unsigned* __restrict__ pmaxu,
                                             const float* __restrict__ psum,
                                             const float* __restrict__ l1wT,
                                             const float* __restrict__ g6, const float* __restrict__ b6,
                                             float* __restrict__ f1) {
    int oc = blockIdx.x, b = blockIdx.y, t = threadIdx.x;
    __shared__ float fin[2048];
    __shared__ float ps[4][64];
    for (int u = t; u < 2048; u += 256) {
        float v;
        if (u < 1024) {
            unsigned tb = pmaxu[b * 1024 + u];
            unsigned bits = (tb & 0x80000000u) ? (tb & 0x7FFFFFFFu) : ~tb;
            v = __uint_as_float(bits);
        } else {
            v = psum[b * 1024 + (u - 1024)] * (1.f / 1024.f);
        }
        fin[u] = v;
    }
    __syncthreads();
    int ol = t & 63, kc = t >> 6;
    int o = oc * 64 + ol;
    float acc = 0.f;
    for (int c = kc * 512; c < kc * 512 + 512; c++) acc += fin[c] * l1wT[(size_t)c * 512 + o];
    ps[kc][ol] = acc;
    __syncthreads();
    if (t < 64) {
        int oo = oc * 64 + t;
        float a = ps[0][t] + ps[1][t] + ps[2][t] + ps[3][t];
        float h = a * (g6[oo] * BN_SCALE) + b6[oo];
        f1[b * 512 + oo] = h >= 0.f ? h : 0.2f * h;
    }
}

// fc2 + fc3 fused (one block per batch; f2 lives in LDS only)
__global__ __launch_bounds__(256) void k_fc23(const float* __restrict__ f1, const float* __restrict__ l2wT,
                                              const float* __restrict__ l2b,
                                              const float* __restrict__ g7, const float* __restrict__ b7,
                                              const float* __restrict__ l3wT, const float* __restrict__ l3b,
                                              void* __restrict__ out, const int* __restrict__ flag) {
    int b = blockIdx.x, t = threadIdx.x;
    __shared__ float fin[512];
    __shared__ float f2s[256];
    for (int u = t; u < 512; u += 256) fin[u] = f1[b * 512 + u];
    __syncthreads();
    {
        float acc = 0.f;
        for (int c = 0; c < 512; c++) acc += fin[c] * l2wT[(size_t)c * 256 + t];
        acc += l2b[t];
        float h = acc * (g7[t] * BN_SCALE) + b7[t];
        f2s[t] = h >= 0.f ? h : 0.2f * h;
    }
    __syncthreads();
    if (t < 40) {
        float acc = 0.f;
        for (int c = 0; c < 256; c++) acc += f2s[c] * l3wT[(size_t)c * 40 + t];
        acc += l3b[t];
        if (*flag) ((__hip_bfloat16*)out)[b * 40 + t] = __float2bfloat16(acc);
        else       ((float*)out)[b * 40 + t] = acc;
    }
}

// ================================================================ host
extern "C" void kernel_launch(void* const* d_in, const int* in_sizes, int n_in,
                              void* d_out, int out_size, void* d_ws, size_t ws_size,
                              hipStream_t stream) {
    auto us = [&](int i) { return (const unsigned short*)d_in[i]; };

    float* ws = (float*)d_ws;
    size_t off = 0;
    auto A = [&](size_t n) { float* p = ws + off; off += (n + 3) & ~(size_t)3; return p; };
    auto AU = [&](size_t n) { return (unsigned short*)A((n + 1) / 2); };
    float* xf0  = A((size_t)BN_ * 3);
    float* x1   = A((size_t)BN_ * 64);
    float* x2   = A((size_t)BN_ * 64);
    float* x3   = A((size_t)BN_ * 128);
    float* x4   = A((size_t)BN_ * 256);
    float* pd   = A((size_t)BN_ * 1024);   // pd scratch
    float* f1   = A(8 * 512);
    float* xx   = A(BN_);
    int*   idx  = (int*)A((size_t)BN_ * K_);
    int*   flag = (int*)A(4);
    float* qkvw = A((size_t)BN_ * 768);   // qkv / yz / knn-split scratch
    // bf16 activation copies
    unsigned short* xf0b = AU((size_t)BN_ * 3);
    unsigned short* x1b  = AU((size_t)BN_ * 64);
    unsigned short* x2b  = AU((size_t)BN_ * 64);
    unsigned short* x3b  = AU((size_t)BN_ * 128);
    unsigned short* x4b  = AU((size_t)BN_ * 256);
    unsigned short* owb  = AU((size_t)BN_ * 256);
    // pooled reductions (conv5 fused epilogue) -- contiguous, zeroed by k_prep
    unsigned* pmaxu = (unsigned*)A(8 * 1024);
    float*    psum  = A(8 * 1024);
    // bf16 weights (n,k) layouts
    unsigned short* w1yzb = AU(128 * 3);
    unsigned short* w2yzb = AU(128 * 64);
    unsigned short* w3yzb = AU(256 * 64);
    unsigned short* w4yzb = AU(512 * 128);
    unsigned short* a1wib = AU(192 * 64);  unsigned short* a1wob = AU(64 * 64);
    unsigned short* a2wib = AU(192 * 64);  unsigned short* a2wob = AU(64 * 64);
    unsigned short* a3wib = AU(384 * 128); unsigned short* a3wob = AU(128 * 128);
    unsigned short* a4wib = AU(768 * 256); unsigned short* a4wob = AU(256 * 256);
    unsigned short* w5b   = AU(1024 * 512);
    // fp32 fc weights (transposed)
    float* l1wT  = A(2048 * 512);
    float* l2wT  = A(512 * 256);
    float* l3wT  = A(256 * 40);
    // converted vectors (fp32)
    float* g1f = A(64);   float* b1f = A(64);
    float* g2f = A(64);   float* b2f = A(64);
    float* g3f = A(128);  float* b3f = A(128);
    float* g4f = A(256);  float* b4f = A(256);
    float* bi1 = A(192);  float* bo1 = A(64);
    float* bi2 = A(192);  float* bo2 = A(64);
    float* bi3 = A(384);  float* bo3 = A(128);
    float* bi4 = A(768);  float* bo4 = A(256);
    float* g5f = A(1024); float* b5f = A(1024);
    float* g6f = A(512);  float* b6f = A(512);
    float* l2bf = A(256);
    float* g7f = A(256);  float* b7f = A(256);
    float* l3bf = A(40);

    // knn split buffers alias qkvw (dead during the kNN phase of each layer)
    unsigned short* xa = (unsigned short*)qkvw;
    unsigned short* xb = (unsigned short*)qkvw + (size_t)BN_ * 512;

    k_detect<<<1, 1, 0, stream>>>(us(2), us(5), us(8), us(11), us(30), us(33), us(37), flag);

    TList tl; int nb = 0; int k = 0;
    auto add = [&](int i, void* dst, int O, int I, int mode) {
        tl.p[k].src = d_in[i]; tl.p[k].dst = dst; tl.p[k].O = O; tl.p[k].I = I;
        tl.p[k].blk0 = nb; tl.p[k].mode = mode;
        nb += (O * I + 255) / 256; k++;
    };
    add(0,  xf0,   BN_ * 3, 1, 0);
    add(0,  xf0b,  BN_ * 3, 1, 2);
    add(0,  pmaxu, 16384, 1, 4);      // zero pmaxu+psum (contiguous)
    add(1,  w1yzb, 64, 6, 3);
    add(4,  w2yzb, 64, 128, 3);
    add(7,  w3yzb, 128, 128, 3);
    add(10, w4yzb, 256, 256, 3);
    add(13, a1wib, 192, 64, 2);
    add(15, a1wob, 64, 64, 2);
    add(17, a2wib, 192, 64, 2);
    add(19, a2wob, 64, 64, 2);
    add(21, a3wib, 384, 128, 2);
    add(23, a3wob, 128, 128, 2);
    add(25, a4wib, 768, 256, 2);
    add(27, a4wob, 256, 256, 2);
    add(29, w5b,   1024, 512, 2);
    add(2,  g1f, 64, 1, 0);   add(3,  b1f, 64, 1, 0);
    add(5,  g2f, 64, 1, 0);   add(6,  b2f, 64, 1, 0);
    add(8,  g3f, 128, 1, 0);  add(9,  b3f, 128, 1, 0);
    add(11, g4f, 256, 1, 0);  add(12, b4f, 256, 1, 0);
    add(14, bi1, 192, 1, 0);  add(16, bo1, 64, 1, 0);
    add(18, bi2, 192, 1, 0);  add(20, bo2, 64, 1, 0);
    add(22, bi3, 384, 1, 0);  add(24, bo3, 128, 1, 0);
    add(26, bi4, 768, 1, 0);  add(28, bo4, 256, 1, 0);
    add(30, g5f, 1024, 1, 0); add(31, b5f, 1024, 1, 0);
    add(33, g6f, 512, 1, 0);  add(34, b6f, 512, 1, 0);
    add(36, l2bf, 256, 1, 0);
    add(37, g7f, 256, 1, 0);  add(38, b7f, 256, 1, 0);
    add(40, l3bf, 40, 1, 0);
    k_prep<<<nb, 256, 0, stream>>>(tl, k, flag);

    // LDS-tiled transposes for the big fp32 FC weights (coalesced both sides)
    TrP tp1{d_in[32], l1wT, 512, 2048, 2048 / 32, 0};
    TrP tp2{d_in[35], l2wT, 256, 512,  512 / 32,  (2048 / 32) * (512 / 32)};
    TrP tp3{d_in[39], l3wT, 40,  256,  256 / 32,  tp2.blk0 + (512 / 32) * (256 / 32)};
    const int trblocks = tp3.blk0 + (256 / 32) * ((40 + 31) / 32);
    k_tr<<<trblocks, 256, 0, stream>>>(tp1, tp2, tp3, flag);

    float* yzb = qkvw;                 // fp32 yz scratch (after kNN phase)
    const dim3 pdmg(8, 8, 8);          // 128x128 tiles per batch
    const unsigned short* N0 = nullptr;
    unsigned* NU = nullptr; float* NF = nullptr;

    // layer 1  (C=3 -> 64)
    k_split<3, 32><<<(BN_ * 32) / 256 + 32, 256, 0, stream>>>(xf0, xa, xb, xx);
    k_pdm<32, 128, 128><<<pdmg, 256, 0, stream>>>(xa, xb, xx, pd);
    k_sel<<<BN_ / 4, 256, 0, stream>>>(pd, idx);
    k_gemmb<3, 128, 64, 64><<<dim3(128, 2), 256, 0, stream>>>(xf0b, N0, N0, N0, w1yzb, nullptr, nullptr, yzb, 0, 1.f, nullptr, nullptr, nullptr, NU, NF);
    k_edgemax<64><<<BN_ / 16, 256, 0, stream>>>(yzb, idx, g1f, b1f, x1, x1b);
    k_gemmb<64, 192, 64, 64><<<dim3(128, 3), 256, 0, stream>>>(x1b, N0, N0, N0, a1wib, bi1, nullptr, qkvw, 64, 0.25f, nullptr, nullptr, nullptr, NU, NF);
    k_attn<64><<<N_, 256, 0, stream>>>(qkvw, owb);
    k_gemmb<64, 64, 64, 64><<<dim3(128, 1), 256, 0, stream>>>(owb, N0, N0, N0, a1wob, bo1, x1, x1, 0, 1.f, nullptr, nullptr, x1b, NU, NF);

    // layer 2  (C=64 -> 64)
    k_split<64, 256><<<(BN_ * 256) / 256 + 32, 256, 0, stream>>>(x1, xa, xb, xx);
    k_pdm<256, 128, 128><<<pdmg, 256, 0, stream>>>(xa, xb, xx, pd);
    k_sel<<<BN_ / 4, 256, 0, stream>>>(pd, idx);
    k_gemmb<64, 128, 64, 64><<<dim3(128, 2), 256, 0, stream>>>(x1b, N0, N0, N0, w2yzb, nullptr, nullptr, yzb, 0, 1.f, nullptr, nullptr, nullptr, NU, NF);
    k_edgemax<64><<<BN_ / 16, 256, 0, stream>>>(yzb, idx, g2f, b2f, x2, x2b);
    k_gemmb<64, 192, 64, 64><<<dim3(128, 3), 256, 0, stream>>>(x2b, N0, N0, N0, a2wib, bi2, nullptr, qkvw, 64, 0.25f, nullptr, nullptr, nullptr, NU, NF);
    k_attn<64><<<N_, 256, 0, stream>>>(qkvw, owb);
    k_gemmb<64, 64, 64, 64><<<dim3(128, 1), 256, 0, stream>>>(owb, N0, N0, N0, a2wob, bo2, x2, x2, 0, 1.f, nullptr, nullptr, x2b, NU, NF);

    // layer 3  (C=64 -> 128)
    k_split<64, 256><<<(BN_ * 256) / 256 + 32, 256, 0, stream>>>(x2, xa, xb, xx);
    k_pdm<256, 128, 128><<<pdmg, 256, 0, stream>>>(xa, xb, xx, pd);
    k_sel<<<BN_ / 4, 256, 0, stream>>>(pd, idx);
    k_gemmb<64, 256, 64, 64><<<dim3(128, 4), 256, 0, stream>>>(x2b, N0, N0, N0, w3yzb, nullptr, nullptr, yzb, 0, 1.f, nullptr, nullptr, nullptr, NU, NF);
    k_edgemax<128><<<BN_ / 8, 256, 0, stream>>>(yzb, idx, g3f, b3f, x3, x3b);
    k_gemmb<128, 384, 64, 128><<<dim3(128, 3), 256, 0, stream>>>(x3b, N0, N0, N0, a3wib, bi3, nullptr, qkvw, 128, 0.17677669529663687f, nullptr, nullptr, nullptr, NU, NF);
    k_attn<128><<<N_, 256, 0, stream>>>(qkvw, owb);
    k_gemmb<128, 128, 64, 64><<<dim3(128, 2), 256, 0, stream>>>(owb, N0, N0, N0, a3wob, bo3, x3, x3, 0, 1.f, nullptr, nullptr, x3b, NU, NF);

    // layer 4  (C=128 -> 256)
    k_split<128, 512><<<(BN_ * 512) / 256 + 32, 256, 0, stream>>>(x3, xa, xb, xx);
    k_pdm<512, 128, 128><<<pdmg, 256, 0, stream>>>(xa, xb, xx, pd);
    k_sel<<<BN_ / 4, 256, 0, stream>>>(pd, idx);
    k_gemmb<128, 512, 128, 128><<<dim3(64, 4), 256, 0, stream>>>(x3b, N0, N0, N0, w4yzb, nullptr, nullptr, yzb, 0, 1.f, nullptr, nullptr, nullptr, NU, NF);
    k_edgemax<256><<<BN_ / 4, 256, 0, stream>>>(yzb, idx, g4f, b4f, x4, x4b);
    k_gemmb<256, 768, 128, 128><<<dim3(64, 6), 256, 0, stream>>>(x4b, N0, N0, N0, a4wib, bi4, nullptr, qkvw, 256, 0.125f, nullptr, nullptr, nullptr, NU, NF);
    k_attn<256><<<N_, 256, 0, stream>>>(qkvw, owb);
    k_gemmb<256, 256, 64, 128><<<dim3(128, 2), 256, 0, stream>>>(owb, N0, N0, N0, a4wob, bo4, x4, x4, 0, 1.f, nullptr, nullptr, x4b, NU, NF);

    // head: conv5 with fused concat-A and fused pooling epilogue
    k_gemmb<512, 1024, 128, 128, true, true><<<dim3(64, 8), 256, 0, stream>>>(
        x1b, x2b, x3b, x4b, w5b, nullptr, nullptr, nullptr, 0, 1.f, g5f, b5f, nullptr, pmaxu, psum);
    k_fc1<<<dim3(8, 8), 256, 0, stream>>>(pmaxu, psum, l1wT, g6f, b6f, f1);
    k_fc23<<<8, 256, 0, stream>>>(f1, l2wT, l2bf, g7f, b7f, l3wT, l3bf, d_out, flag);
}

// Round 8
// 556.787 us; speedup vs baseline: 1.2091x; 1.0735x over previous
//
#include <hip/hip_runtime.h>
#include <hip/hip_bf16.h>

#define B_ 8
#define N_ 1024
#define K_ 20
#define BN_ (B_*N_)

#define BN_SCALE 0.9999950000374997f

typedef __attribute__((ext_vector_type(8))) short short8;
typedef __attribute__((ext_vector_type(4))) float f32x4;

__device__ __forceinline__ float US2F(unsigned short u) {
    union { unsigned u; float f; } c; c.u = ((unsigned)u) << 16; return c.f;
}
__device__ __forceinline__ unsigned short F2BF(float f) {   // RNE fp32->bf16
    union { float f; unsigned u; } c; c.f = f;
    unsigned r = c.u + 0x7FFF + ((c.u >> 16) & 1);
    return (unsigned short)(r >> 16);
}

// async global->LDS 16B DMA: LDS dest = wave-uniform base + lane*16 (linear);
// global source is per-lane (pre-swizzled there when a swizzled layout is wanted).
__device__ __forceinline__ void ldsld16(const unsigned short* g, unsigned short* l) {
    __builtin_amdgcn_global_load_lds(
        (const __attribute__((address_space(1))) void*)g,
        (__attribute__((address_space(3))) void*)l, 16, 0, 0);
}

// ---------------------------------------------------------------- dtype detect
__global__ void k_detect(const unsigned short* g1, const unsigned short* g2,
                         const unsigned short* g3, const unsigned short* g4,
                         const unsigned short* g5, const unsigned short* g6,
                         const unsigned short* g7, int* flag) {
    const unsigned short* gs[7] = {g1, g2, g3, g4, g5, g6, g7};
    int cnt = 0;
    for (int i = 0; i < 7; i++) {
        float v = US2F(gs[i][0]);
        if (v > 0.5f && v < 1.5f) cnt++;
    }
    *flag = (cnt >= 4) ? 1 : 0;   // 1 = bf16 inputs, 0 = fp32 inputs
}

// ---------------------------------------------------------------- prep (+ fused transposes)
// mode 0: fp32 copy (I==1 -> contiguous).  mode 2: bf16 copy.
// mode 3: edge pair -> bf16 (2O, C).  mode 4: zero-fill fp32 (dst only).
// Trailing blocks (>= nbp): LDS-tiled 32x32 fp32 transposes (coalesced both
// sides) for the big FC weights -- was a separate k_tr dispatch.
struct TPar { const void* src; void* dst; int O, I, blk0, mode; };
struct TList { TPar p[44]; };
struct TrP { const void* src; float* dst; int O, I, bx, blk0; };

__global__ __launch_bounds__(256) void k_prep(TList tl, int nent,
                                              TrP q0, TrP q1, TrP q2, int nbp,
                                              const int* flag) {
    const int isbf = *flag;
    if ((int)blockIdx.x >= nbp) {          // ---- transpose region
        int blk = blockIdx.x - nbp;
        TrP p = q0;
        if (blk >= q2.blk0) p = q2; else if (blk >= q1.blk0) p = q1;
        blk -= p.blk0;
        const int tx = threadIdx.x & 31, ty = threadIdx.x >> 5;   // 32 x 8
        const int bi = blk % p.bx, bo = blk / p.bx;
        const int i0 = bi * 32, o0 = bo * 32;
        __shared__ float s[32][33];
        #pragma unroll
        for (int r = 0; r < 4; r++) {
            const int o = o0 + ty + r * 8, i = i0 + tx;
            if (o < p.O && i < p.I) {
                const size_t e = (size_t)o * p.I + i;
                s[ty + r * 8][tx] = isbf ? US2F(((const unsigned short*)p.src)[e])
                                         : ((const float*)p.src)[e];
            }
        }
        __syncthreads();
        #pragma unroll
        for (int r = 0; r < 4; r++) {
            const int i = i0 + ty + r * 8, o = o0 + tx;
            if (i < p.I && o < p.O) p.dst[(size_t)i * p.O + o] = s[tx][ty + r * 8];
        }
        return;
    }
    int blk = blockIdx.x;
    int wi = 0;
    for (int j = nent - 1; j >= 0; j--) { if (blk >= tl.p[j].blk0) { wi = j; break; } }
    const TPar p = tl.p[wi];
    int e = (blk - p.blk0) * 256 + threadIdx.x;
    int n = p.O * p.I;
    if (e >= n) return;
    if (p.mode == 4) { ((float*)p.dst)[e] = 0.f; return; }
    int o = e / p.I, i = e - o * p.I;
    float v = isbf ? US2F(((const unsigned short*)p.src)[e])
                   : ((const float*)p.src)[e];
    if (p.mode == 0) {
        ((float*)p.dst)[(size_t)i * p.O + o] = v;
    } else if (p.mode == 2) {
        ((unsigned short*)p.dst)[e] = F2BF(v);
    } else {
        const int C = p.I >> 1;
        if (i < C) ((unsigned short*)p.dst)[(size_t)o * C + i] = F2BF(v);
        else       ((unsigned short*)p.dst)[(size_t)(p.O + o) * C + (i - C)] = F2BF(v);
    }
}

// ---------------------------------------------------------------- kNN split + norms (fused)
// Layer-1 only (C=3, padded KP=32); layers 2-4 get their split fused into the
// producing out-projection GEMM epilogue (SPLIT template param below).
template<int C, int KP>
__global__ __launch_bounds__(256) void k_split(const float* __restrict__ x,
                                               unsigned short* __restrict__ xa,
                                               unsigned short* __restrict__ xb,
                                               float* __restrict__ xx) {
    constexpr int NB = (BN_ * KP) / 256;
    if (blockIdx.x >= NB) {   // norms
        const int i = (blockIdx.x - NB) * 256 + threadIdx.x;
        if (i >= BN_) return;
        const float* p = x + (size_t)i * C;
        float s = 0.f;
        #pragma unroll
        for (int c = 0; c < C; c++) s += p[c] * p[c];
        xx[i] = s;
        return;
    }
    const int e = blockIdx.x * 256 + threadIdx.x;
    const int i = e / KP, p = e - i * KP;
    unsigned short va = 0, vb = 0;
    if (p < 4 * C) {
        const int seg = p / C, c = p - seg * C;
        const float v = x[(size_t)i * C + c];
        const unsigned short h = F2BF(v);
        const unsigned short l = F2BF(v - US2F(h));
        va = (seg & 1) ? l : h;           // hi,lo,hi,lo
        vb = (seg < 2) ? h : l;           // hi,hi,lo,lo
    }
    xa[e] = va;
    xb[e] = vb;
}

// ---------------------------------------------------------------- kNN phase 1 (MFMA):
// pd[b][i][j] = 2*dot(xa_i, xb_j) - xx_j.  128x128 tile, 4 waves x 64x64
// quadrant.  global_load_lds dwordx4 into linear [128][32] LDS; 16B-granule
// XOR swizzle applied on the GLOBAL source; 2-phase double-buffer.
// NOTE (R5/R6 post-mortem): fused pdm+sel (scores in 151 KB LDS, 1 block/CU)
// measured 70-79 us/layer -- selection needs k_sel's 32-waves/CU TLP.
template<int KP, int TM, int TN>
__global__ __launch_bounds__(256) void k_pdm(const unsigned short* __restrict__ xa,
                                             const unsigned short* __restrict__ xb,
                                             const float* __restrict__ xx,
                                             float* __restrict__ pd) {
    const int b = blockIdx.z;
    const int rb = blockIdx.x * TM, cb = blockIdx.y * TN;
    const unsigned short* Ab = xa + (size_t)b * N_ * KP;
    const unsigned short* Bb = xb + (size_t)b * N_ * KP;
    const float* xxb = xx + (size_t)b * N_;
    const int t = threadIdx.x;
    __shared__ __align__(16) unsigned short As[2][TM * 32];
    __shared__ __align__(16) unsigned short Bs[2][TN * 32];
    const int w = t >> 6, lane = t & 63;
    constexpr int QR = TM / 2, QC = TN / 2;
    constexpr int MR = QR / 16, NR = QC / 16;
    const int wr = (w & 1) * QR, wc = (w >> 1) * QC;
    const int fr = lane & 15, q = lane >> 4;
    f32x4 acc[MR][NR] = {};

    auto STAGE = [&](int buf, int k0) {
        constexpr int AT = TM * 4;
        #pragma unroll
        for (int R = 0; R < (AT + 255) / 256; R++) {
            const int G = t + R * 256;
            if (AT >= (R + 1) * 256 || G < AT) {
                const int m = G >> 2, gs = (G & 3) ^ ((m >> 1) & 3);
                ldsld16(&Ab[(size_t)(rb + m) * KP + k0 + gs * 8], &As[buf][w * 512 + R * 2048]);
            }
        }
        constexpr int BT = TN * 4;
        #pragma unroll
        for (int R = 0; R < (BT + 255) / 256; R++) {
            const int G = t + R * 256;
            if (BT >= (R + 1) * 256 || G < BT) {
                const int n = G >> 2, gs = (G & 3) ^ ((n >> 1) & 3);
                ldsld16(&Bb[(size_t)(cb + n) * KP + k0 + gs * 8], &Bs[buf][w * 512 + R * 2048]);
            }
        }
    };

    constexpr int NT = KP / 32;
    STAGE(0, 0);
    asm volatile("s_waitcnt vmcnt(0)" ::: "memory");
    __builtin_amdgcn_s_barrier();
    int cur = 0;
    for (int ts = 0; ts < NT; ++ts) {
        if (ts + 1 < NT) STAGE(cur ^ 1, (ts + 1) * 32);
        short8 af[MR], bfr[NR];
        #pragma unroll
        for (int mi = 0; mi < MR; mi++) {
            const int r = wr + mi * 16 + fr;
            af[mi] = *reinterpret_cast<const short8*>(&As[cur][r * 32 + ((q ^ ((r >> 1) & 3)) << 3)]);
        }
        #pragma unroll
        for (int ni = 0; ni < NR; ni++) {
            const int r = wc + ni * 16 + fr;
            bfr[ni] = *reinterpret_cast<const short8*>(&Bs[cur][r * 32 + ((q ^ ((r >> 1) & 3)) << 3)]);
        }
        #pragma unroll
        for (int mi = 0; mi < MR; mi++) {
            #pragma unroll
            for (int ni = 0; ni < NR; ni++)
                acc[mi][ni] = __builtin_amdgcn_mfma_f32_16x16x32_bf16(af[mi], bfr[ni], acc[mi][ni], 0, 0, 0);
        }
        asm volatile("s_waitcnt vmcnt(0)" ::: "memory");
        __builtin_amdgcn_s_barrier();
        cur ^= 1;
    }
    float* pdb = pd + (size_t)b * N_ * N_;
    const int cr = (lane >> 4) * 4, cc = lane & 15;
    #pragma unroll
    for (int mi = 0; mi < MR; mi++) {
        #pragma unroll
        for (int ni = 0; ni < NR; ni++) {
            #pragma unroll
            for (int r = 0; r < 4; r++) {
                const int row = rb + wr + mi * 16 + cr + r;
                const int col = cb + wc + ni * 16 + cc;
                pdb[(size_t)row * N_ + col] = 2.f * acc[mi][ni][r] - xxb[col];
            }
        }
    }
}

// ---------------------------------------------------------------- kNN phase 2 (device body)
// 32-bit key top-20; 2048 sel blocks -> 32 waves/CU hides the serial 20-round
// chain (R5/R6 lesson).
__device__ __forceinline__ void sel_dev(const float* __restrict__ pd,
                                        int* __restrict__ idx, int blk) {
    const int w = threadIdx.x >> 6, lane = threadIdx.x & 63;
    const int i = blk * 4 + w;                 // 0..8191
    const int b = i >> 10;
    const float* row = pd + (size_t)b * N_ * N_ + (size_t)(i & 1023) * N_;
    unsigned key[16];
    #pragma unroll
    for (int q = 0; q < 16; q++) {
        const int j = q * 64 + lane;
        unsigned bits = __float_as_uint(row[j]);
        bits = (bits & 0x80000000u) ? ~bits : (bits | 0x80000000u);
        key[q] = (bits & 0xFFFFFC00u) | (unsigned)(N_ - 1 - j);
    }
    int myj = 0;
    for (int kk = 0; kk < K_; kk++) {
        unsigned m = key[0];
        #pragma unroll
        for (int u = 1; u < 16; u++) m = key[u] > m ? key[u] : m;
        #pragma unroll
        for (int s = 1; s < 64; s <<= 1) {
            unsigned o = (unsigned)__shfl_xor((int)m, s, 64);
            m = o > m ? o : m;
        }
        const int j = N_ - 1 - (int)(m & 1023u);
        if (lane == kk) myj = j;
        #pragma unroll
        for (int u = 0; u < 16; u++)
            if (key[u] == m) key[u] = 0u;      // below any plausible real key
    }
    if (lane < K_) idx[(size_t)i * K_ + lane] = myj;
}

// ---------------------------------------------------------------- MFMA bf16 GEMM (device body)
// C[8192][NC] = A[8192][KD] @ Bw^T.  KD%32==0: global_load_lds dwordx4 into
// linear [T][32] LDS, source-side 16B-granule XOR swizzle, 2-phase dbuf.
// CATA: A = virtual concat [x1b|x2b|x3b|x4b].  POOL: fused BN+LReLU+max/sum
// pooling epilogue (atomics).  SPLIT=C>0: out-projection epilogue also emits
// next layer's kNN hi/lo split (xa/xb, KP=4C) and row norms xx (atomicAdd,
// pre-zeroed) -- replaces the standalone k_split for layers 2-4.
template<int KD, int NC, int TM, int TN, bool CATA, bool POOL, int SPLIT>
__device__ __forceinline__ void gemm_dev(int bx, int by,
                                         const unsigned short* __restrict__ A,
                                         const unsigned short* __restrict__ A2,
                                         const unsigned short* __restrict__ A3,
                                         const unsigned short* __restrict__ A4,
                                         const unsigned short* __restrict__ Bw,
                                         const float* __restrict__ bias,
                                         const float* __restrict__ resid,
                                         float* __restrict__ Cout,
                                         int scale_cols, float qs,
                                         const float* __restrict__ gamma,
                                         const float* __restrict__ beta,
                                         unsigned short* __restrict__ obf,
                                         unsigned* __restrict__ pmaxu,
                                         float* __restrict__ psum,
                                         unsigned short* __restrict__ sxa,
                                         unsigned short* __restrict__ sxb,
                                         float* __restrict__ xxo) {
    const int t = threadIdx.x;
    const int rb = bx * TM, cb = by * TN;
    const int w = t >> 6, lane = t & 63;
    constexpr int QR = TM / 2, QC = TN / 2;
    constexpr int MR = QR / 16, NR = QC / 16;
    const int wr = (w & 1) * QR, wc = (w >> 1) * QC;
    const int fr = lane & 15, q = lane >> 4, fq = q * 8;
    f32x4 acc[MR][NR] = {};
    if constexpr (KD % 32 == 0) {
        __shared__ __align__(16) unsigned short As[2][TM * 32];
        __shared__ __align__(16) unsigned short Bs[2][TN * 32];
        auto STAGE = [&](int buf, int k0) {
            const unsigned short* Asrc = A; int AC = KD, ac0 = k0;
            if constexpr (CATA) {
                if (k0 >= 256)      { Asrc = A4; AC = 256; ac0 = k0 - 256; }
                else if (k0 >= 128) { Asrc = A3; AC = 128; ac0 = k0 - 128; }
                else if (k0 >= 64)  { Asrc = A2; AC = 64;  ac0 = k0 - 64; }
                else                { Asrc = A;  AC = 64;  ac0 = k0; }
            }
            constexpr int AT = TM * 4;
            #pragma unroll
            for (int R = 0; R < (AT + 255) / 256; R++) {
                const int G = t + R * 256;
                if (AT >= (R + 1) * 256 || G < AT) {
                    const int m = G >> 2, gs = (G & 3) ^ ((m >> 1) & 3);
                    ldsld16(&Asrc[(size_t)(rb + m) * AC + ac0 + gs * 8], &As[buf][w * 512 + R * 2048]);
                }
            }
            constexpr int BT = TN * 4;
            #pragma unroll
            for (int R = 0; R < (BT + 255) / 256; R++) {
                const int G = t + R * 256;
                if (BT >= (R + 1) * 256 || G < BT) {
                    const int n = G >> 2, gs = (G & 3) ^ ((n >> 1) & 3);
                    ldsld16(&Bw[(size_t)(cb + n) * KD + k0 + gs * 8], &Bs[buf][w * 512 + R * 2048]);
                }
            }
        };
        constexpr int NT = KD / 32;
        STAGE(0, 0);
        asm volatile("s_waitcnt vmcnt(0)" ::: "memory");
        __builtin_amdgcn_s_barrier();
        int cur = 0;
        for (int ts = 0; ts < NT; ++ts) {
            if (ts + 1 < NT) STAGE(cur ^ 1, (ts + 1) * 32);
            short8 af[MR], bfr[NR];
            #pragma unroll
            for (int mi = 0; mi < MR; mi++) {
                const int r = wr + mi * 16 + fr;
                af[mi] = *reinterpret_cast<const short8*>(&As[cur][r * 32 + ((q ^ ((r >> 1) & 3)) << 3)]);
            }
            #pragma unroll
            for (int ni = 0; ni < NR; ni++) {
                const int r = wc + ni * 16 + fr;
                bfr[ni] = *reinterpret_cast<const short8*>(&Bs[cur][r * 32 + ((q ^ ((r >> 1) & 3)) << 3)]);
            }
            #pragma unroll
            for (int mi = 0; mi < MR; mi++) {
                #pragma unroll
                for (int ni = 0; ni < NR; ni++)
                    acc[mi][ni] = __builtin_amdgcn_mfma_f32_16x16x32_bf16(af[mi], bfr[ni], acc[mi][ni], 0, 0, 0);
            }
            asm volatile("s_waitcnt vmcnt(0)" ::: "memory");
            __builtin_amdgcn_s_barrier();
            cur ^= 1;
        }
    } else {
        // fallback (KD=3): reg-staged, padded LDS, scalar guarded loads
        __shared__ __align__(16) unsigned short As[TM * 40];
        __shared__ __align__(16) unsigned short Bs[TN * 40];
        for (int k0 = 0; k0 < KD; k0 += 32) {
            __syncthreads();
            #pragma unroll
            for (int u = t; u < TM * 4; u += 256) {
                const int m = u >> 2, c = (u & 3) * 8;
                #pragma unroll
                for (int j = 0; j < 8; j++) {
                    const int kk = k0 + c + j;
                    As[m * 40 + c + j] = (kk < KD) ? A[(size_t)(rb + m) * KD + kk] : (unsigned short)0;
                }
            }
            #pragma unroll
            for (int u = t; u < TN * 4; u += 256) {
                const int n = u >> 2, c = (u & 3) * 8;
                const int gn = cb + n;
                if (gn < NC) {
                    #pragma unroll
                    for (int j = 0; j < 8; j++) {
                        const int kk = k0 + c + j;
                        Bs[n * 40 + c + j] = (kk < KD) ? Bw[(size_t)gn * KD + kk] : (unsigned short)0;
                    }
                } else {
                    short8 z = {};
                    *reinterpret_cast<short8*>(&Bs[n * 40 + c]) = z;
                }
            }
            __syncthreads();
            short8 af[MR], bfr[NR];
            #pragma unroll
            for (int mi = 0; mi < MR; mi++)
                af[mi] = *reinterpret_cast<const short8*>(&As[(wr + mi * 16 + fr) * 40 + fq]);
            #pragma unroll
            for (int ni = 0; ni < NR; ni++)
                bfr[ni] = *reinterpret_cast<const short8*>(&Bs[(wc + ni * 16 + fr) * 40 + fq]);
            #pragma unroll
            for (int mi = 0; mi < MR; mi++) {
                #pragma unroll
                for (int ni = 0; ni < NR; ni++)
                    acc[mi][ni] = __builtin_amdgcn_mfma_f32_16x16x32_bf16(af[mi], bfr[ni], acc[mi][ni], 0, 0, 0);
            }
        }
    }
    const int cr = (lane >> 4) * 4, cc = lane & 15;
    if constexpr (POOL) {
        const int bidx = rb >> 10;
        #pragma unroll
        for (int ni = 0; ni < NR; ni++) {
            const int col = cb + wc + ni * 16 + cc;
            const float gm = gamma[col] * BN_SCALE, bt = beta[col];
            float sm = 0.f, mxv = -3e38f;
            #pragma unroll
            for (int mi = 0; mi < MR; mi++) {
                #pragma unroll
                for (int r = 0; r < 4; r++) {
                    float v = acc[mi][ni][r] * gm + bt;
                    v = v >= 0.f ? v : 0.2f * v;
                    sm += v; mxv = fmaxf(mxv, v);
                }
            }
            sm += __shfl_xor(sm, 16, 64);
            sm += __shfl_xor(sm, 32, 64);
            mxv = fmaxf(mxv, __shfl_xor(mxv, 16, 64));
            mxv = fmaxf(mxv, __shfl_xor(mxv, 32, 64));
            if (lane < 16) {
                atomicAdd(&psum[bidx * 1024 + col], sm);
                unsigned tb = __float_as_uint(mxv);
                tb = (tb & 0x80000000u) ? ~tb : (tb | 0x80000000u);
                atomicMax(&pmaxu[bidx * 1024 + col], tb);
            }
        }
    } else {
        float sx[MR][4] = {};
        #pragma unroll
        for (int mi = 0; mi < MR; mi++) {
            #pragma unroll
            for (int ni = 0; ni < NR; ni++) {
                #pragma unroll
                for (int r = 0; r < 4; r++) {
                    const int row = rb + wr + mi * 16 + cr + r;
                    const int col = cb + wc + ni * 16 + cc;
                    if (col < NC) {
                        float v = acc[mi][ni][r] + (bias ? bias[col] : 0.f);
                        if (col < scale_cols) v *= qs;
                        if (resid) v += resid[(size_t)row * NC + col];
                        if (gamma) {
                            v = v * (gamma[col] * BN_SCALE) + beta[col];
                            v = v >= 0.f ? v : 0.2f * v;
                        }
                        Cout[(size_t)row * NC + col] = v;
                        if (obf) obf[(size_t)row * NC + col] = F2BF(v);
                        if constexpr (SPLIT > 0) {
                            constexpr int KP2 = 4 * SPLIT;
                            const unsigned short h = F2BF(v);
                            const unsigned short l = F2BF(v - US2F(h));
                            sxa[(size_t)row * KP2 + 0 * SPLIT + col] = h;
                            sxa[(size_t)row * KP2 + 1 * SPLIT + col] = l;
                            sxa[(size_t)row * KP2 + 2 * SPLIT + col] = h;
                            sxa[(size_t)row * KP2 + 3 * SPLIT + col] = l;
                            sxb[(size_t)row * KP2 + 0 * SPLIT + col] = h;
                            sxb[(size_t)row * KP2 + 1 * SPLIT + col] = h;
                            sxb[(size_t)row * KP2 + 2 * SPLIT + col] = l;
                            sxb[(size_t)row * KP2 + 3 * SPLIT + col] = l;
                            sx[mi][r] += v * v;
                        }
                    }
                }
            }
        }
        if constexpr (SPLIT > 0) {
            // row-norm: reduce over the 16 col-lanes (same lane>>4 group = same rows)
            #pragma unroll
            for (int mi = 0; mi < MR; mi++) {
                #pragma unroll
                for (int r = 0; r < 4; r++) {
                    float s = sx[mi][r];
                    s += __shfl_xor(s, 1, 64);
                    s += __shfl_xor(s, 2, 64);
                    s += __shfl_xor(s, 4, 64);
                    s += __shfl_xor(s, 8, 64);
                    if ((lane & 15) == 0)
                        atomicAdd(&xxo[rb + wr + mi * 16 + cr + r], s);
                }
            }
        }
    }
}

template<int KD, int NC, int TM, int TN, bool CATA = false, bool POOL = false, int SPLIT = 0>
__global__ __launch_bounds__(256) void k_gemmb(const unsigned short* __restrict__ A,
                                               const unsigned short* __restrict__ A2,
                                               const unsigned short* __restrict__ A3,
                                               const unsigned short* __restrict__ A4,
                                               const unsigned short* __restrict__ Bw,
                                               const float* __restrict__ bias,
                                               const float* __restrict__ resid,
                                               float* __restrict__ Cout,
                                               int scale_cols, float qs,
                                               const float* __restrict__ gamma,
                                               const float* __restrict__ beta,
                                               unsigned short* __restrict__ obf,
                                               unsigned* __restrict__ pmaxu,
                                               float* __restrict__ psum,
                                               unsigned short* __restrict__ sxa,
                                               unsigned short* __restrict__ sxb,
                                               float* __restrict__ xxo) {
    gemm_dev<KD, NC, TM, TN, CATA, POOL, SPLIT>(blockIdx.x, blockIdx.y,
        A, A2, A3, A4, Bw, bias, resid, Cout, scale_cols, qs, gamma, beta,
        obf, pmaxu, psum, sxa, sxb, xxo);
}

// ---------------------------------------------------------------- combined sel || yz-GEMM
// k_sel (latency-bound, reads pd) and the yz edge-feature GEMM (reads x_prev,
// independent of pd) run concurrently in one launch: blocks [0,selb) = sel,
// the rest = gemm (flattened 2D).  Complementary pipes -> overlap + one less
// dispatch boundary per layer.
template<int KD, int NC, int TM, int TN>
__global__ __launch_bounds__(256) void k_selyz(const float* __restrict__ pd,
                                               int* __restrict__ idx, int selb, int gx,
                                               const unsigned short* __restrict__ A,
                                               const unsigned short* __restrict__ Bw,
                                               float* __restrict__ Cout) {
    if ((int)blockIdx.x < selb) { sel_dev(pd, idx, blockIdx.x); return; }
    const int g = blockIdx.x - selb;
    gemm_dev<KD, NC, TM, TN, false, false, 0>(g % gx, g / gx,
        A, nullptr, nullptr, nullptr, Bw, nullptr, nullptr, Cout, 0, 1.f,
        nullptr, nullptr, nullptr, nullptr, nullptr, nullptr, nullptr, nullptr);
}

// ---------------------------------------------------------------- EdgeConv epilogue (fp32 out + bf16 copy)
template<int CO>
__global__ __launch_bounds__(256) void k_edgemax(const float* __restrict__ yz,
                                                 const int* __restrict__ idx,
                                                 const float* __restrict__ g,
                                                 const float* __restrict__ bb,
                                                 float* __restrict__ out,
                                                 unsigned short* __restrict__ outb) {
    constexpr int TPP = CO / 4;
    constexpr int PPB = 256 / TPP;
    const int t = threadIdx.x;
    const int p = t / TPP;
    const int cw = (t % TPP) * 4;
    const int i0 = blockIdx.x * PPB;
    const int bbase = (i0 >> 10) << 10;
    __shared__ int sidx[PPB][K_];
    for (int u = t; u < PPB * K_; u += 256) {
        int pp = u / K_, kk = u - pp * K_;
        sidx[pp][kk] = idx[(size_t)(i0 + pp) * K_ + kk];
    }
    __syncthreads();
    const int ig = i0 + p;
    float4 m = {-3e38f, -3e38f, -3e38f, -3e38f};
    #pragma unroll 4
    for (int k = 0; k < K_; k++) {
        const int jg = bbase + sidx[p][k];
        const float4 yv = *reinterpret_cast<const float4*>(&yz[(size_t)jg * 2 * CO + cw]);
        m.x = fmaxf(m.x, yv.x); m.y = fmaxf(m.y, yv.y);
        m.z = fmaxf(m.z, yv.z); m.w = fmaxf(m.w, yv.w);
    }
    const float4 yi = *reinterpret_cast<const float4*>(&yz[(size_t)ig * 2 * CO + cw]);
    const float4 zi = *reinterpret_cast<const float4*>(&yz[(size_t)ig * 2 * CO + CO + cw]);
    const float4 gv = *reinterpret_cast<const float4*>(&g[cw]);
    const float4 bv = *reinterpret_cast<const float4*>(&bb[cw]);
    float vals[4] = {m.x - yi.x + zi.x, m.y - yi.y + zi.y,
                     m.z - yi.z + zi.z, m.w - yi.w + zi.w};
    float gs[4] = {gv.x, gv.y, gv.z, gv.w};
    float bs[4] = {bv.x, bv.y, bv.z, bv.w};
    float4 o;
    float* op = &o.x;
    #pragma unroll
    for (int j = 0; j < 4; j++) {
        float h = vals[j] * (gs[j] * BN_SCALE) + bs[j];
        op[j] = h >= 0.f ? h : 0.2f * h;
    }
    *reinterpret_cast<float4*>(&out[(size_t)ig * CO + cw]) = o;
    #pragma unroll
    for (int j = 0; j < 4; j++) outb[(size_t)ig * CO + cw + j] = F2BF(op[j]);
}

// ---------------------------------------------------------------- attention (fp32 math, bf16 out)
template<int E>
__global__ __launch_bounds__(256) void k_attn(const float* __restrict__ qkv,
                                              unsigned short* __restrict__ o) {
    constexpr int H = 4, D = E / H, L = 8;
    const int n = blockIdx.x;
    const int t = threadIdx.x;
    const int h = t >> 6, lane = t & 63;
    __shared__ float sq[L][3 * E];
    __shared__ float so[L][E];
    for (int u = t; u < L * 3 * E; u += 256) {
        int l = u / (3 * E), r = u - l * (3 * E);
        sq[l][r] = qkv[(size_t)(l * N_ + n) * (3 * E) + r];
    }
    __syncthreads();
    const int l = lane >> 3, m = lane & 7;
    float s = 0.f;
    #pragma unroll 8
    for (int dd = 0; dd < D; dd++)
        s += sq[l][h * D + dd] * sq[m][E + h * D + dd];
    float mx = s;
    #pragma unroll
    for (int st = 1; st < 8; st <<= 1) mx = fmaxf(mx, __shfl_xor(mx, st, 64));
    float e = expf(s - mx);
    float sum = e;
    #pragma unroll
    for (int st = 1; st < 8; st <<= 1) sum += __shfl_xor(sum, st, 64);
    const float p = e / sum;
    float pm[8];
    #pragma unroll
    for (int mm = 0; mm < 8; mm++) pm[mm] = __shfl(p, (lane & 56) | mm, 64);
    #pragma unroll
    for (int j = 0; j < D / 8; j++) {
        const int dd = m + 8 * j;
        float a = 0.f;
        #pragma unroll
        for (int mm = 0; mm < 8; mm++) a += pm[mm] * sq[mm][2 * E + h * D + dd];
        so[l][h * D + dd] = a;
    }
    __syncthreads();
    for (int u = t; u < L * E; u += 256) {
        int l2 = u / E, e2 = u - l2 * E;
        o[(size_t)(l2 * N_ + n) * E + e2] = F2BF(so[l2][e2]);
    }
}

// ---------------------------------------------------------------- FC head
// fc1 reads the pooled feat inline from pmaxu/psum (pool2 folded in).
__global__ __launch_bounds__(256) void k_fc1(const unsigned* __restrict__ pmaxu,
                                             const float* __restrict__ psum,
                                             const float* __restrict__ l1wT,
                                             const float* __restrict__ g6, const float* __restrict__ b6,
                                             float* __restrict__ f1) {
    int oc = blockIdx.x, b = blockIdx.y, t = threadIdx.x;
    __shared__ float fin[2048];
    __shared__ float ps[4][64];
    for (int u = t; u < 2048; u += 256) {
        float v;
        if (u < 1024) {
            unsigned tb = pmaxu[b * 1024 + u];
            unsigned bits = (tb & 0x80000000u) ? (tb & 0x7FFFFFFFu) : ~tb;
            v = __uint_as_float(bits);
        } else {
            v = psum[b * 1024 + (u - 1024)] * (1.f / 1024.f);
        }
        fin[u] = v;
    }
    __syncthreads();
    int ol = t & 63, kc = t >> 6;
    int o = oc * 64 + ol;
    float acc = 0.f;
    for (int c = kc * 512; c < kc * 512 + 512; c++) acc += fin[c] * l1wT[(size_t)c * 512 + o];
    ps[kc][ol] = acc;
    __syncthreads();
    if (t < 64) {
        int oo = oc * 64 + t;
        float a = ps[0][t] + ps[1][t] + ps[2][t] + ps[3][t];
        float h = a * (g6[oo] * BN_SCALE) + b6[oo];
        f1[b * 512 + oo] = h >= 0.f ? h : 0.2f * h;
    }
}

// fc2 + fc3 fused (one block per batch; f2 lives in LDS only)
__global__ __launch_bounds__(256) void k_fc23(const float* __restrict__ f1, const float* __restrict__ l2wT,
                                              const float* __restrict__ l2b,
                                              const float* __restrict__ g7, const float* __restrict__ b7,
                                              const float* __restrict__ l3wT, const float* __restrict__ l3b,
                                              void* __restrict__ out, const int* __restrict__ flag) {
    int b = blockIdx.x, t = threadIdx.x;
    __shared__ float fin[512];
    __shared__ float f2s[256];
    for (int u = t; u < 512; u += 256) fin[u] = f1[b * 512 + u];
    __syncthreads();
    {
        float acc = 0.f;
        for (int c = 0; c < 512; c++) acc += fin[c] * l2wT[(size_t)c * 256 + t];
        acc += l2b[t];
        float h = acc * (g7[t] * BN_SCALE) + b7[t];
        f2s[t] = h >= 0.f ? h : 0.2f * h;
    }
    __syncthreads();
    if (t < 40) {
        float acc = 0.f;
        for (int c = 0; c < 256; c++) acc += f2s[c] * l3wT[(size_t)c * 40 + t];
        acc += l3b[t];
        if (*flag) ((__hip_bfloat16*)out)[b * 40 + t] = __float2bfloat16(acc);
        else       ((float*)out)[b * 40 + t] = acc;
    }
}

// ================================================================ host
extern "C" void kernel_launch(void* const* d_in, const int* in_sizes, int n_in,
                              void* d_out, int out_size, void* d_ws, size_t ws_size,
                              hipStream_t stream) {
    auto us = [&](int i) { return (const unsigned short*)d_in[i]; };

    float* ws = (float*)d_ws;
    size_t off = 0;
    auto A = [&](size_t n) { float* p = ws + off; off += (n + 3) & ~(size_t)3; return p; };
    auto AU = [&](size_t n) { return (unsigned short*)A((n + 1) / 2); };
    float* xf0  = A((size_t)BN_ * 3);
    float* x1   = A((size_t)BN_ * 64);
    float* x2   = A((size_t)BN_ * 64);
    float* x3   = A((size_t)BN_ * 128);
    float* x4   = A((size_t)BN_ * 256);
    float* pd   = A((size_t)BN_ * 1024);   // pd scratch
    float* f1   = A(8 * 512);
    float* xx   = A(4 * BN_);              // per-layer row norms (xx2..4 atomic, pre-zeroed)
    int*   idx  = (int*)A((size_t)BN_ * K_);
    int*   flag = (int*)A(4);
    float* qkvw = A((size_t)BN_ * 768);   // qkv / yz / knn-split scratch
    // bf16 activation copies
    unsigned short* xf0b = AU((size_t)BN_ * 3);
    unsigned short* x1b  = AU((size_t)BN_ * 64);
    unsigned short* x2b  = AU((size_t)BN_ * 64);
    unsigned short* x3b  = AU((size_t)BN_ * 128);
    unsigned short* x4b  = AU((size_t)BN_ * 256);
    unsigned short* owb  = AU((size_t)BN_ * 256);
    // pooled reductions (conv5 fused epilogue) -- contiguous, zeroed by k_prep
    unsigned* pmaxu = (unsigned*)A(8 * 1024);
    float*    psum  = A(8 * 1024);
    // bf16 weights (n,k) layouts
    unsigned short* w1yzb = AU(128 * 3);
    unsigned short* w2yzb = AU(128 * 64);
    unsigned short* w3yzb = AU(256 * 64);
    unsigned short* w4yzb = AU(512 * 128);
    unsigned short* a1wib = AU(192 * 64);  unsigned short* a1wob = AU(64 * 64);
    unsigned short* a2wib = AU(192 * 64);  unsigned short* a2wob = AU(64 * 64);
    unsigned short* a3wib = AU(384 * 128); unsigned short* a3wob = AU(128 * 128);
    unsigned short* a4wib = AU(768 * 256); unsigned short* a4wob = AU(256 * 256);
    unsigned short* w5b   = AU(1024 * 512);
    // fp32 fc weights (transposed)
    float* l1wT  = A(2048 * 512);
    float* l2wT  = A(512 * 256);
    float* l3wT  = A(256 * 40);
    // converted vectors (fp32)
    float* g1f = A(64);   float* b1f = A(64);
    float* g2f = A(64);   float* b2f = A(64);
    float* g3f = A(128);  float* b3f = A(128);
    float* g4f = A(256);  float* b4f = A(256);
    float* bi1 = A(192);  float* bo1 = A(64);
    float* bi2 = A(192);  float* bo2 = A(64);
    float* bi3 = A(384);  float* bo3 = A(128);
    float* bi4 = A(768);  float* bo4 = A(256);
    float* g5f = A(1024); float* b5f = A(1024);
    float* g6f = A(512);  float* b6f = A(512);
    float* l2bf = A(256);
    float* g7f = A(256);  float* b7f = A(256);
    float* l3bf = A(40);

    float* xx1 = xx;              float* xx2 = xx + BN_;
    float* xx3 = xx + 2 * BN_;    float* xx4 = xx + 3 * BN_;

    // knn split buffers alias qkvw (dead during the kNN phase of each layer)
    unsigned short* xa = (unsigned short*)qkvw;
    unsigned short* xb = (unsigned short*)qkvw + (size_t)BN_ * 512;

    k_detect<<<1, 1, 0, stream>>>(us(2), us(5), us(8), us(11), us(30), us(33), us(37), flag);

    TList tl; int nb = 0; int k = 0;
    auto add = [&](int i, void* dst, int O, int I, int mode) {
        tl.p[k].src = d_in[i]; tl.p[k].dst = dst; tl.p[k].O = O; tl.p[k].I = I;
        tl.p[k].blk0 = nb; tl.p[k].mode = mode;
        nb += (O * I + 255) / 256; k++;
    };
    add(0,  xf0,   BN_ * 3, 1, 0);
    add(0,  xf0b,  BN_ * 3, 1, 2);
    add(0,  pmaxu, 16384, 1, 4);      // zero pmaxu+psum (contiguous)
    add(0,  xx2,   3 * BN_, 1, 4);    // zero xx2..xx4 (atomic targets)
    add(1,  w1yzb, 64, 6, 3);
    add(4,  w2yzb, 64, 128, 3);
    add(7,  w3yzb, 128, 128, 3);
    add(10, w4yzb, 256, 256, 3);
    add(13, a1wib, 192, 64, 2);
    add(15, a1wob, 64, 64, 2);
    add(17, a2wib, 192, 64, 2);
    add(19, a2wob, 64, 64, 2);
    add(21, a3wib, 384, 128, 2);
    add(23, a3wob, 128, 128, 2);
    add(25, a4wib, 768, 256, 2);
    add(27, a4wob, 256, 256, 2);
    add(29, w5b,   1024, 512, 2);
    add(2,  g1f, 64, 1, 0);   add(3,  b1f, 64, 1, 0);
    add(5,  g2f, 64, 1, 0);   add(6,  b2f, 64, 1, 0);
    add(8,  g3f, 128, 1, 0);  add(9,  b3f, 128, 1, 0);
    add(11, g4f, 256, 1, 0);  add(12, b4f, 256, 1, 0);
    add(14, bi1, 192, 1, 0);  add(16, bo1, 64, 1, 0);
    add(18, bi2, 192, 1, 0);  add(20, bo2, 64, 1, 0);
    add(22, bi3, 384, 1, 0);  add(24, bo3, 128, 1, 0);
    add(26, bi4, 768, 1, 0);  add(28, bo4, 256, 1, 0);
    add(30, g5f, 1024, 1, 0); add(31, b5f, 1024, 1, 0);
    add(33, g6f, 512, 1, 0);  add(34, b6f, 512, 1, 0);
    add(36, l2bf, 256, 1, 0);
    add(37, g7f, 256, 1, 0);  add(38, b7f, 256, 1, 0);
    add(40, l3bf, 40, 1, 0);

    // FC-weight transposes fused into k_prep's tail blocks
    TrP tp1{d_in[32], l1wT, 512, 2048, 2048 / 32, 0};
    TrP tp2{d_in[35], l2wT, 256, 512,  512 / 32,  (2048 / 32) * (512 / 32)};
    TrP tp3{d_in[39], l3wT, 40,  256,  256 / 32,  tp2.blk0 + (512 / 32) * (256 / 32)};
    const int trblocks = tp3.blk0 + (256 / 32) * ((40 + 31) / 32);
    k_prep<<<nb + trblocks, 256, 0, stream>>>(tl, k, tp1, tp2, tp3, nb, flag);

    float* yzb = qkvw;                 // fp32 yz scratch (after kNN phase)
    const dim3 pdmg(8, 8, 8);          // 128x128 tiles per batch
    const unsigned short* N0 = nullptr;
    unsigned short* U0 = nullptr;
    unsigned* NU = nullptr; float* NF = nullptr;

    // layer 1  (C=3 -> 64)
    k_split<3, 32><<<(BN_ * 32) / 256 + 32, 256, 0, stream>>>(xf0, xa, xb, xx1);
    k_pdm<32, 128, 128><<<pdmg, 256, 0, stream>>>(xa, xb, xx1, pd);
    k_selyz<3, 128, 64, 64><<<2048 + 256, 256, 0, stream>>>(pd, idx, 2048, 128, xf0b, w1yzb, yzb);
    k_edgemax<64><<<BN_ / 16, 256, 0, stream>>>(yzb, idx, g1f, b1f, x1, x1b);
    k_gemmb<64, 192, 64, 64><<<dim3(128, 3), 256, 0, stream>>>(x1b, N0, N0, N0, a1wib, bi1, nullptr, qkvw, 64, 0.25f, nullptr, nullptr, nullptr, NU, NF, U0, U0, NF);
    k_attn<64><<<N_, 256, 0, stream>>>(qkvw, owb);
    k_gemmb<64, 64, 64, 64, false, false, 64><<<dim3(128, 1), 256, 0, stream>>>(owb, N0, N0, N0, a1wob, bo1, x1, x1, 0, 1.f, nullptr, nullptr, x1b, NU, NF, xa, xb, xx2);

    // layer 2  (C=64 -> 64)
    k_pdm<256, 128, 128><<<pdmg, 256, 0, stream>>>(xa, xb, xx2, pd);
    k_selyz<64, 128, 64, 64><<<2048 + 256, 256, 0, stream>>>(pd, idx, 2048, 128, x1b, w2yzb, yzb);
    k_edgemax<64><<<BN_ / 16, 256, 0, stream>>>(yzb, idx, g2f, b2f, x2, x2b);
    k_gemmb<64, 192, 64, 64><<<dim3(128, 3), 256, 0, stream>>>(x2b, N0, N0, N0, a2wib, bi2, nullptr, qkvw, 64, 0.25f, nullptr, nullptr, nullptr, NU, NF, U0, U0, NF);
    k_attn<64><<<N_, 256, 0, stream>>>(qkvw, owb);
    k_gemmb<64, 64, 64, 64, false, false, 64><<<dim3(128, 1), 256, 0, stream>>>(owb, N0, N0, N0, a2wob, bo2, x2, x2, 0, 1.f, nullptr, nullptr, x2b, NU, NF, xa, xb, xx3);

    // layer 3  (C=64 -> 128)
    k_pdm<256, 128, 128><<<pdmg, 256, 0, stream>>>(xa, xb, xx3, pd);
    k_selyz<64, 256, 64, 64><<<2048 + 512, 256, 0, stream>>>(pd, idx, 2048, 128, x2b, w3yzb, yzb);
    k_edgemax<128><<<BN_ / 8, 256, 0, stream>>>(yzb, idx, g3f, b3f, x3, x3b);
    k_gemmb<128, 384, 64, 128><<<dim3(128, 3), 256, 0, stream>>>(x3b, N0, N0, N0, a3wib, bi3, nullptr, qkvw, 128, 0.17677669529663687f, nullptr, nullptr, nullptr, NU, NF, U0, U0, NF);
    k_attn<128><<<N_, 256, 0, stream>>>(qkvw, owb);
    k_gemmb<128, 128, 64, 64, false, false, 128><<<dim3(128, 2), 256, 0, stream>>>(owb, N0, N0, N0, a3wob, bo3, x3, x3, 0, 1.f, nullptr, nullptr, x3b, NU, NF, xa, xb, xx4);

    // layer 4  (C=128 -> 256)
    k_pdm<512, 128, 128><<<pdmg, 256, 0, stream>>>(xa, xb, xx4, pd);
    k_selyz<128, 512, 128, 128><<<2048 + 256, 256, 0, stream>>>(pd, idx, 2048, 64, x3b, w4yzb, yzb);
    k_edgemax<256><<<BN_ / 4, 256, 0, stream>>>(yzb, idx, g4f, b4f, x4, x4b);
    k_gemmb<256, 768, 128, 128><<<dim3(64, 6), 256, 0, stream>>>(x4b, N0, N0, N0, a4wib, bi4, nullptr, qkvw, 256, 0.125f, nullptr, nullptr, nullptr, NU, NF, U0, U0, NF);
    k_attn<256><<<N_, 256, 0, stream>>>(qkvw, owb);
    k_gemmb<256, 256, 64, 128><<<dim3(128, 2), 256, 0, stream>>>(owb, N0, N0, N0, a4wob, bo4, x4, x4, 0, 1.f, nullptr, nullptr, x4b, NU, NF, U0, U0, NF);

    // head: conv5 with fused concat-A and fused pooling epilogue
    k_gemmb<512, 1024, 128, 128, true, true><<<dim3(64, 8), 256, 0, stream>>>(
        x1b, x2b, x3b, x4b, w5b, nullptr, nullptr, nullptr, 0, 1.f, g5f, b5f, nullptr, pmaxu, psum, U0, U0, NF);
    k_fc1<<<dim3(8, 8), 256, 0, stream>>>(pmaxu, psum, l1wT, g6f, b6f, f1);
    k_fc23<<<8, 256, 0, stream>>>(f1, l2wT, l2bf, g7f, b7f, l3wT, l3bf, d_out, flag);
}

// Round 9
// 525.461 us; speedup vs baseline: 1.2812x; 1.0596x over previous
//
#include <hip/hip_runtime.h>
#include <hip/hip_bf16.h>

#define B_ 8
#define N_ 1024
#define K_ 20
#define BN_ (B_*N_)

#define BN_SCALE 0.9999950000374997f

typedef __attribute__((ext_vector_type(8))) short short8;
typedef __attribute__((ext_vector_type(4))) float f32x4;

__device__ __forceinline__ float US2F(unsigned short u) {
    union { unsigned u; float f; } c; c.u = ((unsigned)u) << 16; return c.f;
}
__device__ __forceinline__ unsigned short F2BF(float f) {   // RNE fp32->bf16
    union { float f; unsigned u; } c; c.f = f;
    unsigned r = c.u + 0x7FFF + ((c.u >> 16) & 1);
    return (unsigned short)(r >> 16);
}

// async global->LDS 16B DMA: LDS dest = wave-uniform base + lane*16 (linear);
// global source is per-lane (pre-swizzled there when a swizzled layout is wanted).
__device__ __forceinline__ void ldsld16(const unsigned short* g, unsigned short* l) {
    __builtin_amdgcn_global_load_lds(
        (const __attribute__((address_space(1))) void*)g,
        (__attribute__((address_space(3))) void*)l, 16, 0, 0);
}

// dtype-detect data: first element of 7 gamma vectors (bf16 gammas ~1.0)
struct DetP { const unsigned short* g[7]; };
__device__ __forceinline__ int det_isbf(const DetP& dp) {
    int cnt = 0;
    #pragma unroll
    for (int i = 0; i < 7; i++) {
        float v = US2F(dp.g[i][0]);
        if (v > 0.5f && v < 1.5f) cnt++;
    }
    return cnt >= 4;
}

// ---------------------------------------------------------------- prep (+ transposes + L1 split)
// Region 1 [0,nbp): table entries -- mode 0: fp32 copy (I==1); mode 2: bf16
// copy; mode 3: edge pair -> bf16 (2O,C); mode 4: zero-fill fp32.
// Region 2 [nbp,nbp+nbtr): LDS-tiled 32x32 fp32 transposes (FC weights).
// Region 3 [nbp+nbtr,..): layer-1 kNN split (reads d_in[0] directly, C=3,
// KP=32, 3-seg exact-split) + row norms xx1.  Dtype flag computed inline
// (k_detect dispatch eliminated).
struct TPar { const void* src; void* dst; int O, I, blk0, mode; };
struct TList { TPar p[44]; };
struct TrP { const void* src; float* dst; int O, I, bx, blk0; };

__global__ __launch_bounds__(256) void k_prep(TList tl, int nent,
                                              TrP q0, TrP q1, TrP q2,
                                              int nbp, int nbtr,
                                              const void* x0, DetP dp,
                                              unsigned short* __restrict__ xa,
                                              unsigned short* __restrict__ xb,
                                              float* __restrict__ xx1) {
    __shared__ int sbf;
    if (threadIdx.x == 0) sbf = det_isbf(dp);
    __syncthreads();
    const int isbf = sbf;
    auto ld0 = [&](int idx) {
        return isbf ? US2F(((const unsigned short*)x0)[idx])
                    : ((const float*)x0)[idx];
    };
    const int bid = blockIdx.x;
    if (bid >= nbp + nbtr) {               // ---- region 3: L1 split + norms
        int blk = bid - nbp - nbtr;
        if (blk >= (BN_ * 32) / 256) {     // norms (32 blocks)
            int i = (blk - (BN_ * 32) / 256) * 256 + threadIdx.x;
            if (i >= BN_) return;
            float s = 0.f;
            #pragma unroll
            for (int c = 0; c < 3; c++) { float v = ld0(i * 3 + c); s += v * v; }
            xx1[i] = s;
            return;
        }
        const int e = blk * 256 + threadIdx.x;   // e < BN_*32
        const int i = e >> 5, p = e & 31;
        unsigned short va = 0, vb = 0;
        if (p < 9) {                        // 3 segs x C=3
            const int seg = p / 3, c = p - seg * 3;
            const float v = ld0(i * 3 + c);
            const unsigned short h = F2BF(v);
            const unsigned short l = F2BF(v - US2F(h));
            va = (seg == 1) ? l : h;        // hi,lo,hi
            vb = (seg < 2) ? h : l;         // hi,hi,lo
        }
        xa[e] = va; xb[e] = vb;
        return;
    }
    if (bid >= nbp) {                      // ---- region 2: transposes
        int blk = bid - nbp;
        TrP p = q0;
        if (blk >= q2.blk0) p = q2; else if (blk >= q1.blk0) p = q1;
        blk -= p.blk0;
        const int tx = threadIdx.x & 31, ty = threadIdx.x >> 5;   // 32 x 8
        const int bi = blk % p.bx, bo = blk / p.bx;
        const int i0 = bi * 32, o0 = bo * 32;
        __shared__ float s[32][33];
        #pragma unroll
        for (int r = 0; r < 4; r++) {
            const int o = o0 + ty + r * 8, i = i0 + tx;
            if (o < p.O && i < p.I) {
                const size_t e = (size_t)o * p.I + i;
                s[ty + r * 8][tx] = isbf ? US2F(((const unsigned short*)p.src)[e])
                                         : ((const float*)p.src)[e];
            }
        }
        __syncthreads();
        #pragma unroll
        for (int r = 0; r < 4; r++) {
            const int i = i0 + ty + r * 8, o = o0 + tx;
            if (i < p.I && o < p.O) p.dst[(size_t)i * p.O + o] = s[tx][ty + r * 8];
        }
        return;
    }
    int blk = bid;                          // ---- region 1: entries
    int wi = 0;
    for (int j = nent - 1; j >= 0; j--) { if (blk >= tl.p[j].blk0) { wi = j; break; } }
    const TPar p = tl.p[wi];
    int e = (blk - p.blk0) * 256 + threadIdx.x;
    int n = p.O * p.I;
    if (e >= n) return;
    if (p.mode == 4) { ((float*)p.dst)[e] = 0.f; return; }
    int o = e / p.I, i = e - o * p.I;
    float v = isbf ? US2F(((const unsigned short*)p.src)[e])
                   : ((const float*)p.src)[e];
    if (p.mode == 0) {
        ((float*)p.dst)[(size_t)i * p.O + o] = v;
    } else if (p.mode == 2) {
        ((unsigned short*)p.dst)[e] = F2BF(v);
    } else {
        const int C = p.I >> 1;
        if (i < C) ((unsigned short*)p.dst)[(size_t)o * C + i] = F2BF(v);
        else       ((unsigned short*)p.dst)[(size_t)(p.O + o) * C + (i - C)] = F2BF(v);
    }
}

// ---------------------------------------------------------------- kNN phase 1 (MFMA):
// pd[b][i][j] = 2*dot(xa_i, xb_j) - xx_j.  3-seg exact-split: dot over KP=3C
// = hi.hi + lo.hi + hi.lo (the dropped lo.lo term is ~2^-18 relative, 16x
// below the selection key's own 2^-14 truncation).  128x128 tile, 4 waves,
// global_load_lds + source-side 16B-granule XOR swizzle, 2-phase dbuf.
// NOTE (R5/R6): fused pdm+sel (1 block/CU) measured 70-79us/layer --
// selection needs k_sel's 32-waves/CU TLP.  Keep the two-kernel form.
template<int KP, int TM, int TN>
__global__ __launch_bounds__(256) void k_pdm(const unsigned short* __restrict__ xa,
                                             const unsigned short* __restrict__ xb,
                                             const float* __restrict__ xx,
                                             float* __restrict__ pd) {
    const int b = blockIdx.z;
    const int rb = blockIdx.x * TM, cb = blockIdx.y * TN;
    const unsigned short* Ab = xa + (size_t)b * N_ * KP;
    const unsigned short* Bb = xb + (size_t)b * N_ * KP;
    const float* xxb = xx + (size_t)b * N_;
    const int t = threadIdx.x;
    __shared__ __align__(16) unsigned short As[2][TM * 32];
    __shared__ __align__(16) unsigned short Bs[2][TN * 32];
    const int w = t >> 6, lane = t & 63;
    constexpr int QR = TM / 2, QC = TN / 2;
    constexpr int MR = QR / 16, NR = QC / 16;
    const int wr = (w & 1) * QR, wc = (w >> 1) * QC;
    const int fr = lane & 15, q = lane >> 4;
    f32x4 acc[MR][NR] = {};

    auto STAGE = [&](int buf, int k0) {
        constexpr int AT = TM * 4;
        #pragma unroll
        for (int R = 0; R < (AT + 255) / 256; R++) {
            const int G = t + R * 256;
            if (AT >= (R + 1) * 256 || G < AT) {
                const int m = G >> 2, gs = (G & 3) ^ ((m >> 1) & 3);
                ldsld16(&Ab[(size_t)(rb + m) * KP + k0 + gs * 8], &As[buf][w * 512 + R * 2048]);
            }
        }
        constexpr int BT = TN * 4;
        #pragma unroll
        for (int R = 0; R < (BT + 255) / 256; R++) {
            const int G = t + R * 256;
            if (BT >= (R + 1) * 256 || G < BT) {
                const int n = G >> 2, gs = (G & 3) ^ ((n >> 1) & 3);
                ldsld16(&Bb[(size_t)(cb + n) * KP + k0 + gs * 8], &Bs[buf][w * 512 + R * 2048]);
            }
        }
    };

    constexpr int NT = KP / 32;
    STAGE(0, 0);
    asm volatile("s_waitcnt vmcnt(0)" ::: "memory");
    __builtin_amdgcn_s_barrier();
    int cur = 0;
    for (int ts = 0; ts < NT; ++ts) {
        if (ts + 1 < NT) STAGE(cur ^ 1, (ts + 1) * 32);
        short8 af[MR], bfr[NR];
        #pragma unroll
        for (int mi = 0; mi < MR; mi++) {
            const int r = wr + mi * 16 + fr;
            af[mi] = *reinterpret_cast<const short8*>(&As[cur][r * 32 + ((q ^ ((r >> 1) & 3)) << 3)]);
        }
        #pragma unroll
        for (int ni = 0; ni < NR; ni++) {
            const int r = wc + ni * 16 + fr;
            bfr[ni] = *reinterpret_cast<const short8*>(&Bs[cur][r * 32 + ((q ^ ((r >> 1) & 3)) << 3)]);
        }
        #pragma unroll
        for (int mi = 0; mi < MR; mi++) {
            #pragma unroll
            for (int ni = 0; ni < NR; ni++)
                acc[mi][ni] = __builtin_amdgcn_mfma_f32_16x16x32_bf16(af[mi], bfr[ni], acc[mi][ni], 0, 0, 0);
        }
        asm volatile("s_waitcnt vmcnt(0)" ::: "memory");
        __builtin_amdgcn_s_barrier();
        cur ^= 1;
    }
    float* pdb = pd + (size_t)b * N_ * N_;
    const int cr = (lane >> 4) * 4, cc = lane & 15;
    #pragma unroll
    for (int mi = 0; mi < MR; mi++) {
        #pragma unroll
        for (int ni = 0; ni < NR; ni++) {
            #pragma unroll
            for (int r = 0; r < 4; r++) {
                const int row = rb + wr + mi * 16 + cr + r;
                const int col = cb + wc + ni * 16 + cc;
                pdb[(size_t)row * N_ + col] = 2.f * acc[mi][ni][r] - xxb[col];
            }
        }
    }
}

// ---------------------------------------------------------------- kNN phase 2 (device body)
// 32-bit key top-20; 2048 sel blocks -> 32 waves/CU hides the serial 20-round
// chain (R5/R6 lesson).
__device__ __forceinline__ void sel_dev(const float* __restrict__ pd,
                                        int* __restrict__ idx, int blk) {
    const int w = threadIdx.x >> 6, lane = threadIdx.x & 63;
    const int i = blk * 4 + w;                 // 0..8191
    const int b = i >> 10;
    const float* row = pd + (size_t)b * N_ * N_ + (size_t)(i & 1023) * N_;
    unsigned key[16];
    #pragma unroll
    for (int q = 0; q < 16; q++) {
        const int j = q * 64 + lane;
        unsigned bits = __float_as_uint(row[j]);
        bits = (bits & 0x80000000u) ? ~bits : (bits | 0x80000000u);
        key[q] = (bits & 0xFFFFFC00u) | (unsigned)(N_ - 1 - j);
    }
    int myj = 0;
    for (int kk = 0; kk < K_; kk++) {
        unsigned m = key[0];
        #pragma unroll
        for (int u = 1; u < 16; u++) m = key[u] > m ? key[u] : m;
        #pragma unroll
        for (int s = 1; s < 64; s <<= 1) {
            unsigned o = (unsigned)__shfl_xor((int)m, s, 64);
            m = o > m ? o : m;
        }
        const int j = N_ - 1 - (int)(m & 1023u);
        if (lane == kk) myj = j;
        #pragma unroll
        for (int u = 0; u < 16; u++)
            if (key[u] == m) key[u] = 0u;      // below any plausible real key
    }
    if (lane < K_) idx[(size_t)i * K_ + lane] = myj;
}

// ---------------------------------------------------------------- MFMA bf16 GEMM (device body)
// C[8192][NC] = A[8192][KD] @ Bw^T.  KD%32==0: global_load_lds dwordx4 into
// linear [T][32] LDS, source-side 16B-granule XOR swizzle, 2-phase dbuf.
// CATA: A = virtual concat [x1b|x2b|x3b|x4b].  POOL: fused BN+LReLU+max/sum
// pooling epilogue (atomics).  SPLIT=C>0: out-projection epilogue also emits
// next layer's 3-seg kNN split (xa/xb, KP=3C) and row norms xx (atomicAdd,
// pre-zeroed).
template<int KD, int NC, int TM, int TN, bool CATA, bool POOL, int SPLIT>
__device__ __forceinline__ void gemm_dev(int bx, int by,
                                         const unsigned short* __restrict__ A,
                                         const unsigned short* __restrict__ A2,
                                         const unsigned short* __restrict__ A3,
                                         const unsigned short* __restrict__ A4,
                                         const unsigned short* __restrict__ Bw,
                                         const float* __restrict__ bias,
                                         const float* __restrict__ resid,
                                         float* __restrict__ Cout,
                                         int scale_cols, float qs,
                                         const float* __restrict__ gamma,
                                         const float* __restrict__ beta,
                                         unsigned short* __restrict__ obf,
                                         unsigned* __restrict__ pmaxu,
                                         float* __restrict__ psum,
                                         unsigned short* __restrict__ sxa,
                                         unsigned short* __restrict__ sxb,
                                         float* __restrict__ xxo) {
    const int t = threadIdx.x;
    const int rb = bx * TM, cb = by * TN;
    const int w = t >> 6, lane = t & 63;
    constexpr int QR = TM / 2, QC = TN / 2;
    constexpr int MR = QR / 16, NR = QC / 16;
    const int wr = (w & 1) * QR, wc = (w >> 1) * QC;
    const int fr = lane & 15, q = lane >> 4, fq = q * 8;
    f32x4 acc[MR][NR] = {};
    if constexpr (KD % 32 == 0) {
        __shared__ __align__(16) unsigned short As[2][TM * 32];
        __shared__ __align__(16) unsigned short Bs[2][TN * 32];
        auto STAGE = [&](int buf, int k0) {
            const unsigned short* Asrc = A; int AC = KD, ac0 = k0;
            if constexpr (CATA) {
                if (k0 >= 256)      { Asrc = A4; AC = 256; ac0 = k0 - 256; }
                else if (k0 >= 128) { Asrc = A3; AC = 128; ac0 = k0 - 128; }
                else if (k0 >= 64)  { Asrc = A2; AC = 64;  ac0 = k0 - 64; }
                else                { Asrc = A;  AC = 64;  ac0 = k0; }
            }
            constexpr int AT = TM * 4;
            #pragma unroll
            for (int R = 0; R < (AT + 255) / 256; R++) {
                const int G = t + R * 256;
                if (AT >= (R + 1) * 256 || G < AT) {
                    const int m = G >> 2, gs = (G & 3) ^ ((m >> 1) & 3);
                    ldsld16(&Asrc[(size_t)(rb + m) * AC + ac0 + gs * 8], &As[buf][w * 512 + R * 2048]);
                }
            }
            constexpr int BT = TN * 4;
            #pragma unroll
            for (int R = 0; R < (BT + 255) / 256; R++) {
                const int G = t + R * 256;
                if (BT >= (R + 1) * 256 || G < BT) {
                    const int n = G >> 2, gs = (G & 3) ^ ((n >> 1) & 3);
                    ldsld16(&Bw[(size_t)(cb + n) * KD + k0 + gs * 8], &Bs[buf][w * 512 + R * 2048]);
                }
            }
        };
        constexpr int NT = KD / 32;
        STAGE(0, 0);
        asm volatile("s_waitcnt vmcnt(0)" ::: "memory");
        __builtin_amdgcn_s_barrier();
        int cur = 0;
        for (int ts = 0; ts < NT; ++ts) {
            if (ts + 1 < NT) STAGE(cur ^ 1, (ts + 1) * 32);
            short8 af[MR], bfr[NR];
            #pragma unroll
            for (int mi = 0; mi < MR; mi++) {
                const int r = wr + mi * 16 + fr;
                af[mi] = *reinterpret_cast<const short8*>(&As[cur][r * 32 + ((q ^ ((r >> 1) & 3)) << 3)]);
            }
            #pragma unroll
            for (int ni = 0; ni < NR; ni++) {
                const int r = wc + ni * 16 + fr;
                bfr[ni] = *reinterpret_cast<const short8*>(&Bs[cur][r * 32 + ((q ^ ((r >> 1) & 3)) << 3)]);
            }
            #pragma unroll
            for (int mi = 0; mi < MR; mi++) {
                #pragma unroll
                for (int ni = 0; ni < NR; ni++)
                    acc[mi][ni] = __builtin_amdgcn_mfma_f32_16x16x32_bf16(af[mi], bfr[ni], acc[mi][ni], 0, 0, 0);
            }
            asm volatile("s_waitcnt vmcnt(0)" ::: "memory");
            __builtin_amdgcn_s_barrier();
            cur ^= 1;
        }
    } else {
        // fallback (KD=3): reg-staged, padded LDS, scalar guarded loads
        __shared__ __align__(16) unsigned short As[TM * 40];
        __shared__ __align__(16) unsigned short Bs[TN * 40];
        for (int k0 = 0; k0 < KD; k0 += 32) {
            __syncthreads();
            #pragma unroll
            for (int u = t; u < TM * 4; u += 256) {
                const int m = u >> 2, c = (u & 3) * 8;
                #pragma unroll
                for (int j = 0; j < 8; j++) {
                    const int kk = k0 + c + j;
                    As[m * 40 + c + j] = (kk < KD) ? A[(size_t)(rb + m) * KD + kk] : (unsigned short)0;
                }
            }
            #pragma unroll
            for (int u = t; u < TN * 4; u += 256) {
                const int n = u >> 2, c = (u & 3) * 8;
                const int gn = cb + n;
                if (gn < NC) {
                    #pragma unroll
                    for (int j = 0; j < 8; j++) {
                        const int kk = k0 + c + j;
                        Bs[n * 40 + c + j] = (kk < KD) ? Bw[(size_t)gn * KD + kk] : (unsigned short)0;
                    }
                } else {
                    short8 z = {};
                    *reinterpret_cast<short8*>(&Bs[n * 40 + c]) = z;
                }
            }
            __syncthreads();
            short8 af[MR], bfr[NR];
            #pragma unroll
            for (int mi = 0; mi < MR; mi++)
                af[mi] = *reinterpret_cast<const short8*>(&As[(wr + mi * 16 + fr) * 40 + fq]);
            #pragma unroll
            for (int ni = 0; ni < NR; ni++)
                bfr[ni] = *reinterpret_cast<const short8*>(&Bs[(wc + ni * 16 + fr) * 40 + fq]);
            #pragma unroll
            for (int mi = 0; mi < MR; mi++) {
                #pragma unroll
                for (int ni = 0; ni < NR; ni++)
                    acc[mi][ni] = __builtin_amdgcn_mfma_f32_16x16x32_bf16(af[mi], bfr[ni], acc[mi][ni], 0, 0, 0);
            }
        }
    }
    const int cr = (lane >> 4) * 4, cc = lane & 15;
    if constexpr (POOL) {
        const int bidx = rb >> 10;
        #pragma unroll
        for (int ni = 0; ni < NR; ni++) {
            const int col = cb + wc + ni * 16 + cc;
            const float gm = gamma[col] * BN_SCALE, bt = beta[col];
            float sm = 0.f, mxv = -3e38f;
            #pragma unroll
            for (int mi = 0; mi < MR; mi++) {
                #pragma unroll
                for (int r = 0; r < 4; r++) {
                    float v = acc[mi][ni][r] * gm + bt;
                    v = v >= 0.f ? v : 0.2f * v;
                    sm += v; mxv = fmaxf(mxv, v);
                }
            }
            sm += __shfl_xor(sm, 16, 64);
            sm += __shfl_xor(sm, 32, 64);
            mxv = fmaxf(mxv, __shfl_xor(mxv, 16, 64));
            mxv = fmaxf(mxv, __shfl_xor(mxv, 32, 64));
            if (lane < 16) {
                atomicAdd(&psum[bidx * 1024 + col], sm);
                unsigned tb = __float_as_uint(mxv);
                tb = (tb & 0x80000000u) ? ~tb : (tb | 0x80000000u);
                atomicMax(&pmaxu[bidx * 1024 + col], tb);
            }
        }
    } else {
        float sx[MR][4] = {};
        #pragma unroll
        for (int mi = 0; mi < MR; mi++) {
            #pragma unroll
            for (int ni = 0; ni < NR; ni++) {
                #pragma unroll
                for (int r = 0; r < 4; r++) {
                    const int row = rb + wr + mi * 16 + cr + r;
                    const int col = cb + wc + ni * 16 + cc;
                    if (col < NC) {
                        float v = acc[mi][ni][r] + (bias ? bias[col] : 0.f);
                        if (col < scale_cols) v *= qs;
                        if (resid) v += resid[(size_t)row * NC + col];
                        if (gamma) {
                            v = v * (gamma[col] * BN_SCALE) + beta[col];
                            v = v >= 0.f ? v : 0.2f * v;
                        }
                        Cout[(size_t)row * NC + col] = v;
                        if (obf) obf[(size_t)row * NC + col] = F2BF(v);
                        if constexpr (SPLIT > 0) {
                            constexpr int KP2 = 3 * SPLIT;
                            const unsigned short h = F2BF(v);
                            const unsigned short l = F2BF(v - US2F(h));
                            sxa[(size_t)row * KP2 + 0 * SPLIT + col] = h;
                            sxa[(size_t)row * KP2 + 1 * SPLIT + col] = l;
                            sxa[(size_t)row * KP2 + 2 * SPLIT + col] = h;
                            sxb[(size_t)row * KP2 + 0 * SPLIT + col] = h;
                            sxb[(size_t)row * KP2 + 1 * SPLIT + col] = h;
                            sxb[(size_t)row * KP2 + 2 * SPLIT + col] = l;
                            sx[mi][r] += v * v;
                        }
                    }
                }
            }
        }
        if constexpr (SPLIT > 0) {
            // row-norm: reduce over the 16 col-lanes (same lane>>4 group = same rows)
            #pragma unroll
            for (int mi = 0; mi < MR; mi++) {
                #pragma unroll
                for (int r = 0; r < 4; r++) {
                    float s = sx[mi][r];
                    s += __shfl_xor(s, 1, 64);
                    s += __shfl_xor(s, 2, 64);
                    s += __shfl_xor(s, 4, 64);
                    s += __shfl_xor(s, 8, 64);
                    if ((lane & 15) == 0)
                        atomicAdd(&xxo[rb + wr + mi * 16 + cr + r], s);
                }
            }
        }
    }
}

template<int KD, int NC, int TM, int TN, bool CATA = false, bool POOL = false, int SPLIT = 0>
__global__ __launch_bounds__(256) void k_gemmb(const unsigned short* __restrict__ A,
                                               const unsigned short* __restrict__ A2,
                                               const unsigned short* __restrict__ A3,
                                               const unsigned short* __restrict__ A4,
                                               const unsigned short* __restrict__ Bw,
                                               const float* __restrict__ bias,
                                               const float* __restrict__ resid,
                                               float* __restrict__ Cout,
                                               int scale_cols, float qs,
                                               const float* __restrict__ gamma,
                                               const float* __restrict__ beta,
                                               unsigned short* __restrict__ obf,
                                               unsigned* __restrict__ pmaxu,
                                               float* __restrict__ psum,
                                               unsigned short* __restrict__ sxa,
                                               unsigned short* __restrict__ sxb,
                                               float* __restrict__ xxo) {
    gemm_dev<KD, NC, TM, TN, CATA, POOL, SPLIT>(blockIdx.x, blockIdx.y,
        A, A2, A3, A4, Bw, bias, resid, Cout, scale_cols, qs, gamma, beta,
        obf, pmaxu, psum, sxa, sxb, xxo);
}

// ---------------------------------------------------------------- combined sel || yz-GEMM
// k_sel (latency-bound, reads pd) and the yz edge-feature GEMM (reads x_prev,
// independent of pd) run concurrently in one launch: blocks [0,selb) = sel,
// the rest = gemm (flattened 2D).
template<int KD, int NC, int TM, int TN>
__global__ __launch_bounds__(256) void k_selyz(const float* __restrict__ pd,
                                               int* __restrict__ idx, int selb, int gx,
                                               const unsigned short* __restrict__ A,
                                               const unsigned short* __restrict__ Bw,
                                               float* __restrict__ Cout) {
    if ((int)blockIdx.x < selb) { sel_dev(pd, idx, blockIdx.x); return; }
    const int g = blockIdx.x - selb;
    gemm_dev<KD, NC, TM, TN, false, false, 0>(g % gx, g / gx,
        A, nullptr, nullptr, nullptr, Bw, nullptr, nullptr, Cout, 0, 1.f,
        nullptr, nullptr, nullptr, nullptr, nullptr, nullptr, nullptr, nullptr);
}

// ---------------------------------------------------------------- EdgeConv epilogue (fp32 out + bf16 copy)
template<int CO>
__global__ __launch_bounds__(256) void k_edgemax(const float* __restrict__ yz,
                                                 const int* __restrict__ idx,
                                                 const float* __restrict__ g,
                                                 const float* __restrict__ bb,
                                                 float* __restrict__ out,
                                                 unsigned short* __restrict__ outb) {
    constexpr int TPP = CO / 4;
    constexpr int PPB = 256 / TPP;
    const int t = threadIdx.x;
    const int p = t / TPP;
    const int cw = (t % TPP) * 4;
    const int i0 = blockIdx.x * PPB;
    const int bbase = (i0 >> 10) << 10;
    __shared__ int sidx[PPB][K_];
    for (int u = t; u < PPB * K_; u += 256) {
        int pp = u / K_, kk = u - pp * K_;
        sidx[pp][kk] = idx[(size_t)(i0 + pp) * K_ + kk];
    }
    __syncthreads();
    const int ig = i0 + p;
    float4 m = {-3e38f, -3e38f, -3e38f, -3e38f};
    #pragma unroll 4
    for (int k = 0; k < K_; k++) {
        const int jg = bbase + sidx[p][k];
        const float4 yv = *reinterpret_cast<const float4*>(&yz[(size_t)jg * 2 * CO + cw]);
        m.x = fmaxf(m.x, yv.x); m.y = fmaxf(m.y, yv.y);
        m.z = fmaxf(m.z, yv.z); m.w = fmaxf(m.w, yv.w);
    }
    const float4 yi = *reinterpret_cast<const float4*>(&yz[(size_t)ig * 2 * CO + cw]);
    const float4 zi = *reinterpret_cast<const float4*>(&yz[(size_t)ig * 2 * CO + CO + cw]);
    const float4 gv = *reinterpret_cast<const float4*>(&g[cw]);
    const float4 bv = *reinterpret_cast<const float4*>(&bb[cw]);
    float vals[4] = {m.x - yi.x + zi.x, m.y - yi.y + zi.y,
                     m.z - yi.z + zi.z, m.w - yi.w + zi.w};
    float gs[4] = {gv.x, gv.y, gv.z, gv.w};
    float bs[4] = {bv.x, bv.y, bv.z, bv.w};
    float4 o;
    float* op = &o.x;
    #pragma unroll
    for (int j = 0; j < 4; j++) {
        float h = vals[j] * (gs[j] * BN_SCALE) + bs[j];
        op[j] = h >= 0.f ? h : 0.2f * h;
    }
    *reinterpret_cast<float4*>(&out[(size_t)ig * CO + cw]) = o;
    #pragma unroll
    for (int j = 0; j < 4; j++) outb[(size_t)ig * CO + cw + j] = F2BF(op[j]);
}

// ---------------------------------------------------------------- attention (fp32 math, bf16 out)
template<int E>
__global__ __launch_bounds__(256) void k_attn(const float* __restrict__ qkv,
                                              unsigned short* __restrict__ o) {
    constexpr int H = 4, D = E / H, L = 8;
    const int n = blockIdx.x;
    const int t = threadIdx.x;
    const int h = t >> 6, lane = t & 63;
    __shared__ float sq[L][3 * E];
    __shared__ float so[L][E];
    for (int u = t; u < L * 3 * E; u += 256) {
        int l = u / (3 * E), r = u - l * (3 * E);
        sq[l][r] = qkv[(size_t)(l * N_ + n) * (3 * E) + r];
    }
    __syncthreads();
    const int l = lane >> 3, m = lane & 7;
    float s = 0.f;
    #pragma unroll 8
    for (int dd = 0; dd < D; dd++)
        s += sq[l][h * D + dd] * sq[m][E + h * D + dd];
    float mx = s;
    #pragma unroll
    for (int st = 1; st < 8; st <<= 1) mx = fmaxf(mx, __shfl_xor(mx, st, 64));
    float e = expf(s - mx);
    float sum = e;
    #pragma unroll
    for (int st = 1; st < 8; st <<= 1) sum += __shfl_xor(sum, st, 64);
    const float p = e / sum;
    float pm[8];
    #pragma unroll
    for (int mm = 0; mm < 8; mm++) pm[mm] = __shfl(p, (lane & 56) | mm, 64);
    #pragma unroll
    for (int j = 0; j < D / 8; j++) {
        const int dd = m + 8 * j;
        float a = 0.f;
        #pragma unroll
        for (int mm = 0; mm < 8; mm++) a += pm[mm] * sq[mm][2 * E + h * D + dd];
        so[l][h * D + dd] = a;
    }
    __syncthreads();
    for (int u = t; u < L * E; u += 256) {
        int l2 = u / E, e2 = u - l2 * E;
        o[(size_t)(l2 * N_ + n) * E + e2] = F2BF(so[l2][e2]);
    }
}

// ---------------------------------------------------------------- FC head
// fc1 reads the pooled feat inline from pmaxu/psum (pool2 folded in).
__global__ __launch_bounds__(256) void k_fc1(const unsigned* __restrict__ pmaxu,
                                             const float* __restrict__ psum,
                                             const float* __restrict__ l1wT,
                                             const float* __restrict__ g6, const float* __restrict__ b6,
                                             float* __restrict__ f1) {
    int oc = blockIdx.x, b = blockIdx.y, t = threadIdx.x;
    __shared__ float fin[2048];
    __shared__ float ps[4][64];
    for (int u = t; u < 2048; u += 256) {
        float v;
        if (u < 1024) {
            unsigned tb = pmaxu[b * 1024 + u];
            unsigned bits = (tb & 0x80000000u) ? (tb & 0x7FFFFFFFu) : ~tb;
            v = __uint_as_float(bits);
        } else {
            v = psum[b * 1024 + (u - 1024)] * (1.f / 1024.f);
        }
        fin[u] = v;
    }
    __syncthreads();
    int ol = t & 63, kc = t >> 6;
    int o = oc * 64 + ol;
    float acc = 0.f;
    for (int c = kc * 512; c < kc * 512 + 512; c++) acc += fin[c] * l1wT[(size_t)c * 512 + o];
    ps[kc][ol] = acc;
    __syncthreads();
    if (t < 64) {
        int oo = oc * 64 + t;
        float a = ps[0][t] + ps[1][t] + ps[2][t] + ps[3][t];
        float h = a * (g6[oo] * BN_SCALE) + b6[oo];
        f1[b * 512 + oo] = h >= 0.f ? h : 0.2f * h;
    }
}

// fc2 + fc3 fused (one block per batch; f2 lives in LDS only).  Output dtype
// flag computed inline (k_detect eliminated).
__global__ __launch_bounds__(256) void k_fc23(const float* __restrict__ f1, const float* __restrict__ l2wT,
                                              const float* __restrict__ l2b,
                                              const float* __restrict__ g7, const float* __restrict__ b7,
                                              const float* __restrict__ l3wT, const float* __restrict__ l3b,
                                              void* __restrict__ out, DetP dp) {
    int b = blockIdx.x, t = threadIdx.x;
    __shared__ float fin[512];
    __shared__ float f2s[256];
    __shared__ int sbf;
    if (t == 0) sbf = det_isbf(dp);
    for (int u = t; u < 512; u += 256) fin[u] = f1[b * 512 + u];
    __syncthreads();
    {
        float acc = 0.f;
        for (int c = 0; c < 512; c++) acc += fin[c] * l2wT[(size_t)c * 256 + t];
        acc += l2b[t];
        float h = acc * (g7[t] * BN_SCALE) + b7[t];
        f2s[t] = h >= 0.f ? h : 0.2f * h;
    }
    __syncthreads();
    if (t < 40) {
        float acc = 0.f;
        for (int c = 0; c < 256; c++) acc += f2s[c] * l3wT[(size_t)c * 40 + t];
        acc += l3b[t];
        if (sbf) ((__hip_bfloat16*)out)[b * 40 + t] = __float2bfloat16(acc);
        else     ((float*)out)[b * 40 + t] = acc;
    }
}

// ================================================================ host
extern "C" void kernel_launch(void* const* d_in, const int* in_sizes, int n_in,
                              void* d_out, int out_size, void* d_ws, size_t ws_size,
                              hipStream_t stream) {
    auto us = [&](int i) { return (const unsigned short*)d_in[i]; };

    float* ws = (float*)d_ws;
    size_t off = 0;
    auto A = [&](size_t n) { float* p = ws + off; off += (n + 3) & ~(size_t)3; return p; };
    auto AU = [&](size_t n) { return (unsigned short*)A((n + 1) / 2); };
    float* x1   = A((size_t)BN_ * 64);
    float* x2   = A((size_t)BN_ * 64);
    float* x3   = A((size_t)BN_ * 128);
    float* x4   = A((size_t)BN_ * 256);
    float* pd   = A((size_t)BN_ * 1024);   // pd scratch
    float* f1   = A(8 * 512);
    float* xx   = A(4 * BN_);              // per-layer row norms (xx2..4 atomic, pre-zeroed)
    int*   idx  = (int*)A((size_t)BN_ * K_);
    float* qkvw = A((size_t)BN_ * 768);   // qkv / yz / knn-split scratch
    // bf16 activation copies
    unsigned short* xf0b = AU((size_t)BN_ * 3);
    unsigned short* x1b  = AU((size_t)BN_ * 64);
    unsigned short* x2b  = AU((size_t)BN_ * 64);
    unsigned short* x3b  = AU((size_t)BN_ * 128);
    unsigned short* x4b  = AU((size_t)BN_ * 256);
    unsigned short* owb  = AU((size_t)BN_ * 256);
    // pooled reductions (conv5 fused epilogue) -- contiguous, zeroed by k_prep
    unsigned* pmaxu = (unsigned*)A(8 * 1024);
    float*    psum  = A(8 * 1024);
    // bf16 weights (n,k) layouts
    unsigned short* w1yzb = AU(128 * 3);
    unsigned short* w2yzb = AU(128 * 64);
    unsigned short* w3yzb = AU(256 * 64);
    unsigned short* w4yzb = AU(512 * 128);
    unsigned short* a1wib = AU(192 * 64);  unsigned short* a1wob = AU(64 * 64);
    unsigned short* a2wib = AU(192 * 64);  unsigned short* a2wob = AU(64 * 64);
    unsigned short* a3wib = AU(384 * 128); unsigned short* a3wob = AU(128 * 128);
    unsigned short* a4wib = AU(768 * 256); unsigned short* a4wob = AU(256 * 256);
    unsigned short* w5b   = AU(1024 * 512);
    // fp32 fc weights (transposed)
    float* l1wT  = A(2048 * 512);
    float* l2wT  = A(512 * 256);
    float* l3wT  = A(256 * 40);
    // converted vectors (fp32)
    float* g1f = A(64);   float* b1f = A(64);
    float* g2f = A(64);   float* b2f = A(64);
    float* g3f = A(128);  float* b3f = A(128);
    float* g4f = A(256);  float* b4f = A(256);
    float* bi1 = A(192);  float* bo1 = A(64);
    float* bi2 = A(192);  float* bo2 = A(64);
    float* bi3 = A(384);  float* bo3 = A(128);
    float* bi4 = A(768);  float* bo4 = A(256);
    float* g5f = A(1024); float* b5f = A(1024);
    float* g6f = A(512);  float* b6f = A(512);
    float* l2bf = A(256);
    float* g7f = A(256);  float* b7f = A(256);
    float* l3bf = A(40);

    float* xx1 = xx;              float* xx2 = xx + BN_;
    float* xx3 = xx + 2 * BN_;    float* xx4 = xx + 3 * BN_;

    // knn split buffers alias qkvw (dead during the kNN phase of each layer);
    // 3-seg split: max KP = 384 -> xa/xb each BN_*384 u16 (12.6 MB < 25 MB).
    unsigned short* xa = (unsigned short*)qkvw;
    unsigned short* xb = (unsigned short*)qkvw + (size_t)BN_ * 384;

    DetP dp{{us(2), us(5), us(8), us(11), us(30), us(33), us(37)}};

    TList tl; int nb = 0; int k = 0;
    auto add = [&](int i, void* dst, int O, int I, int mode) {
        tl.p[k].src = d_in[i]; tl.p[k].dst = dst; tl.p[k].O = O; tl.p[k].I = I;
        tl.p[k].blk0 = nb; tl.p[k].mode = mode;
        nb += (O * I + 255) / 256; k++;
    };
    add(0,  xf0b,  BN_ * 3, 1, 2);
    add(0,  pmaxu, 16384, 1, 4);      // zero pmaxu+psum (contiguous)
    add(0,  xx2,   3 * BN_, 1, 4);    // zero xx2..xx4 (atomic targets)
    add(1,  w1yzb, 64, 6, 3);
    add(4,  w2yzb, 64, 128, 3);
    add(7,  w3yzb, 128, 128, 3);
    add(10, w4yzb, 256, 256, 3);
    add(13, a1wib, 192, 64, 2);
    add(15, a1wob, 64, 64, 2);
    add(17, a2wib, 192, 64, 2);
    add(19, a2wob, 64, 64, 2);
    add(21, a3wib, 384, 128, 2);
    add(23, a3wob, 128, 128, 2);
    add(25, a4wib, 768, 256, 2);
    add(27, a4wob, 256, 256, 2);
    add(29, w5b,   1024, 512, 2);
    add(2,  g1f, 64, 1, 0);   add(3,  b1f, 64, 1, 0);
    add(5,  g2f, 64, 1, 0);   add(6,  b2f, 64, 1, 0);
    add(8,  g3f, 128, 1, 0);  add(9,  b3f, 128, 1, 0);
    add(11, g4f, 256, 1, 0);  add(12, b4f, 256, 1, 0);
    add(14, bi1, 192, 1, 0);  add(16, bo1, 64, 1, 0);
    add(18, bi2, 192, 1, 0);  add(20, bo2, 64, 1, 0);
    add(22, bi3, 384, 1, 0);  add(24, bo3, 128, 1, 0);
    add(26, bi4, 768, 1, 0);  add(28, bo4, 256, 1, 0);
    add(30, g5f, 1024, 1, 0); add(31, b5f, 1024, 1, 0);
    add(33, g6f, 512, 1, 0);  add(34, b6f, 512, 1, 0);
    add(36, l2bf, 256, 1, 0);
    add(37, g7f, 256, 1, 0);  add(38, b7f, 256, 1, 0);
    add(40, l3bf, 40, 1, 0);

    // FC-weight transposes + layer-1 split/norms fused into k_prep tail blocks
    TrP tp1{d_in[32], l1wT, 512, 2048, 2048 / 32, 0};
    TrP tp2{d_in[35], l2wT, 256, 512,  512 / 32,  (2048 / 32) * (512 / 32)};
    TrP tp3{d_in[39], l3wT, 40,  256,  256 / 32,  tp2.blk0 + (512 / 32) * (256 / 32)};
    const int trblocks = tp3.blk0 + (256 / 32) * ((40 + 31) / 32);
    const int splblocks = (BN_ * 32) / 256 + 32;   // split + norms
    k_prep<<<nb + trblocks + splblocks, 256, 0, stream>>>(
        tl, k, tp1, tp2, tp3, nb, trblocks, d_in[0], dp, xa, xb, xx1);

    float* yzb = qkvw;                 // fp32 yz scratch (after kNN phase)
    const dim3 pdmg(8, 8, 8);          // 128x128 tiles per batch
    const unsigned short* N0 = nullptr;
    unsigned short* U0 = nullptr;
    unsigned* NU = nullptr; float* NF = nullptr;

    // layer 1  (C=3 -> 64)
    k_pdm<32, 128, 128><<<pdmg, 256, 0, stream>>>(xa, xb, xx1, pd);
    k_selyz<3, 128, 64, 64><<<2048 + 256, 256, 0, stream>>>(pd, idx, 2048, 128, xf0b, w1yzb, yzb);
    k_edgemax<64><<<BN_ / 16, 256, 0, stream>>>(yzb, idx, g1f, b1f, x1, x1b);
    k_gemmb<64, 192, 64, 64><<<dim3(128, 3), 256, 0, stream>>>(x1b, N0, N0, N0, a1wib, bi1, nullptr, qkvw, 64, 0.25f, nullptr, nullptr, nullptr, NU, NF, U0, U0, NF);
    k_attn<64><<<N_, 256, 0, stream>>>(qkvw, owb);
    k_gemmb<64, 64, 64, 64, false, false, 64><<<dim3(128, 1), 256, 0, stream>>>(owb, N0, N0, N0, a1wob, bo1, x1, x1, 0, 1.f, nullptr, nullptr, x1b, NU, NF, xa, xb, xx2);

    // layer 2  (C=64 -> 64, KP=192)
    k_pdm<192, 128, 128><<<pdmg, 256, 0, stream>>>(xa, xb, xx2, pd);
    k_selyz<64, 128, 64, 64><<<2048 + 256, 256, 0, stream>>>(pd, idx, 2048, 128, x1b, w2yzb, yzb);
    k_edgemax<64><<<BN_ / 16, 256, 0, stream>>>(yzb, idx, g2f, b2f, x2, x2b);
    k_gemmb<64, 192, 64, 64><<<dim3(128, 3), 256, 0, stream>>>(x2b, N0, N0, N0, a2wib, bi2, nullptr, qkvw, 64, 0.25f, nullptr, nullptr, nullptr, NU, NF, U0, U0, NF);
    k_attn<64><<<N_, 256, 0, stream>>>(qkvw, owb);
    k_gemmb<64, 64, 64, 64, false, false, 64><<<dim3(128, 1), 256, 0, stream>>>(owb, N0, N0, N0, a2wob, bo2, x2, x2, 0, 1.f, nullptr, nullptr, x2b, NU, NF, xa, xb, xx3);

    // layer 3  (C=64 -> 128, KP=192)
    k_pdm<192, 128, 128><<<pdmg, 256, 0, stream>>>(xa, xb, xx3, pd);
    k_selyz<64, 256, 64, 64><<<2048 + 512, 256, 0, stream>>>(pd, idx, 2048, 128, x2b, w3yzb, yzb);
    k_edgemax<128><<<BN_ / 8, 256, 0, stream>>>(yzb, idx, g3f, b3f, x3, x3b);
    k_gemmb<128, 384, 64, 128><<<dim3(128, 3), 256, 0, stream>>>(x3b, N0, N0, N0, a3wib, bi3, nullptr, qkvw, 128, 0.17677669529663687f, nullptr, nullptr, nullptr, NU, NF, U0, U0, NF);
    k_attn<128><<<N_, 256, 0, stream>>>(qkvw, owb);
    k_gemmb<128, 128, 64, 64, false, false, 128><<<dim3(128, 2), 256, 0, stream>>>(owb, N0, N0, N0, a3wob, bo3, x3, x3, 0, 1.f, nullptr, nullptr, x3b, NU, NF, xa, xb, xx4);

    // layer 4  (C=128 -> 256, KP=384)
    k_pdm<384, 128, 128><<<pdmg, 256, 0, stream>>>(xa, xb, xx4, pd);
    k_selyz<128, 512, 128, 128><<<2048 + 256, 256, 0, stream>>>(pd, idx, 2048, 64, x3b, w4yzb, yzb);
    k_edgemax<256><<<BN_ / 4, 256, 0, stream>>>(yzb, idx, g4f, b4f, x4, x4b);
    k_gemmb<256, 768, 128, 128><<<dim3(64, 6), 256, 0, stream>>>(x4b, N0, N0, N0, a4wib, bi4, nullptr, qkvw, 256, 0.125f, nullptr, nullptr, nullptr, NU, NF, U0, U0, NF);
    k_attn<256><<<N_, 256, 0, stream>>>(qkvw, owb);
    k_gemmb<256, 256, 64, 128><<<dim3(128, 2), 256, 0, stream>>>(owb, N0, N0, N0, a4wob, bo4, x4, x4, 0, 1.f, nullptr, nullptr, x4b, NU, NF, U0, U0, NF);

    // head: conv5 with fused concat-A and fused pooling epilogue
    k_gemmb<512, 1024, 128, 128, true, true><<<dim3(64, 8), 256, 0, stream>>>(
        x1b, x2b, x3b, x4b, w5b, nullptr, nullptr, nullptr, 0, 1.f, g5f, b5f, nullptr, pmaxu, psum, U0, U0, NF);
    k_fc1<<<dim3(8, 8), 256, 0, stream>>>(pmaxu, psum, l1wT, g6f, b6f, f1);
    k_fc23<<<8, 256, 0, stream>>>(f1, l2wT, l2bf, g7f, b7f, l3wT, l3bf, d_out, dp);
}

// Round 10
// 510.817 us; speedup vs baseline: 1.3179x; 1.0287x over previous
//
#include <hip/hip_runtime.h>
#include <hip/hip_bf16.h>

#define B_ 8
#define N_ 1024
#define K_ 20
#define BN_ (B_*N_)

#define BN_SCALE 0.9999950000374997f

typedef __attribute__((ext_vector_type(8))) short short8;
typedef __attribute__((ext_vector_type(4))) float f32x4;

__device__ __forceinline__ float US2F(unsigned short u) {
    union { unsigned u; float f; } c; c.u = ((unsigned)u) << 16; return c.f;
}
__device__ __forceinline__ unsigned short F2BF(float f) {   // RNE fp32->bf16
    union { float f; unsigned u; } c; c.f = f;
    unsigned r = c.u + 0x7FFF + ((c.u >> 16) & 1);
    return (unsigned short)(r >> 16);
}

// async global->LDS 16B DMA: LDS dest = wave-uniform base + lane*16 (linear);
// global source is per-lane (pre-swizzled there when a swizzled layout is wanted).
__device__ __forceinline__ void ldsld16(const unsigned short* g, unsigned short* l) {
    __builtin_amdgcn_global_load_lds(
        (const __attribute__((address_space(1))) void*)g,
        (__attribute__((address_space(3))) void*)l, 16, 0, 0);
}

// dtype-detect data: first element of 7 gamma vectors (bf16 gammas ~1.0)
struct DetP { const unsigned short* g[7]; };
__device__ __forceinline__ int det_isbf(const DetP& dp) {
    int cnt = 0;
    #pragma unroll
    for (int i = 0; i < 7; i++) {
        float v = US2F(dp.g[i][0]);
        if (v > 0.5f && v < 1.5f) cnt++;
    }
    return cnt >= 4;
}

// ---------------------------------------------------------------- prep (+ transposes + L1 split)
// Region 1 [0,nbp): table entries -- mode 0: fp32 copy (I==1); mode 2: bf16
// copy; mode 3: edge pair -> bf16 (2O,C); mode 4: zero-fill fp32.
// Region 2 [nbp,nbp+nbtr): LDS-tiled 32x32 fp32 transposes (FC weights).
// Region 3 [nbp+nbtr,..): layer-1 kNN split (reads d_in[0] directly, C=3,
// KP=32, 3-seg exact-split) + row norms xx1.  Dtype flag computed inline.
struct TPar { const void* src; void* dst; int O, I, blk0, mode; };
struct TList { TPar p[44]; };
struct TrP { const void* src; float* dst; int O, I, bx, blk0; };

__global__ __launch_bounds__(256) void k_prep(TList tl, int nent,
                                              TrP q0, TrP q1, TrP q2,
                                              int nbp, int nbtr,
                                              const void* x0, DetP dp,
                                              unsigned short* __restrict__ xa,
                                              unsigned short* __restrict__ xb,
                                              float* __restrict__ xx1) {
    __shared__ int sbf;
    if (threadIdx.x == 0) sbf = det_isbf(dp);
    __syncthreads();
    const int isbf = sbf;
    auto ld0 = [&](int idx) {
        return isbf ? US2F(((const unsigned short*)x0)[idx])
                    : ((const float*)x0)[idx];
    };
    const int bid = blockIdx.x;
    if (bid >= nbp + nbtr) {               // ---- region 3: L1 split + norms
        int blk = bid - nbp - nbtr;
        if (blk >= (BN_ * 32) / 256) {     // norms (32 blocks)
            int i = (blk - (BN_ * 32) / 256) * 256 + threadIdx.x;
            if (i >= BN_) return;
            float s = 0.f;
            #pragma unroll
            for (int c = 0; c < 3; c++) { float v = ld0(i * 3 + c); s += v * v; }
            xx1[i] = s;
            return;
        }
        const int e = blk * 256 + threadIdx.x;   // e < BN_*32
        const int i = e >> 5, p = e & 31;
        unsigned short va = 0, vb = 0;
        if (p < 9) {                        // 3 segs x C=3
            const int seg = p / 3, c = p - seg * 3;
            const float v = ld0(i * 3 + c);
            const unsigned short h = F2BF(v);
            const unsigned short l = F2BF(v - US2F(h));
            va = (seg == 1) ? l : h;        // hi,lo,hi
            vb = (seg < 2) ? h : l;         // hi,hi,lo
        }
        xa[e] = va; xb[e] = vb;
        return;
    }
    if (bid >= nbp) {                      // ---- region 2: transposes
        int blk = bid - nbp;
        TrP p = q0;
        if (blk >= q2.blk0) p = q2; else if (blk >= q1.blk0) p = q1;
        blk -= p.blk0;
        const int tx = threadIdx.x & 31, ty = threadIdx.x >> 5;   // 32 x 8
        const int bi = blk % p.bx, bo = blk / p.bx;
        const int i0 = bi * 32, o0 = bo * 32;
        __shared__ float s[32][33];
        #pragma unroll
        for (int r = 0; r < 4; r++) {
            const int o = o0 + ty + r * 8, i = i0 + tx;
            if (o < p.O && i < p.I) {
                const size_t e = (size_t)o * p.I + i;
                s[ty + r * 8][tx] = isbf ? US2F(((const unsigned short*)p.src)[e])
                                         : ((const float*)p.src)[e];
            }
        }
        __syncthreads();
        #pragma unroll
        for (int r = 0; r < 4; r++) {
            const int i = i0 + ty + r * 8, o = o0 + tx;
            if (i < p.I && o < p.O) p.dst[(size_t)i * p.O + o] = s[tx][ty + r * 8];
        }
        return;
    }
    int blk = bid;                          // ---- region 1: entries
    int wi = 0;
    for (int j = nent - 1; j >= 0; j--) { if (blk >= tl.p[j].blk0) { wi = j; break; } }
    const TPar p = tl.p[wi];
    int e = (blk - p.blk0) * 256 + threadIdx.x;
    int n = p.O * p.I;
    if (e >= n) return;
    if (p.mode == 4) { ((float*)p.dst)[e] = 0.f; return; }
    int o = e / p.I, i = e - o * p.I;
    float v = isbf ? US2F(((const unsigned short*)p.src)[e])
                   : ((const float*)p.src)[e];
    if (p.mode == 0) {
        ((float*)p.dst)[(size_t)i * p.O + o] = v;
    } else if (p.mode == 2) {
        ((unsigned short*)p.dst)[e] = F2BF(v);
    } else {
        const int C = p.I >> 1;
        if (i < C) ((unsigned short*)p.dst)[(size_t)o * C + i] = F2BF(v);
        else       ((unsigned short*)p.dst)[(size_t)(p.O + o) * C + (i - C)] = F2BF(v);
    }
}

// ---------------------------------------------------------------- kNN phase 1 (MFMA):
// pd[b][i][j] = 2*dot(xa_i, xb_j) - xx_j.  3-seg exact-split over KP=3C
// (dropped lo.lo term ~2^-18, below the key's 2^-14 truncation).  128x128
// tile, global_load_lds + source 16B-granule XOR swizzle, 2-phase dbuf.
// NOTE (R5/R6): fused pdm+sel (1 block/CU) measured 70-79us/layer --
// selection needs k_sel's 32-waves/CU TLP.  Keep the two-kernel form.
template<int KP, int TM, int TN>
__global__ __launch_bounds__(256) void k_pdm(const unsigned short* __restrict__ xa,
                                             const unsigned short* __restrict__ xb,
                                             const float* __restrict__ xx,
                                             float* __restrict__ pd) {
    const int b = blockIdx.z;
    const int rb = blockIdx.x * TM, cb = blockIdx.y * TN;
    const unsigned short* Ab = xa + (size_t)b * N_ * KP;
    const unsigned short* Bb = xb + (size_t)b * N_ * KP;
    const float* xxb = xx + (size_t)b * N_;
    const int t = threadIdx.x;
    __shared__ __align__(16) unsigned short As[2][TM * 32];
    __shared__ __align__(16) unsigned short Bs[2][TN * 32];
    const int w = t >> 6, lane = t & 63;
    constexpr int QR = TM / 2, QC = TN / 2;
    constexpr int MR = QR / 16, NR = QC / 16;
    const int wr = (w & 1) * QR, wc = (w >> 1) * QC;
    const int fr = lane & 15, q = lane >> 4;
    f32x4 acc[MR][NR] = {};

    auto STAGE = [&](int buf, int k0) {
        constexpr int AT = TM * 4;
        #pragma unroll
        for (int R = 0; R < (AT + 255) / 256; R++) {
            const int G = t + R * 256;
            if (AT >= (R + 1) * 256 || G < AT) {
                const int m = G >> 2, gs = (G & 3) ^ ((m >> 1) & 3);
                ldsld16(&Ab[(size_t)(rb + m) * KP + k0 + gs * 8], &As[buf][w * 512 + R * 2048]);
            }
        }
        constexpr int BT = TN * 4;
        #pragma unroll
        for (int R = 0; R < (BT + 255) / 256; R++) {
            const int G = t + R * 256;
            if (BT >= (R + 1) * 256 || G < BT) {
                const int n = G >> 2, gs = (G & 3) ^ ((n >> 1) & 3);
                ldsld16(&Bb[(size_t)(cb + n) * KP + k0 + gs * 8], &Bs[buf][w * 512 + R * 2048]);
            }
        }
    };

    constexpr int NT = KP / 32;
    STAGE(0, 0);
    asm volatile("s_waitcnt vmcnt(0)" ::: "memory");
    __builtin_amdgcn_s_barrier();
    int cur = 0;
    for (int ts = 0; ts < NT; ++ts) {
        if (ts + 1 < NT) STAGE(cur ^ 1, (ts + 1) * 32);
        short8 af[MR], bfr[NR];
        #pragma unroll
        for (int mi = 0; mi < MR; mi++) {
            const int r = wr + mi * 16 + fr;
            af[mi] = *reinterpret_cast<const short8*>(&As[cur][r * 32 + ((q ^ ((r >> 1) & 3)) << 3)]);
        }
        #pragma unroll
        for (int ni = 0; ni < NR; ni++) {
            const int r = wc + ni * 16 + fr;
            bfr[ni] = *reinterpret_cast<const short8*>(&Bs[cur][r * 32 + ((q ^ ((r >> 1) & 3)) << 3)]);
        }
        #pragma unroll
        for (int mi = 0; mi < MR; mi++) {
            #pragma unroll
            for (int ni = 0; ni < NR; ni++)
                acc[mi][ni] = __builtin_amdgcn_mfma_f32_16x16x32_bf16(af[mi], bfr[ni], acc[mi][ni], 0, 0, 0);
        }
        asm volatile("s_waitcnt vmcnt(0)" ::: "memory");
        __builtin_amdgcn_s_barrier();
        cur ^= 1;
    }
    float* pdb = pd + (size_t)b * N_ * N_;
    const int cr = (lane >> 4) * 4, cc = lane & 15;
    #pragma unroll
    for (int mi = 0; mi < MR; mi++) {
        #pragma unroll
        for (int ni = 0; ni < NR; ni++) {
            #pragma unroll
            for (int r = 0; r < 4; r++) {
                const int row = rb + wr + mi * 16 + cr + r;
                const int col = cb + wc + ni * 16 + cc;
                pdb[(size_t)row * N_ + col] = 2.f * acc[mi][ni][r] - xxb[col];
            }
        }
    }
}

// ---------------------------------------------------------------- kNN phase 2 (device body)
// 32-bit key top-20; 2048 sel blocks -> 32 waves/CU hides the serial 20-round
// chain (R5/R6 lesson).
__device__ __forceinline__ void sel_dev(const float* __restrict__ pd,
                                        int* __restrict__ idx, int blk) {
    const int w = threadIdx.x >> 6, lane = threadIdx.x & 63;
    const int i = blk * 4 + w;                 // 0..8191
    const int b = i >> 10;
    const float* row = pd + (size_t)b * N_ * N_ + (size_t)(i & 1023) * N_;
    unsigned key[16];
    #pragma unroll
    for (int q = 0; q < 16; q++) {
        const int j = q * 64 + lane;
        unsigned bits = __float_as_uint(row[j]);
        bits = (bits & 0x80000000u) ? ~bits : (bits | 0x80000000u);
        key[q] = (bits & 0xFFFFFC00u) | (unsigned)(N_ - 1 - j);
    }
    int myj = 0;
    for (int kk = 0; kk < K_; kk++) {
        unsigned m = key[0];
        #pragma unroll
        for (int u = 1; u < 16; u++) m = key[u] > m ? key[u] : m;
        #pragma unroll
        for (int s = 1; s < 64; s <<= 1) {
            unsigned o = (unsigned)__shfl_xor((int)m, s, 64);
            m = o > m ? o : m;
        }
        const int j = N_ - 1 - (int)(m & 1023u);
        if (lane == kk) myj = j;
        #pragma unroll
        for (int u = 0; u < 16; u++)
            if (key[u] == m) key[u] = 0u;      // below any plausible real key
    }
    if (lane < K_) idx[(size_t)i * K_ + lane] = myj;
}

// ---------------------------------------------------------------- MFMA bf16 GEMM (device body)
// C[8192][NC] = A[8192][KD] @ Bw^T.  KD%32==0: global_load_lds dwordx4 into
// linear [T][32] LDS, source-side 16B-granule XOR swizzle, 2-phase dbuf.
// CATA: A = virtual concat [x1b|x2b|x3b|x4b].  POOL: fused BN+LReLU+max/sum
// pooling epilogue (atomics).  SPLIT=C>0: epilogue also emits next layer's
// 3-seg kNN split + row norms.  yco>0: yz-GEMM column routing -- col<yco ->
// Cout (y array, dense CO rows for the edgemax gather), else Cz (z array).
template<int KD, int NC, int TM, int TN, bool CATA, bool POOL, int SPLIT>
__device__ __forceinline__ void gemm_dev(int bx, int by,
                                         const unsigned short* __restrict__ A,
                                         const unsigned short* __restrict__ A2,
                                         const unsigned short* __restrict__ A3,
                                         const unsigned short* __restrict__ A4,
                                         const unsigned short* __restrict__ Bw,
                                         const float* __restrict__ bias,
                                         const float* __restrict__ resid,
                                         float* __restrict__ Cout,
                                         float* __restrict__ Cz, int yco,
                                         int scale_cols, float qs,
                                         const float* __restrict__ gamma,
                                         const float* __restrict__ beta,
                                         unsigned short* __restrict__ obf,
                                         unsigned* __restrict__ pmaxu,
                                         float* __restrict__ psum,
                                         unsigned short* __restrict__ sxa,
                                         unsigned short* __restrict__ sxb,
                                         float* __restrict__ xxo) {
    const int t = threadIdx.x;
    const int rb = bx * TM, cb = by * TN;
    const int w = t >> 6, lane = t & 63;
    constexpr int QR = TM / 2, QC = TN / 2;
    constexpr int MR = QR / 16, NR = QC / 16;
    const int wr = (w & 1) * QR, wc = (w >> 1) * QC;
    const int fr = lane & 15, q = lane >> 4, fq = q * 8;
    f32x4 acc[MR][NR] = {};
    if constexpr (KD % 32 == 0) {
        __shared__ __align__(16) unsigned short As[2][TM * 32];
        __shared__ __align__(16) unsigned short Bs[2][TN * 32];
        auto STAGE = [&](int buf, int k0) {
            const unsigned short* Asrc = A; int AC = KD, ac0 = k0;
            if constexpr (CATA) {
                if (k0 >= 256)      { Asrc = A4; AC = 256; ac0 = k0 - 256; }
                else if (k0 >= 128) { Asrc = A3; AC = 128; ac0 = k0 - 128; }
                else if (k0 >= 64)  { Asrc = A2; AC = 64;  ac0 = k0 - 64; }
                else                { Asrc = A;  AC = 64;  ac0 = k0; }
            }
            constexpr int AT = TM * 4;
            #pragma unroll
            for (int R = 0; R < (AT + 255) / 256; R++) {
                const int G = t + R * 256;
                if (AT >= (R + 1) * 256 || G < AT) {
                    const int m = G >> 2, gs = (G & 3) ^ ((m >> 1) & 3);
                    ldsld16(&Asrc[(size_t)(rb + m) * AC + ac0 + gs * 8], &As[buf][w * 512 + R * 2048]);
                }
            }
            constexpr int BT = TN * 4;
            #pragma unroll
            for (int R = 0; R < (BT + 255) / 256; R++) {
                const int G = t + R * 256;
                if (BT >= (R + 1) * 256 || G < BT) {
                    const int n = G >> 2, gs = (G & 3) ^ ((n >> 1) & 3);
                    ldsld16(&Bw[(size_t)(cb + n) * KD + k0 + gs * 8], &Bs[buf][w * 512 + R * 2048]);
                }
            }
        };
        constexpr int NT = KD / 32;
        STAGE(0, 0);
        asm volatile("s_waitcnt vmcnt(0)" ::: "memory");
        __builtin_amdgcn_s_barrier();
        int cur = 0;
        for (int ts = 0; ts < NT; ++ts) {
            if (ts + 1 < NT) STAGE(cur ^ 1, (ts + 1) * 32);
            short8 af[MR], bfr[NR];
            #pragma unroll
            for (int mi = 0; mi < MR; mi++) {
                const int r = wr + mi * 16 + fr;
                af[mi] = *reinterpret_cast<const short8*>(&As[cur][r * 32 + ((q ^ ((r >> 1) & 3)) << 3)]);
            }
            #pragma unroll
            for (int ni = 0; ni < NR; ni++) {
                const int r = wc + ni * 16 + fr;
                bfr[ni] = *reinterpret_cast<const short8*>(&Bs[cur][r * 32 + ((q ^ ((r >> 1) & 3)) << 3)]);
            }
            #pragma unroll
            for (int mi = 0; mi < MR; mi++) {
                #pragma unroll
                for (int ni = 0; ni < NR; ni++)
                    acc[mi][ni] = __builtin_amdgcn_mfma_f32_16x16x32_bf16(af[mi], bfr[ni], acc[mi][ni], 0, 0, 0);
            }
            asm volatile("s_waitcnt vmcnt(0)" ::: "memory");
            __builtin_amdgcn_s_barrier();
            cur ^= 1;
        }
    } else {
        // fallback (KD=3): reg-staged, padded LDS, scalar guarded loads
        __shared__ __align__(16) unsigned short As[TM * 40];
        __shared__ __align__(16) unsigned short Bs[TN * 40];
        for (int k0 = 0; k0 < KD; k0 += 32) {
            __syncthreads();
            #pragma unroll
            for (int u = t; u < TM * 4; u += 256) {
                const int m = u >> 2, c = (u & 3) * 8;
                #pragma unroll
                for (int j = 0; j < 8; j++) {
                    const int kk = k0 + c + j;
                    As[m * 40 + c + j] = (kk < KD) ? A[(size_t)(rb + m) * KD + kk] : (unsigned short)0;
                }
            }
            #pragma unroll
            for (int u = t; u < TN * 4; u += 256) {
                const int n = u >> 2, c = (u & 3) * 8;
                const int gn = cb + n;
                if (gn < NC) {
                    #pragma unroll
                    for (int j = 0; j < 8; j++) {
                        const int kk = k0 + c + j;
                        Bs[n * 40 + c + j] = (kk < KD) ? Bw[(size_t)gn * KD + kk] : (unsigned short)0;
                    }
                } else {
                    short8 z = {};
                    *reinterpret_cast<short8*>(&Bs[n * 40 + c]) = z;
                }
            }
            __syncthreads();
            short8 af[MR], bfr[NR];
            #pragma unroll
            for (int mi = 0; mi < MR; mi++)
                af[mi] = *reinterpret_cast<const short8*>(&As[(wr + mi * 16 + fr) * 40 + fq]);
            #pragma unroll
            for (int ni = 0; ni < NR; ni++)
                bfr[ni] = *reinterpret_cast<const short8*>(&Bs[(wc + ni * 16 + fr) * 40 + fq]);
            #pragma unroll
            for (int mi = 0; mi < MR; mi++) {
                #pragma unroll
                for (int ni = 0; ni < NR; ni++)
                    acc[mi][ni] = __builtin_amdgcn_mfma_f32_16x16x32_bf16(af[mi], bfr[ni], acc[mi][ni], 0, 0, 0);
            }
        }
    }
    const int cr = (lane >> 4) * 4, cc = lane & 15;
    if constexpr (POOL) {
        const int bidx = rb >> 10;
        #pragma unroll
        for (int ni = 0; ni < NR; ni++) {
            const int col = cb + wc + ni * 16 + cc;
            const float gm = gamma[col] * BN_SCALE, bt = beta[col];
            float sm = 0.f, mxv = -3e38f;
            #pragma unroll
            for (int mi = 0; mi < MR; mi++) {
                #pragma unroll
                for (int r = 0; r < 4; r++) {
                    float v = acc[mi][ni][r] * gm + bt;
                    v = v >= 0.f ? v : 0.2f * v;
                    sm += v; mxv = fmaxf(mxv, v);
                }
            }
            sm += __shfl_xor(sm, 16, 64);
            sm += __shfl_xor(sm, 32, 64);
            mxv = fmaxf(mxv, __shfl_xor(mxv, 16, 64));
            mxv = fmaxf(mxv, __shfl_xor(mxv, 32, 64));
            if (lane < 16) {
                atomicAdd(&psum[bidx * 1024 + col], sm);
                unsigned tb = __float_as_uint(mxv);
                tb = (tb & 0x80000000u) ? ~tb : (tb | 0x80000000u);
                atomicMax(&pmaxu[bidx * 1024 + col], tb);
            }
        }
    } else {
        float sx[MR][4] = {};
        #pragma unroll
        for (int mi = 0; mi < MR; mi++) {
            #pragma unroll
            for (int ni = 0; ni < NR; ni++) {
                #pragma unroll
                for (int r = 0; r < 4; r++) {
                    const int row = rb + wr + mi * 16 + cr + r;
                    const int col = cb + wc + ni * 16 + cc;
                    if (col < NC) {
                        float v = acc[mi][ni][r] + (bias ? bias[col] : 0.f);
                        if (col < scale_cols) v *= qs;
                        if (resid) v += resid[(size_t)row * NC + col];
                        if (gamma) {
                            v = v * (gamma[col] * BN_SCALE) + beta[col];
                            v = v >= 0.f ? v : 0.2f * v;
                        }
                        if (yco > 0) {
                            if (col < yco) Cout[(size_t)row * yco + col] = v;
                            else           Cz[(size_t)row * yco + (col - yco)] = v;
                        } else {
                            Cout[(size_t)row * NC + col] = v;
                        }
                        if (obf) obf[(size_t)row * NC + col] = F2BF(v);
                        if constexpr (SPLIT > 0) {
                            constexpr int KP2 = 3 * SPLIT;
                            const unsigned short h = F2BF(v);
                            const unsigned short l = F2BF(v - US2F(h));
                            sxa[(size_t)row * KP2 + 0 * SPLIT + col] = h;
                            sxa[(size_t)row * KP2 + 1 * SPLIT + col] = l;
                            sxa[(size_t)row * KP2 + 2 * SPLIT + col] = h;
                            sxb[(size_t)row * KP2 + 0 * SPLIT + col] = h;
                            sxb[(size_t)row * KP2 + 1 * SPLIT + col] = h;
                            sxb[(size_t)row * KP2 + 2 * SPLIT + col] = l;
                            sx[mi][r] += v * v;
                        }
                    }
                }
            }
        }
        if constexpr (SPLIT > 0) {
            // row-norm: reduce over the 16 col-lanes (same lane>>4 group = same rows)
            #pragma unroll
            for (int mi = 0; mi < MR; mi++) {
                #pragma unroll
                for (int r = 0; r < 4; r++) {
                    float s = sx[mi][r];
                    s += __shfl_xor(s, 1, 64);
                    s += __shfl_xor(s, 2, 64);
                    s += __shfl_xor(s, 4, 64);
                    s += __shfl_xor(s, 8, 64);
                    if ((lane & 15) == 0)
                        atomicAdd(&xxo[rb + wr + mi * 16 + cr + r], s);
                }
            }
        }
    }
}

template<int KD, int NC, int TM, int TN, bool CATA = false, bool POOL = false, int SPLIT = 0>
__global__ __launch_bounds__(256) void k_gemmb(const unsigned short* __restrict__ A,
                                               const unsigned short* __restrict__ A2,
                                               const unsigned short* __restrict__ A3,
                                               const unsigned short* __restrict__ A4,
                                               const unsigned short* __restrict__ Bw,
                                               const float* __restrict__ bias,
                                               const float* __restrict__ resid,
                                               float* __restrict__ Cout,
                                               int scale_cols, float qs,
                                               const float* __restrict__ gamma,
                                               const float* __restrict__ beta,
                                               unsigned short* __restrict__ obf,
                                               unsigned* __restrict__ pmaxu,
                                               float* __restrict__ psum,
                                               unsigned short* __restrict__ sxa,
                                               unsigned short* __restrict__ sxb,
                                               float* __restrict__ xxo) {
    gemm_dev<KD, NC, TM, TN, CATA, POOL, SPLIT>(blockIdx.x, blockIdx.y,
        A, A2, A3, A4, Bw, bias, resid, Cout, nullptr, 0, scale_cols, qs, gamma, beta,
        obf, pmaxu, psum, sxa, sxb, xxo);
}

// ---------------------------------------------------------------- combined sel || yz-GEMM
// k_sel (latency-bound, reads pd) and the yz edge-feature GEMM (reads x_prev,
// independent of pd) run concurrently in one launch: blocks [0,selb) = sel,
// the rest = gemm (flattened 2D).  The gemm routes y-cols and z-cols to
// separate dense arrays (yco=CO) so the edgemax gather pulls pure-y rows.
template<int KD, int NC, int TM, int TN>
__global__ __launch_bounds__(256) void k_selyz(const float* __restrict__ pd,
                                               int* __restrict__ idx, int selb, int gx,
                                               const unsigned short* __restrict__ A,
                                               const unsigned short* __restrict__ Bw,
                                               float* __restrict__ Cy,
                                               float* __restrict__ Cz, int yco) {
    if ((int)blockIdx.x < selb) { sel_dev(pd, idx, blockIdx.x); return; }
    const int g = blockIdx.x - selb;
    gemm_dev<KD, NC, TM, TN, false, false, 0>(g % gx, g / gx,
        A, nullptr, nullptr, nullptr, Bw, nullptr, nullptr, Cy, Cz, yco, 0, 1.f,
        nullptr, nullptr, nullptr, nullptr, nullptr, nullptr, nullptr, nullptr);
}

// ---------------------------------------------------------------- EdgeConv epilogue (fp32 out + bf16 copy)
// y/z in separate dense [BN][CO] arrays: the 20-neighbor gather reads pure-y
// rows (half the traffic of the old interleaved yz).  XCD-locality swizzle:
// batch = blockIdx & 7 -- consecutive blockIdx round-robin XCDs (T1), so all
// blocks gathering batch b share one XCD whose L2 holds that batch's y-panel
// (1-2 MB << 4 MB) with ~20x reuse.
template<int CO>
__global__ __launch_bounds__(256) void k_edgemax(const float* __restrict__ y,
                                                 const float* __restrict__ z,
                                                 const int* __restrict__ idx,
                                                 const float* __restrict__ g,
                                                 const float* __restrict__ bb,
                                                 float* __restrict__ out,
                                                 unsigned short* __restrict__ outb) {
    constexpr int TPP = CO / 4;
    constexpr int PPB = 256 / TPP;
    const int t = threadIdx.x;
    const int p = t / TPP;
    const int cw = (t % TPP) * 4;
    const int batch = blockIdx.x & 7;
    const int within = blockIdx.x >> 3;
    const int i0 = batch * N_ + within * PPB;
    const int bbase = batch << 10;
    __shared__ int sidx[PPB][K_];
    for (int u = t; u < PPB * K_; u += 256) {
        int pp = u / K_, kk = u - pp * K_;
        sidx[pp][kk] = idx[(size_t)(i0 + pp) * K_ + kk];
    }
    __syncthreads();
    const int ig = i0 + p;
    float4 m = {-3e38f, -3e38f, -3e38f, -3e38f};
    #pragma unroll 4
    for (int k = 0; k < K_; k++) {
        const int jg = bbase + sidx[p][k];
        const float4 yv = *reinterpret_cast<const float4*>(&y[(size_t)jg * CO + cw]);
        m.x = fmaxf(m.x, yv.x); m.y = fmaxf(m.y, yv.y);
        m.z = fmaxf(m.z, yv.z); m.w = fmaxf(m.w, yv.w);
    }
    const float4 yi = *reinterpret_cast<const float4*>(&y[(size_t)ig * CO + cw]);
    const float4 zi = *reinterpret_cast<const float4*>(&z[(size_t)ig * CO + cw]);
    const float4 gv = *reinterpret_cast<const float4*>(&g[cw]);
    const float4 bv = *reinterpret_cast<const float4*>(&bb[cw]);
    float vals[4] = {m.x - yi.x + zi.x, m.y - yi.y + zi.y,
                     m.z - yi.z + zi.z, m.w - yi.w + zi.w};
    float gs[4] = {gv.x, gv.y, gv.z, gv.w};
    float bs[4] = {bv.x, bv.y, bv.z, bv.w};
    float4 o;
    float* op = &o.x;
    #pragma unroll
    for (int j = 0; j < 4; j++) {
        float h = vals[j] * (gs[j] * BN_SCALE) + bs[j];
        op[j] = h >= 0.f ? h : 0.2f * h;
    }
    *reinterpret_cast<float4*>(&out[(size_t)ig * CO + cw]) = o;
    #pragma unroll
    for (int j = 0; j < 4; j++) outb[(size_t)ig * CO + cw + j] = F2BF(op[j]);
}

// ---------------------------------------------------------------- attention (fp32 math, bf16 out)
template<int E>
__global__ __launch_bounds__(256) void k_attn(const float* __restrict__ qkv,
                                              unsigned short* __restrict__ o) {
    constexpr int H = 4, D = E / H, L = 8;
    const int n = blockIdx.x;
    const int t = threadIdx.x;
    const int h = t >> 6, lane = t & 63;
    __shared__ float sq[L][3 * E];
    __shared__ float so[L][E];
    for (int u = t; u < L * 3 * E; u += 256) {
        int l = u / (3 * E), r = u - l * (3 * E);
        sq[l][r] = qkv[(size_t)(l * N_ + n) * (3 * E) + r];
    }
    __syncthreads();
    const int l = lane >> 3, m = lane & 7;
    float s = 0.f;
    #pragma unroll 8
    for (int dd = 0; dd < D; dd++)
        s += sq[l][h * D + dd] * sq[m][E + h * D + dd];
    float mx = s;
    #pragma unroll
    for (int st = 1; st < 8; st <<= 1) mx = fmaxf(mx, __shfl_xor(mx, st, 64));
    float e = expf(s - mx);
    float sum = e;
    #pragma unroll
    for (int st = 1; st < 8; st <<= 1) sum += __shfl_xor(sum, st, 64);
    const float p = e / sum;
    float pm[8];
    #pragma unroll
    for (int mm = 0; mm < 8; mm++) pm[mm] = __shfl(p, (lane & 56) | mm, 64);
    #pragma unroll
    for (int j = 0; j < D / 8; j++) {
        const int dd = m + 8 * j;
        float a = 0.f;
        #pragma unroll
        for (int mm = 0; mm < 8; mm++) a += pm[mm] * sq[mm][2 * E + h * D + dd];
        so[l][h * D + dd] = a;
    }
    __syncthreads();
    for (int u = t; u < L * E; u += 256) {
        int l2 = u / E, e2 = u - l2 * E;
        o[(size_t)(l2 * N_ + n) * E + e2] = F2BF(so[l2][e2]);
    }
}

// ---------------------------------------------------------------- FC head
// fc1 reads the pooled feat inline from pmaxu/psum (pool2 folded in).
__global__ __launch_bounds__(256) void k_fc1(const unsigned* __restrict__ pmaxu,
                                             const float* __restrict__ psum,
                                             const float* __restrict__ l1wT,
                                             const float* __restrict__ g6, const float* __restrict__ b6,
                                             float* __restrict__ f1) {
    int oc = blockIdx.x, b = blockIdx.y, t = threadIdx.x;
    __shared__ float fin[2048];
    __shared__ float ps[4][64];
    for (int u = t; u < 2048; u += 256) {
        float v;
        if (u < 1024) {
            unsigned tb = pmaxu[b * 1024 + u];
            unsigned bits = (tb & 0x80000000u) ? (tb & 0x7FFFFFFFu) : ~tb;
            v = __uint_as_float(bits);
        } else {
            v = psum[b * 1024 + (u - 1024)] * (1.f / 1024.f);
        }
        fin[u] = v;
    }
    __syncthreads();
    int ol = t & 63, kc = t >> 6;
    int o = oc * 64 + ol;
    float acc = 0.f;
    for (int c = kc * 512; c < kc * 512 + 512; c++) acc += fin[c] * l1wT[(size_t)c * 512 + o];
    ps[kc][ol] = acc;
    __syncthreads();
    if (t < 64) {
        int oo = oc * 64 + t;
        float a = ps[0][t] + ps[1][t] + ps[2][t] + ps[3][t];
        float h = a * (g6[oo] * BN_SCALE) + b6[oo];
        f1[b * 512 + oo] = h >= 0.f ? h : 0.2f * h;
    }
}

// fc2 + fc3 fused (one block per batch; f2 lives in LDS only).  Output dtype
// flag computed inline.
__global__ __launch_bounds__(256) void k_fc23(const float* __restrict__ f1, const float* __restrict__ l2wT,
                                              const float* __restrict__ l2b,
                                              const float* __restrict__ g7, const float* __restrict__ b7,
                                              const float* __restrict__ l3wT, const float* __restrict__ l3b,
                                              void* __restrict__ out, DetP dp) {
    int b = blockIdx.x, t = threadIdx.x;
    __shared__ float fin[512];
    __shared__ float f2s[256];
    __shared__ int sbf;
    if (t == 0) sbf = det_isbf(dp);
    for (int u = t; u < 512; u += 256) fin[u] = f1[b * 512 + u];
    __syncthreads();
    {
        float acc = 0.f;
        for (int c = 0; c < 512; c++) acc += fin[c] * l2wT[(size_t)c * 256 + t];
        acc += l2b[t];
        float h = acc * (g7[t] * BN_SCALE) + b7[t];
        f2s[t] = h >= 0.f ? h : 0.2f * h;
    }
    __syncthreads();
    if (t < 40) {
        float acc = 0.f;
        for (int c = 0; c < 256; c++) acc += f2s[c] * l3wT[(size_t)c * 40 + t];
        acc += l3b[t];
        if (sbf) ((__hip_bfloat16*)out)[b * 40 + t] = __float2bfloat16(acc);
        else     ((float*)out)[b * 40 + t] = acc;
    }
}

// ================================================================ host
extern "C" void kernel_launch(void* const* d_in, const int* in_sizes, int n_in,
                              void* d_out, int out_size, void* d_ws, size_t ws_size,
                              hipStream_t stream) {
    auto us = [&](int i) { return (const unsigned short*)d_in[i]; };

    float* ws = (float*)d_ws;
    size_t off = 0;
    auto A = [&](size_t n) { float* p = ws + off; off += (n + 3) & ~(size_t)3; return p; };
    auto AU = [&](size_t n) { return (unsigned short*)A((n + 1) / 2); };
    float* x1   = A((size_t)BN_ * 64);
    float* x2   = A((size_t)BN_ * 64);
    float* x3   = A((size_t)BN_ * 128);
    float* x4   = A((size_t)BN_ * 256);
    float* pd   = A((size_t)BN_ * 1024);   // pd scratch
    float* f1   = A(8 * 512);
    float* xx   = A(4 * BN_);              // per-layer row norms (xx2..4 atomic, pre-zeroed)
    int*   idx  = (int*)A((size_t)BN_ * K_);
    float* qkvw = A((size_t)BN_ * 768);   // qkv / y,z / knn-split scratch
    // bf16 activation copies
    unsigned short* xf0b = AU((size_t)BN_ * 3);
    unsigned short* x1b  = AU((size_t)BN_ * 64);
    unsigned short* x2b  = AU((size_t)BN_ * 64);
    unsigned short* x3b  = AU((size_t)BN_ * 128);
    unsigned short* x4b  = AU((size_t)BN_ * 256);
    unsigned short* owb  = AU((size_t)BN_ * 256);
    // pooled reductions (conv5 fused epilogue) -- contiguous, zeroed by k_prep
    unsigned* pmaxu = (unsigned*)A(8 * 1024);
    float*    psum  = A(8 * 1024);
    // bf16 weights (n,k) layouts
    unsigned short* w1yzb = AU(128 * 3);
    unsigned short* w2yzb = AU(128 * 64);
    unsigned short* w3yzb = AU(256 * 64);
    unsigned short* w4yzb = AU(512 * 128);
    unsigned short* a1wib = AU(192 * 64);  unsigned short* a1wob = AU(64 * 64);
    unsigned short* a2wib = AU(192 * 64);  unsigned short* a2wob = AU(64 * 64);
    unsigned short* a3wib = AU(384 * 128); unsigned short* a3wob = AU(128 * 128);
    unsigned short* a4wib = AU(768 * 256); unsigned short* a4wob = AU(256 * 256);
    unsigned short* w5b   = AU(1024 * 512);
    // fp32 fc weights (transposed)
    float* l1wT  = A(2048 * 512);
    float* l2wT  = A(512 * 256);
    float* l3wT  = A(256 * 40);
    // converted vectors (fp32)
    float* g1f = A(64);   float* b1f = A(64);
    float* g2f = A(64);   float* b2f = A(64);
    float* g3f = A(128);  float* b3f = A(128);
    float* g4f = A(256);  float* b4f = A(256);
    float* bi1 = A(192);  float* bo1 = A(64);
    float* bi2 = A(192);  float* bo2 = A(64);
    float* bi3 = A(384);  float* bo3 = A(128);
    float* bi4 = A(768);  float* bo4 = A(256);
    float* g5f = A(1024); float* b5f = A(1024);
    float* g6f = A(512);  float* b6f = A(512);
    float* l2bf = A(256);
    float* g7f = A(256);  float* b7f = A(256);
    float* l3bf = A(40);

    float* xx1 = xx;              float* xx2 = xx + BN_;
    float* xx3 = xx + 2 * BN_;    float* xx4 = xx + 3 * BN_;

    // knn split buffers alias qkvw (dead during the kNN phase of each layer);
    // 3-seg split: max KP = 384 -> xa/xb each BN_*384 u16 (12.6 MB < 25 MB).
    unsigned short* xa = (unsigned short*)qkvw;
    unsigned short* xb = (unsigned short*)qkvw + (size_t)BN_ * 384;
    // y/z edge-feature arrays (written by selyz gemm AFTER pdm consumed xa/xb;
    // consumed by edgemax; overwritten later by the qkv gemm)
    float* yy = qkvw;
    float* zz = qkvw + (size_t)BN_ * 256;

    DetP dp{{us(2), us(5), us(8), us(11), us(30), us(33), us(37)}};

    TList tl; int nb = 0; int k = 0;
    auto add = [&](int i, void* dst, int O, int I, int mode) {
        tl.p[k].src = d_in[i]; tl.p[k].dst = dst; tl.p[k].O = O; tl.p[k].I = I;
        tl.p[k].blk0 = nb; tl.p[k].mode = mode;
        nb += (O * I + 255) / 256; k++;
    };
    add(0,  xf0b,  BN_ * 3, 1, 2);
    add(0,  pmaxu, 16384, 1, 4);      // zero pmaxu+psum (contiguous)
    add(0,  xx2,   3 * BN_, 1, 4);    // zero xx2..xx4 (atomic targets)
    add(1,  w1yzb, 64, 6, 3);
    add(4,  w2yzb, 64, 128, 3);
    add(7,  w3yzb, 128, 128, 3);
    add(10, w4yzb, 256, 256, 3);
    add(13, a1wib, 192, 64, 2);
    add(15, a1wob, 64, 64, 2);
    add(17, a2wib, 192, 64, 2);
    add(19, a2wob, 64, 64, 2);
    add(21, a3wib, 384, 128, 2);
    add(23, a3wob, 128, 128, 2);
    add(25, a4wib, 768, 256, 2);
    add(27, a4wob, 256, 256, 2);
    add(29, w5b,   1024, 512, 2);
    add(2,  g1f, 64, 1, 0);   add(3,  b1f, 64, 1, 0);
    add(5,  g2f, 64, 1, 0);   add(6,  b2f, 64, 1, 0);
    add(8,  g3f, 128, 1, 0);  add(9,  b3f, 128, 1, 0);
    add(11, g4f, 256, 1, 0);  add(12, b4f, 256, 1, 0);
    add(14, bi1, 192, 1, 0);  add(16, bo1, 64, 1, 0);
    add(18, bi2, 192, 1, 0);  add(20, bo2, 64, 1, 0);
    add(22, bi3, 384, 1, 0);  add(24, bo3, 128, 1, 0);
    add(26, bi4, 768, 1, 0);  add(28, bo4, 256, 1, 0);
    add(30, g5f, 1024, 1, 0); add(31, b5f, 1024, 1, 0);
    add(33, g6f, 512, 1, 0);  add(34, b6f, 512, 1, 0);
    add(36, l2bf, 256, 1, 0);
    add(37, g7f, 256, 1, 0);  add(38, b7f, 256, 1, 0);
    add(40, l3bf, 40, 1, 0);

    // FC-weight transposes + layer-1 split/norms fused into k_prep tail blocks
    TrP tp1{d_in[32], l1wT, 512, 2048, 2048 / 32, 0};
    TrP tp2{d_in[35], l2wT, 256, 512,  512 / 32,  (2048 / 32) * (512 / 32)};
    TrP tp3{d_in[39], l3wT, 40,  256,  256 / 32,  tp2.blk0 + (512 / 32) * (256 / 32)};
    const int trblocks = tp3.blk0 + (256 / 32) * ((40 + 31) / 32);
    const int splblocks = (BN_ * 32) / 256 + 32;   // split + norms
    k_prep<<<nb + trblocks + splblocks, 256, 0, stream>>>(
        tl, k, tp1, tp2, tp3, nb, trblocks, d_in[0], dp, xa, xb, xx1);

    const dim3 pdmg(8, 8, 8);          // 128x128 tiles per batch
    const unsigned short* N0 = nullptr;
    unsigned short* U0 = nullptr;
    unsigned* NU = nullptr; float* NF = nullptr;

    // layer 1  (C=3 -> 64)
    k_pdm<32, 128, 128><<<pdmg, 256, 0, stream>>>(xa, xb, xx1, pd);
    k_selyz<3, 128, 64, 64><<<2048 + 256, 256, 0, stream>>>(pd, idx, 2048, 128, xf0b, w1yzb, yy, zz, 64);
    k_edgemax<64><<<BN_ / 16, 256, 0, stream>>>(yy, zz, idx, g1f, b1f, x1, x1b);
    k_gemmb<64, 192, 64, 64><<<dim3(128, 3), 256, 0, stream>>>(x1b, N0, N0, N0, a1wib, bi1, nullptr, qkvw, 64, 0.25f, nullptr, nullptr, nullptr, NU, NF, U0, U0, NF);
    k_attn<64><<<N_, 256, 0, stream>>>(qkvw, owb);
    k_gemmb<64, 64, 64, 64, false, false, 64><<<dim3(128, 1), 256, 0, stream>>>(owb, N0, N0, N0, a1wob, bo1, x1, x1, 0, 1.f, nullptr, nullptr, x1b, NU, NF, xa, xb, xx2);

    // layer 2  (C=64 -> 64, KP=192)
    k_pdm<192, 128, 128><<<pdmg, 256, 0, stream>>>(xa, xb, xx2, pd);
    k_selyz<64, 128, 64, 64><<<2048 + 256, 256, 0, stream>>>(pd, idx, 2048, 128, x1b, w2yzb, yy, zz, 64);
    k_edgemax<64><<<BN_ / 16, 256, 0, stream>>>(yy, zz, idx, g2f, b2f, x2, x2b);
    k_gemmb<64, 192, 64, 64><<<dim3(128, 3), 256, 0, stream>>>(x2b, N0, N0, N0, a2wib, bi2, nullptr, qkvw, 64, 0.25f, nullptr, nullptr, nullptr, NU, NF, U0, U0, NF);
    k_attn<64><<<N_, 256, 0, stream>>>(qkvw, owb);
    k_gemmb<64, 64, 64, 64, false, false, 64><<<dim3(128, 1), 256, 0, stream>>>(owb, N0, N0, N0, a2wob, bo2, x2, x2, 0, 1.f, nullptr, nullptr, x2b, NU, NF, xa, xb, xx3);

    // layer 3  (C=64 -> 128, KP=192)
    k_pdm<192, 128, 128><<<pdmg, 256, 0, stream>>>(xa, xb, xx3, pd);
    k_selyz<64, 256, 64, 64><<<2048 + 512, 256, 0, stream>>>(pd, idx, 2048, 128, x2b, w3yzb, yy, zz, 128);
    k_edgemax<128><<<BN_ / 8, 256, 0, stream>>>(yy, zz, idx, g3f, b3f, x3, x3b);
    k_gemmb<128, 384, 64, 128><<<dim3(128, 3), 256, 0, stream>>>(x3b, N0, N0, N0, a3wib, bi3, nullptr, qkvw, 128, 0.17677669529663687f, nullptr, nullptr, nullptr, NU, NF, U0, U0, NF);
    k_attn<128><<<N_, 256, 0, stream>>>(qkvw, owb);
    k_gemmb<128, 128, 64, 64, false, false, 128><<<dim3(128, 2), 256, 0, stream>>>(owb, N0, N0, N0, a3wob, bo3, x3, x3, 0, 1.f, nullptr, nullptr, x3b, NU, NF, xa, xb, xx4);

    // layer 4  (C=128 -> 256, KP=384)
    k_pdm<384, 128, 128><<<pdmg, 256, 0, stream>>>(xa, xb, xx4, pd);
    k_selyz<128, 512, 128, 128><<<2048 + 256, 256, 0, stream>>>(pd, idx, 2048, 64, x3b, w4yzb, yy, zz, 256);
    k_edgemax<256><<<BN_ / 4, 256, 0, stream>>>(yy, zz, idx, g4f, b4f, x4, x4b);
    k_gemmb<256, 768, 128, 128><<<dim3(64, 6), 256, 0, stream>>>(x4b, N0, N0, N0, a4wib, bi4, nullptr, qkvw, 256, 0.125f, nullptr, nullptr, nullptr, NU, NF, U0, U0, NF);
    k_attn<256><<<N_, 256, 0, stream>>>(qkvw, owb);
    k_gemmb<256, 256, 64, 128><<<dim3(128, 2), 256, 0, stream>>>(owb, N0, N0, N0, a4wob, bo4, x4, x4, 0, 1.f, nullptr, nullptr, x4b, NU, NF, U0, U0, NF);

    // head: conv5 with fused concat-A and fused pooling epilogue
    k_gemmb<512, 1024, 128, 128, true, true><<<dim3(64, 8), 256, 0, stream>>>(
        x1b, x2b, x3b, x4b, w5b, nullptr, nullptr, nullptr, 0, 1.f, g5f, b5f, nullptr, pmaxu, psum, U0, U0, NF);
    k_fc1<<<dim3(8, 8), 256, 0, stream>>>(pmaxu, psum, l1wT, g6f, b6f, f1);
    k_fc23<<<8, 256, 0, stream>>>(f1, l2wT, l2bf, g7f, b7f, l3wT, l3bf, d_out, dp);
}

// Round 11
// 501.725 us; speedup vs baseline: 1.3418x; 1.0181x over previous
//
#include <hip/hip_runtime.h>
#include <hip/hip_bf16.h>

#define B_ 8
#define N_ 1024
#define K_ 20
#define BN_ (B_*N_)

#define BN_SCALE 0.9999950000374997f

typedef __attribute__((ext_vector_type(8))) short short8;
typedef __attribute__((ext_vector_type(4))) float f32x4;

__device__ __forceinline__ float US2F(unsigned short u) {
    union { unsigned u; float f; } c; c.u = ((unsigned)u) << 16; return c.f;
}
__device__ __forceinline__ unsigned short F2BF(float f) {   // RNE fp32->bf16
    union { float f; unsigned u; } c; c.f = f;
    unsigned r = c.u + 0x7FFF + ((c.u >> 16) & 1);
    return (unsigned short)(r >> 16);
}

// async global->LDS 16B DMA: LDS dest = wave-uniform base + lane*16 (linear);
// global source is per-lane (pre-swizzled there when a swizzled layout is wanted).
__device__ __forceinline__ void ldsld16(const unsigned short* g, unsigned short* l) {
    __builtin_amdgcn_global_load_lds(
        (const __attribute__((address_space(1))) void*)g,
        (__attribute__((address_space(3))) void*)l, 16, 0, 0);
}

// dtype-detect data: first element of 7 gamma vectors (bf16 gammas ~1.0)
struct DetP { const unsigned short* g[7]; };
__device__ __forceinline__ int det_isbf(const DetP& dp) {
    int cnt = 0;
    #pragma unroll
    for (int i = 0; i < 7; i++) {
        float v = US2F(dp.g[i][0]);
        if (v > 0.5f && v < 1.5f) cnt++;
    }
    return cnt >= 4;
}

// ---------------------------------------------------------------- prep (+ transposes + L1 split)
// Region 1 [0,nbp): table entries -- mode 0: fp32 copy (I==1); mode 2: bf16
// copy; mode 3: edge pair -> bf16 (2O,C); mode 4: zero-fill fp32.
// Region 2 [nbp,nbp+nbtr): LDS-tiled 32x32 fp32 transposes (FC weights).
// Region 3 [nbp+nbtr,..): layer-1 kNN split (reads d_in[0] directly, C=3,
// KP=32, 3-seg exact-split) + row norms xx1.  Dtype flag computed inline.
struct TPar { const void* src; void* dst; int O, I, blk0, mode; };
struct TList { TPar p[44]; };
struct TrP { const void* src; float* dst; int O, I, bx, blk0; };

__global__ __launch_bounds__(256) void k_prep(TList tl, int nent,
                                              TrP q0, TrP q1, TrP q2,
                                              int nbp, int nbtr,
                                              const void* x0, DetP dp,
                                              unsigned short* __restrict__ xa,
                                              unsigned short* __restrict__ xb,
                                              float* __restrict__ xx1) {
    __shared__ int sbf;
    if (threadIdx.x == 0) sbf = det_isbf(dp);
    __syncthreads();
    const int isbf = sbf;
    auto ld0 = [&](int idx) {
        return isbf ? US2F(((const unsigned short*)x0)[idx])
                    : ((const float*)x0)[idx];
    };
    const int bid = blockIdx.x;
    if (bid >= nbp + nbtr) {               // ---- region 3: L1 split + norms
        int blk = bid - nbp - nbtr;
        if (blk >= (BN_ * 32) / 256) {     // norms (32 blocks)
            int i = (blk - (BN_ * 32) / 256) * 256 + threadIdx.x;
            if (i >= BN_) return;
            float s = 0.f;
            #pragma unroll
            for (int c = 0; c < 3; c++) { float v = ld0(i * 3 + c); s += v * v; }
            xx1[i] = s;
            return;
        }
        const int e = blk * 256 + threadIdx.x;   // e < BN_*32
        const int i = e >> 5, p = e & 31;
        unsigned short va = 0, vb = 0;
        if (p < 9) {                        // 3 segs x C=3
            const int seg = p / 3, c = p - seg * 3;
            const float v = ld0(i * 3 + c);
            const unsigned short h = F2BF(v);
            const unsigned short l = F2BF(v - US2F(h));
            va = (seg == 1) ? l : h;        // hi,lo,hi
            vb = (seg < 2) ? h : l;         // hi,hi,lo
        }
        xa[e] = va; xb[e] = vb;
        return;
    }
    if (bid >= nbp) {                      // ---- region 2: transposes
        int blk = bid - nbp;
        TrP p = q0;
        if (blk >= q2.blk0) p = q2; else if (blk >= q1.blk0) p = q1;
        blk -= p.blk0;
        const int tx = threadIdx.x & 31, ty = threadIdx.x >> 5;   // 32 x 8
        const int bi = blk % p.bx, bo = blk / p.bx;
        const int i0 = bi * 32, o0 = bo * 32;
        __shared__ float s[32][33];
        #pragma unroll
        for (int r = 0; r < 4; r++) {
            const int o = o0 + ty + r * 8, i = i0 + tx;
            if (o < p.O && i < p.I) {
                const size_t e = (size_t)o * p.I + i;
                s[ty + r * 8][tx] = isbf ? US2F(((const unsigned short*)p.src)[e])
                                         : ((const float*)p.src)[e];
            }
        }
        __syncthreads();
        #pragma unroll
        for (int r = 0; r < 4; r++) {
            const int i = i0 + ty + r * 8, o = o0 + tx;
            if (i < p.I && o < p.O) p.dst[(size_t)i * p.O + o] = s[tx][ty + r * 8];
        }
        return;
    }
    int blk = bid;                          // ---- region 1: entries
    int wi = 0;
    for (int j = nent - 1; j >= 0; j--) { if (blk >= tl.p[j].blk0) { wi = j; break; } }
    const TPar p = tl.p[wi];
    int e = (blk - p.blk0) * 256 + threadIdx.x;
    int n = p.O * p.I;
    if (e >= n) return;
    if (p.mode == 4) { ((float*)p.dst)[e] = 0.f; return; }
    int o = e / p.I, i = e - o * p.I;
    float v = isbf ? US2F(((const unsigned short*)p.src)[e])
                   : ((const float*)p.src)[e];
    if (p.mode == 0) {
        ((float*)p.dst)[(size_t)i * p.O + o] = v;
    } else if (p.mode == 2) {
        ((unsigned short*)p.dst)[e] = F2BF(v);
    } else {
        const int C = p.I >> 1;
        if (i < C) ((unsigned short*)p.dst)[(size_t)o * C + i] = F2BF(v);
        else       ((unsigned short*)p.dst)[(size_t)(p.O + o) * C + (i - C)] = F2BF(v);
    }
}

// ---------------------------------------------------------------- kNN phase 1 (MFMA):
// pd[b][i][j] = 2*dot(xa_i, xb_j) - xx_j.  3-seg exact-split over KP=3C.
// 128x128 tile, global_load_lds + source 16B-granule XOR swizzle, 2-phase
// dbuf.  XCD batch-affinity: 1D grid, batch = bid&7 (consecutive linear ids
// round-robin XCDs) -> batch b's pd writes land in XCD b's L2 (4.2 MB slice
// ~= one XCD L2) where the immediately-following sel reads them.
template<int KP, int TM, int TN>
__global__ __launch_bounds__(256) void k_pdm(const unsigned short* __restrict__ xa,
                                             const unsigned short* __restrict__ xb,
                                             const float* __restrict__ xx,
                                             float* __restrict__ pd) {
    const int bid = blockIdx.x;
    const int b = bid & 7;
    const int tt = bid >> 3;                 // 0..63 tile index within batch
    const int rb = (tt >> 3) * TM, cb = (tt & 7) * TN;
    const unsigned short* Ab = xa + (size_t)b * N_ * KP;
    const unsigned short* Bb = xb + (size_t)b * N_ * KP;
    const float* xxb = xx + (size_t)b * N_;
    const int t = threadIdx.x;
    __shared__ __align__(16) unsigned short As[2][TM * 32];
    __shared__ __align__(16) unsigned short Bs[2][TN * 32];
    const int w = t >> 6, lane = t & 63;
    constexpr int QR = TM / 2, QC = TN / 2;
    constexpr int MR = QR / 16, NR = QC / 16;
    const int wr = (w & 1) * QR, wc = (w >> 1) * QC;
    const int fr = lane & 15, q = lane >> 4;
    f32x4 acc[MR][NR] = {};

    auto STAGE = [&](int buf, int k0) {
        constexpr int AT = TM * 4;
        #pragma unroll
        for (int R = 0; R < (AT + 255) / 256; R++) {
            const int G = t + R * 256;
            if (AT >= (R + 1) * 256 || G < AT) {
                const int m = G >> 2, gs = (G & 3) ^ ((m >> 1) & 3);
                ldsld16(&Ab[(size_t)(rb + m) * KP + k0 + gs * 8], &As[buf][w * 512 + R * 2048]);
            }
        }
        constexpr int BT = TN * 4;
        #pragma unroll
        for (int R = 0; R < (BT + 255) / 256; R++) {
            const int G = t + R * 256;
            if (BT >= (R + 1) * 256 || G < BT) {
                const int n = G >> 2, gs = (G & 3) ^ ((n >> 1) & 3);
                ldsld16(&Bb[(size_t)(cb + n) * KP + k0 + gs * 8], &Bs[buf][w * 512 + R * 2048]);
            }
        }
    };

    constexpr int NT = KP / 32;
    STAGE(0, 0);
    asm volatile("s_waitcnt vmcnt(0)" ::: "memory");
    __builtin_amdgcn_s_barrier();
    int cur = 0;
    for (int ts = 0; ts < NT; ++ts) {
        if (ts + 1 < NT) STAGE(cur ^ 1, (ts + 1) * 32);
        short8 af[MR], bfr[NR];
        #pragma unroll
        for (int mi = 0; mi < MR; mi++) {
            const int r = wr + mi * 16 + fr;
            af[mi] = *reinterpret_cast<const short8*>(&As[cur][r * 32 + ((q ^ ((r >> 1) & 3)) << 3)]);
        }
        #pragma unroll
        for (int ni = 0; ni < NR; ni++) {
            const int r = wc + ni * 16 + fr;
            bfr[ni] = *reinterpret_cast<const short8*>(&Bs[cur][r * 32 + ((q ^ ((r >> 1) & 3)) << 3)]);
        }
        #pragma unroll
        for (int mi = 0; mi < MR; mi++) {
            #pragma unroll
            for (int ni = 0; ni < NR; ni++)
                acc[mi][ni] = __builtin_amdgcn_mfma_f32_16x16x32_bf16(af[mi], bfr[ni], acc[mi][ni], 0, 0, 0);
        }
        asm volatile("s_waitcnt vmcnt(0)" ::: "memory");
        __builtin_amdgcn_s_barrier();
        cur ^= 1;
    }
    float* pdb = pd + (size_t)b * N_ * N_;
    const int cr = (lane >> 4) * 4, cc = lane & 15;
    #pragma unroll
    for (int mi = 0; mi < MR; mi++) {
        #pragma unroll
        for (int ni = 0; ni < NR; ni++) {
            #pragma unroll
            for (int r = 0; r < 4; r++) {
                const int row = rb + wr + mi * 16 + cr + r;
                const int col = cb + wc + ni * 16 + cc;
                pdb[(size_t)row * N_ + col] = 2.f * acc[mi][ni][r] - xxb[col];
            }
        }
    }
}

// ---------------------------------------------------------------- kNN phase 2 (device body)
// 32-bit key top-20; 2048 sel blocks -> 32 waves/CU hides the serial 20-round
// chain (R5/R6 lesson).  Batch-affine row map: batch = blk&7 -> reads batch
// b's pd slice from XCD b's L2 (written there by the affine k_pdm).
__device__ __forceinline__ void sel_dev(const float* __restrict__ pd,
                                        int* __restrict__ idx, int blk) {
    const int w = threadIdx.x >> 6, lane = threadIdx.x & 63;
    const int b = blk & 7;
    const int i = (b << 10) + ((blk >> 3) << 2) + w;   // 4 rows per block
    const float* row = pd + (size_t)b * N_ * N_ + (size_t)(i & 1023) * N_;
    unsigned key[16];
    #pragma unroll
    for (int q = 0; q < 16; q++) {
        const int j = q * 64 + lane;
        unsigned bits = __float_as_uint(row[j]);
        bits = (bits & 0x80000000u) ? ~bits : (bits | 0x80000000u);
        key[q] = (bits & 0xFFFFFC00u) | (unsigned)(N_ - 1 - j);
    }
    int myj = 0;
    for (int kk = 0; kk < K_; kk++) {
        unsigned m = key[0];
        #pragma unroll
        for (int u = 1; u < 16; u++) m = key[u] > m ? key[u] : m;
        #pragma unroll
        for (int s = 1; s < 64; s <<= 1) {
            unsigned o = (unsigned)__shfl_xor((int)m, s, 64);
            m = o > m ? o : m;
        }
        const int j = N_ - 1 - (int)(m & 1023u);
        if (lane == kk) myj = j;
        #pragma unroll
        for (int u = 0; u < 16; u++)
            if (key[u] == m) key[u] = 0u;      // below any plausible real key
    }
    if (lane < K_) idx[(size_t)i * K_ + lane] = myj;
}

// ---------------------------------------------------------------- MFMA bf16 GEMM (device body)
// C[8192][NC] = A[8192][KD] @ Bw^T.  KD%32==0: global_load_lds dwordx4 into
// linear [T][32] LDS, source-side 16B-granule XOR swizzle, 2-phase dbuf.
// CATA: A = virtual concat [x1b|x2b|x3b|x4b].  POOL: fused BN+LReLU+max/sum
// pooling epilogue (atomics).  SPLIT=C>0: epilogue also emits next layer's
// 3-seg kNN split + row norms.  yco>0: yz column routing (y / z arrays).
template<int KD, int NC, int TM, int TN, bool CATA, bool POOL, int SPLIT>
__device__ __forceinline__ void gemm_dev(int bx, int by,
                                         const unsigned short* __restrict__ A,
                                         const unsigned short* __restrict__ A2,
                                         const unsigned short* __restrict__ A3,
                                         const unsigned short* __restrict__ A4,
                                         const unsigned short* __restrict__ Bw,
                                         const float* __restrict__ bias,
                                         const float* __restrict__ resid,
                                         float* __restrict__ Cout,
                                         float* __restrict__ Cz, int yco,
                                         int scale_cols, float qs,
                                         const float* __restrict__ gamma,
                                         const float* __restrict__ beta,
                                         unsigned short* __restrict__ obf,
                                         unsigned* __restrict__ pmaxu,
                                         float* __restrict__ psum,
                                         unsigned short* __restrict__ sxa,
                                         unsigned short* __restrict__ sxb,
                                         float* __restrict__ xxo) {
    const int t = threadIdx.x;
    const int rb = bx * TM, cb = by * TN;
    const int w = t >> 6, lane = t & 63;
    constexpr int QR = TM / 2, QC = TN / 2;
    constexpr int MR = QR / 16, NR = QC / 16;
    const int wr = (w & 1) * QR, wc = (w >> 1) * QC;
    const int fr = lane & 15, q = lane >> 4, fq = q * 8;
    f32x4 acc[MR][NR] = {};
    if constexpr (KD % 32 == 0) {
        __shared__ __align__(16) unsigned short As[2][TM * 32];
        __shared__ __align__(16) unsigned short Bs[2][TN * 32];
        auto STAGE = [&](int buf, int k0) {
            const unsigned short* Asrc = A; int AC = KD, ac0 = k0;
            if constexpr (CATA) {
                if (k0 >= 256)      { Asrc = A4; AC = 256; ac0 = k0 - 256; }
                else if (k0 >= 128) { Asrc = A3; AC = 128; ac0 = k0 - 128; }
                else if (k0 >= 64)  { Asrc = A2; AC = 64;  ac0 = k0 - 64; }
                else                { Asrc = A;  AC = 64;  ac0 = k0; }
            }
            constexpr int AT = TM * 4;
            #pragma unroll
            for (int R = 0; R < (AT + 255) / 256; R++) {
                const int G = t + R * 256;
                if (AT >= (R + 1) * 256 || G < AT) {
                    const int m = G >> 2, gs = (G & 3) ^ ((m >> 1) & 3);
                    ldsld16(&Asrc[(size_t)(rb + m) * AC + ac0 + gs * 8], &As[buf][w * 512 + R * 2048]);
                }
            }
            constexpr int BT = TN * 4;
            #pragma unroll
            for (int R = 0; R < (BT + 255) / 256; R++) {
                const int G = t + R * 256;
                if (BT >= (R + 1) * 256 || G < BT) {
                    const int n = G >> 2, gs = (G & 3) ^ ((n >> 1) & 3);
                    ldsld16(&Bw[(size_t)(cb + n) * KD + k0 + gs * 8], &Bs[buf][w * 512 + R * 2048]);
                }
            }
        };
        constexpr int NT = KD / 32;
        STAGE(0, 0);
        asm volatile("s_waitcnt vmcnt(0)" ::: "memory");
        __builtin_amdgcn_s_barrier();
        int cur = 0;
        for (int ts = 0; ts < NT; ++ts) {
            if (ts + 1 < NT) STAGE(cur ^ 1, (ts + 1) * 32);
            short8 af[MR], bfr[NR];
            #pragma unroll
            for (int mi = 0; mi < MR; mi++) {
                const int r = wr + mi * 16 + fr;
                af[mi] = *reinterpret_cast<const short8*>(&As[cur][r * 32 + ((q ^ ((r >> 1) & 3)) << 3)]);
            }
            #pragma unroll
            for (int ni = 0; ni < NR; ni++) {
                const int r = wc + ni * 16 + fr;
                bfr[ni] = *reinterpret_cast<const short8*>(&Bs[cur][r * 32 + ((q ^ ((r >> 1) & 3)) << 3)]);
            }
            #pragma unroll
            for (int mi = 0; mi < MR; mi++) {
                #pragma unroll
                for (int ni = 0; ni < NR; ni++)
                    acc[mi][ni] = __builtin_amdgcn_mfma_f32_16x16x32_bf16(af[mi], bfr[ni], acc[mi][ni], 0, 0, 0);
            }
            asm volatile("s_waitcnt vmcnt(0)" ::: "memory");
            __builtin_amdgcn_s_barrier();
            cur ^= 1;
        }
    } else {
        // fallback (KD=3): reg-staged, padded LDS, scalar guarded loads
        __shared__ __align__(16) unsigned short As[TM * 40];
        __shared__ __align__(16) unsigned short Bs[TN * 40];
        for (int k0 = 0; k0 < KD; k0 += 32) {
            __syncthreads();
            #pragma unroll
            for (int u = t; u < TM * 4; u += 256) {
                const int m = u >> 2, c = (u & 3) * 8;
                #pragma unroll
                for (int j = 0; j < 8; j++) {
                    const int kk = k0 + c + j;
                    As[m * 40 + c + j] = (kk < KD) ? A[(size_t)(rb + m) * KD + kk] : (unsigned short)0;
                }
            }
            #pragma unroll
            for (int u = t; u < TN * 4; u += 256) {
                const int n = u >> 2, c = (u & 3) * 8;
                const int gn = cb + n;
                if (gn < NC) {
                    #pragma unroll
                    for (int j = 0; j < 8; j++) {
                        const int kk = k0 + c + j;
                        Bs[n * 40 + c + j] = (kk < KD) ? Bw[(size_t)gn * KD + kk] : (unsigned short)0;
                    }
                } else {
                    short8 z = {};
                    *reinterpret_cast<short8*>(&Bs[n * 40 + c]) = z;
                }
            }
            __syncthreads();
            short8 af[MR], bfr[NR];
            #pragma unroll
            for (int mi = 0; mi < MR; mi++)
                af[mi] = *reinterpret_cast<const short8*>(&As[(wr + mi * 16 + fr) * 40 + fq]);
            #pragma unroll
            for (int ni = 0; ni < NR; ni++)
                bfr[ni] = *reinterpret_cast<const short8*>(&Bs[(wc + ni * 16 + fr) * 40 + fq]);
            #pragma unroll
            for (int mi = 0; mi < MR; mi++) {
                #pragma unroll
                for (int ni = 0; ni < NR; ni++)
                    acc[mi][ni] = __builtin_amdgcn_mfma_f32_16x16x32_bf16(af[mi], bfr[ni], acc[mi][ni], 0, 0, 0);
            }
        }
    }
    const int cr = (lane >> 4) * 4, cc = lane & 15;
    if constexpr (POOL) {
        const int bidx = rb >> 10;
        #pragma unroll
        for (int ni = 0; ni < NR; ni++) {
            const int col = cb + wc + ni * 16 + cc;
            const float gm = gamma[col] * BN_SCALE, bt = beta[col];
            float sm = 0.f, mxv = -3e38f;
            #pragma unroll
            for (int mi = 0; mi < MR; mi++) {
                #pragma unroll
                for (int r = 0; r < 4; r++) {
                    float v = acc[mi][ni][r] * gm + bt;
                    v = v >= 0.f ? v : 0.2f * v;
                    sm += v; mxv = fmaxf(mxv, v);
                }
            }
            sm += __shfl_xor(sm, 16, 64);
            sm += __shfl_xor(sm, 32, 64);
            mxv = fmaxf(mxv, __shfl_xor(mxv, 16, 64));
            mxv = fmaxf(mxv, __shfl_xor(mxv, 32, 64));
            if (lane < 16) {
                atomicAdd(&psum[bidx * 1024 + col], sm);
                unsigned tb = __float_as_uint(mxv);
                tb = (tb & 0x80000000u) ? ~tb : (tb | 0x80000000u);
                atomicMax(&pmaxu[bidx * 1024 + col], tb);
            }
        }
    } else {
        float sx[MR][4] = {};
        #pragma unroll
        for (int mi = 0; mi < MR; mi++) {
            #pragma unroll
            for (int ni = 0; ni < NR; ni++) {
                #pragma unroll
                for (int r = 0; r < 4; r++) {
                    const int row = rb + wr + mi * 16 + cr + r;
                    const int col = cb + wc + ni * 16 + cc;
                    if (col < NC) {
                        float v = acc[mi][ni][r] + (bias ? bias[col] : 0.f);
                        if (col < scale_cols) v *= qs;
                        if (resid) v += resid[(size_t)row * NC + col];
                        if (gamma) {
                            v = v * (gamma[col] * BN_SCALE) + beta[col];
                            v = v >= 0.f ? v : 0.2f * v;
                        }
                        if (yco > 0) {
                            if (col < yco) Cout[(size_t)row * yco + col] = v;
                            else           Cz[(size_t)row * yco + (col - yco)] = v;
                        } else {
                            Cout[(size_t)row * NC + col] = v;
                        }
                        if (obf) obf[(size_t)row * NC + col] = F2BF(v);
                        if constexpr (SPLIT > 0) {
                            constexpr int KP2 = 3 * SPLIT;
                            const unsigned short h = F2BF(v);
                            const unsigned short l = F2BF(v - US2F(h));
                            sxa[(size_t)row * KP2 + 0 * SPLIT + col] = h;
                            sxa[(size_t)row * KP2 + 1 * SPLIT + col] = l;
                            sxa[(size_t)row * KP2 + 2 * SPLIT + col] = h;
                            sxb[(size_t)row * KP2 + 0 * SPLIT + col] = h;
                            sxb[(size_t)row * KP2 + 1 * SPLIT + col] = h;
                            sxb[(size_t)row * KP2 + 2 * SPLIT + col] = l;
                            sx[mi][r] += v * v;
                        }
                    }
                }
            }
        }
        if constexpr (SPLIT > 0) {
            // row-norm: reduce over the 16 col-lanes (same lane>>4 group = same rows)
            #pragma unroll
            for (int mi = 0; mi < MR; mi++) {
                #pragma unroll
                for (int r = 0; r < 4; r++) {
                    float s = sx[mi][r];
                    s += __shfl_xor(s, 1, 64);
                    s += __shfl_xor(s, 2, 64);
                    s += __shfl_xor(s, 4, 64);
                    s += __shfl_xor(s, 8, 64);
                    if ((lane & 15) == 0)
                        atomicAdd(&xxo[rb + wr + mi * 16 + cr + r], s);
                }
            }
        }
    }
}

// AFF: remap blockIdx.x so row-block batch == XCD (linear id % 8).  Requires
// gridDim.x % 8 == 0 and 1024 % TM == 0 (rows-per-batch = gridDim.x/8 blocks).
// Makes x_ib reads / xa,xb writes land on the XCD whose L2 holds that batch.
template<int KD, int NC, int TM, int TN, bool CATA = false, bool POOL = false, int SPLIT = 0, bool AFF = false>
__global__ __launch_bounds__(256) void k_gemmb(const unsigned short* __restrict__ A,
                                               const unsigned short* __restrict__ A2,
                                               const unsigned short* __restrict__ A3,
                                               const unsigned short* __restrict__ A4,
                                               const unsigned short* __restrict__ Bw,
                                               const float* __restrict__ bias,
                                               const float* __restrict__ resid,
                                               float* __restrict__ Cout,
                                               int scale_cols, float qs,
                                               const float* __restrict__ gamma,
                                               const float* __restrict__ beta,
                                               unsigned short* __restrict__ obf,
                                               unsigned* __restrict__ pmaxu,
                                               float* __restrict__ psum,
                                               unsigned short* __restrict__ sxa,
                                               unsigned short* __restrict__ sxb,
                                               float* __restrict__ xxo) {
    int bx = blockIdx.x;
    if constexpr (AFF) bx = (bx & 7) * (gridDim.x >> 3) + (bx >> 3);
    gemm_dev<KD, NC, TM, TN, CATA, POOL, SPLIT>(bx, blockIdx.y,
        A, A2, A3, A4, Bw, bias, resid, Cout, nullptr, 0, scale_cols, qs, gamma, beta,
        obf, pmaxu, psum, sxa, sxb, xxo);
}

// ---------------------------------------------------------------- combined sel || yz-GEMM
// blocks [0,selb) = sel (batch-affine, reads pd from local XCD L2); the rest
// = yz gemm, remapped so each row-block's batch == XCD -> yy/zz writes stay in
// the L2 where the (batch-affine) edgemax will gather them.
template<int KD, int NC, int TM, int TN>
__global__ __launch_bounds__(256) void k_selyz(const float* __restrict__ pd,
                                               int* __restrict__ idx, int selb, int gx,
                                               const unsigned short* __restrict__ A,
                                               const unsigned short* __restrict__ Bw,
                                               float* __restrict__ Cy,
                                               float* __restrict__ Cz, int yco) {
    if ((int)blockIdx.x < selb) { sel_dev(pd, idx, blockIdx.x); return; }
    const int g = blockIdx.x - selb;          // selb = 2048 ≡ 0 mod 8 -> XCD = g&7
    const int batch = g & 7, rem = g >> 3;
    const int rpb = gx >> 3;                  // row-blocks per batch
    const int bx = batch * rpb + rem % rpb;
    const int by = rem / rpb;
    gemm_dev<KD, NC, TM, TN, false, false, 0>(bx, by,
        A, nullptr, nullptr, nullptr, Bw, nullptr, nullptr, Cy, Cz, yco, 0, 1.f,
        nullptr, nullptr, nullptr, nullptr, nullptr, nullptr, nullptr, nullptr);
}

// ---------------------------------------------------------------- EdgeConv epilogue (fp32 out + bf16 copy)
// y/z separate dense [BN][CO] arrays; batch = blockIdx.x & 7 (XCD-affine,
// matching the yz-gemm writer) -> gathers hit the local L2 y-panel ~20x.
template<int CO>
__global__ __launch_bounds__(256) void k_edgemax(const float* __restrict__ y,
                                                 const float* __restrict__ z,
                                                 const int* __restrict__ idx,
                                                 const float* __restrict__ g,
                                                 const float* __restrict__ bb,
                                                 float* __restrict__ out,
                                                 unsigned short* __restrict__ outb) {
    constexpr int TPP = CO / 4;
    constexpr int PPB = 256 / TPP;
    const int t = threadIdx.x;
    const int p = t / TPP;
    const int cw = (t % TPP) * 4;
    const int batch = blockIdx.x & 7;
    const int within = blockIdx.x >> 3;
    const int i0 = batch * N_ + within * PPB;
    const int bbase = batch << 10;
    __shared__ int sidx[PPB][K_];
    for (int u = t; u < PPB * K_; u += 256) {
        int pp = u / K_, kk = u - pp * K_;
        sidx[pp][kk] = idx[(size_t)(i0 + pp) * K_ + kk];
    }
    __syncthreads();
    const int ig = i0 + p;
    float4 m = {-3e38f, -3e38f, -3e38f, -3e38f};
    #pragma unroll 4
    for (int k = 0; k < K_; k++) {
        const int jg = bbase + sidx[p][k];
        const float4 yv = *reinterpret_cast<const float4*>(&y[(size_t)jg * CO + cw]);
        m.x = fmaxf(m.x, yv.x); m.y = fmaxf(m.y, yv.y);
        m.z = fmaxf(m.z, yv.z); m.w = fmaxf(m.w, yv.w);
    }
    const float4 yi = *reinterpret_cast<const float4*>(&y[(size_t)ig * CO + cw]);
    const float4 zi = *reinterpret_cast<const float4*>(&z[(size_t)ig * CO + cw]);
    const float4 gv = *reinterpret_cast<const float4*>(&g[cw]);
    const float4 bv = *reinterpret_cast<const float4*>(&bb[cw]);
    float vals[4] = {m.x - yi.x + zi.x, m.y - yi.y + zi.y,
                     m.z - yi.z + zi.z, m.w - yi.w + zi.w};
    float gs[4] = {gv.x, gv.y, gv.z, gv.w};
    float bs[4] = {bv.x, bv.y, bv.z, bv.w};
    float4 o;
    float* op = &o.x;
    #pragma unroll
    for (int j = 0; j < 4; j++) {
        float h = vals[j] * (gs[j] * BN_SCALE) + bs[j];
        op[j] = h >= 0.f ? h : 0.2f * h;
    }
    *reinterpret_cast<float4*>(&out[(size_t)ig * CO + cw]) = o;
    #pragma unroll
    for (int j = 0; j < 4; j++) outb[(size_t)ig * CO + cw + j] = F2BF(op[j]);
}

// ---------------------------------------------------------------- attention (fp32 math, bf16 out)
template<int E>
__global__ __launch_bounds__(256) void k_attn(const float* __restrict__ qkv,
                                              unsigned short* __restrict__ o) {
    constexpr int H = 4, D = E / H, L = 8;
    const int n = blockIdx.x;
    const int t = threadIdx.x;
    const int h = t >> 6, lane = t & 63;
    __shared__ float sq[L][3 * E];
    __shared__ float so[L][E];
    for (int u = t; u < L * 3 * E; u += 256) {
        int l = u / (3 * E), r = u - l * (3 * E);
        sq[l][r] = qkv[(size_t)(l * N_ + n) * (3 * E) + r];
    }
    __syncthreads();
    const int l = lane >> 3, m = lane & 7;
    float s = 0.f;
    #pragma unroll 8
    for (int dd = 0; dd < D; dd++)
        s += sq[l][h * D + dd] * sq[m][E + h * D + dd];
    float mx = s;
    #pragma unroll
    for (int st = 1; st < 8; st <<= 1) mx = fmaxf(mx, __shfl_xor(mx, st, 64));
    float e = expf(s - mx);
    float sum = e;
    #pragma unroll
    for (int st = 1; st < 8; st <<= 1) sum += __shfl_xor(sum, st, 64);
    const float p = e / sum;
    float pm[8];
    #pragma unroll
    for (int mm = 0; mm < 8; mm++) pm[mm] = __shfl(p, (lane & 56) | mm, 64);
    #pragma unroll
    for (int j = 0; j < D / 8; j++) {
        const int dd = m + 8 * j;
        float a = 0.f;
        #pragma unroll
        for (int mm = 0; mm < 8; mm++) a += pm[mm] * sq[mm][2 * E + h * D + dd];
        so[l][h * D + dd] = a;
    }
    __syncthreads();
    for (int u = t; u < L * E; u += 256) {
        int l2 = u / E, e2 = u - l2 * E;
        o[(size_t)(l2 * N_ + n) * E + e2] = F2BF(so[l2][e2]);
    }
}

// ---------------------------------------------------------------- FC head
// fc1 reads the pooled feat inline from pmaxu/psum (pool2 folded in).
__global__ __launch_bounds__(256) void k_fc1(const unsigned* __restrict__ pmaxu,
                                             const float* __restrict__ psum,
                                             const float* __restrict__ l1wT,
                                             const float* __restrict__ g6, const float* __restrict__ b6,
                                             float* __restrict__ f1) {
    int oc = blockIdx.x, b = blockIdx.y, t = threadIdx.x;
    __shared__ float fin[2048];
    __shared__ float ps[4][64];
    for (int u = t; u < 2048; u += 256) {
        float v;
        if (u < 1024) {
            unsigned tb = pmaxu[b * 1024 + u];
            unsigned bits = (tb & 0x80000000u) ? (tb & 0x7FFFFFFFu) : ~tb;
            v = __uint_as_float(bits);
        } else {
            v = psum[b * 1024 + (u - 1024)] * (1.f / 1024.f);
        }
        fin[u] = v;
    }
    __syncthreads();
    int ol = t & 63, kc = t >> 6;
    int o = oc * 64 + ol;
    float acc = 0.f;
    for (int c = kc * 512; c < kc * 512 + 512; c++) acc += fin[c] * l1wT[(size_t)c * 512 + o];
    ps[kc][ol] = acc;
    __syncthreads();
    if (t < 64) {
        int oo = oc * 64 + t;
        float a = ps[0][t] + ps[1][t] + ps[2][t] + ps[3][t];
        float h = a * (g6[oo] * BN_SCALE) + b6[oo];
        f1[b * 512 + oo] = h >= 0.f ? h : 0.2f * h;
    }
}

// fc2 + fc3 fused (one block per batch; f2 lives in LDS only).
__global__ __launch_bounds__(256) void k_fc23(const float* __restrict__ f1, const float* __restrict__ l2wT,
                                              const float* __restrict__ l2b,
                                              const float* __restrict__ g7, const float* __restrict__ b7,
                                              const float* __restrict__ l3wT, const float* __restrict__ l3b,
                                              void* __restrict__ out, DetP dp) {
    int b = blockIdx.x, t = threadIdx.x;
    __shared__ float fin[512];
    __shared__ float f2s[256];
    __shared__ int sbf;
    if (t == 0) sbf = det_isbf(dp);
    for (int u = t; u < 512; u += 256) fin[u] = f1[b * 512 + u];
    __syncthreads();
    {
        float acc = 0.f;
        for (int c = 0; c < 512; c++) acc += fin[c] * l2wT[(size_t)c * 256 + t];
        acc += l2b[t];
        float h = acc * (g7[t] * BN_SCALE) + b7[t];
        f2s[t] = h >= 0.f ? h : 0.2f * h;
    }
    __syncthreads();
    if (t < 40) {
        float acc = 0.f;
        for (int c = 0; c < 256; c++) acc += f2s[c] * l3wT[(size_t)c * 40 + t];
        acc += l3b[t];
        if (sbf) ((__hip_bfloat16*)out)[b * 40 + t] = __float2bfloat16(acc);
        else     ((float*)out)[b * 40 + t] = acc;
    }
}

// ================================================================ host
extern "C" void kernel_launch(void* const* d_in, const int* in_sizes, int n_in,
                              void* d_out, int out_size, void* d_ws, size_t ws_size,
                              hipStream_t stream) {
    auto us = [&](int i) { return (const unsigned short*)d_in[i]; };

    float* ws = (float*)d_ws;
    size_t off = 0;
    auto A = [&](size_t n) { float* p = ws + off; off += (n + 3) & ~(size_t)3; return p; };
    auto AU = [&](size_t n) { return (unsigned short*)A((n + 1) / 2); };
    float* x1   = A((size_t)BN_ * 64);
    float* x2   = A((size_t)BN_ * 64);
    float* x3   = A((size_t)BN_ * 128);
    float* x4   = A((size_t)BN_ * 256);
    float* pd   = A((size_t)BN_ * 1024);   // pd scratch
    float* f1   = A(8 * 512);
    float* xx   = A(4 * BN_);              // per-layer row norms (xx2..4 atomic, pre-zeroed)
    int*   idx  = (int*)A((size_t)BN_ * K_);
    float* qkvw = A((size_t)BN_ * 768);   // qkv / y,z / knn-split scratch
    // bf16 activation copies
    unsigned short* xf0b = AU((size_t)BN_ * 3);
    unsigned short* x1b  = AU((size_t)BN_ * 64);
    unsigned short* x2b  = AU((size_t)BN_ * 64);
    unsigned short* x3b  = AU((size_t)BN_ * 128);
    unsigned short* x4b  = AU((size_t)BN_ * 256);
    unsigned short* owb  = AU((size_t)BN_ * 256);
    // pooled reductions (conv5 fused epilogue) -- contiguous, zeroed by k_prep
    unsigned* pmaxu = (unsigned*)A(8 * 1024);
    float*    psum  = A(8 * 1024);
    // bf16 weights (n,k) layouts
    unsigned short* w1yzb = AU(128 * 3);
    unsigned short* w2yzb = AU(128 * 64);
    unsigned short* w3yzb = AU(256 * 64);
    unsigned short* w4yzb = AU(512 * 128);
    unsigned short* a1wib = AU(192 * 64);  unsigned short* a1wob = AU(64 * 64);
    unsigned short* a2wib = AU(192 * 64);  unsigned short* a2wob = AU(64 * 64);
    unsigned short* a3wib = AU(384 * 128); unsigned short* a3wob = AU(128 * 128);
    unsigned short* a4wib = AU(768 * 256); unsigned short* a4wob = AU(256 * 256);
    unsigned short* w5b   = AU(1024 * 512);
    // fp32 fc weights (transposed)
    float* l1wT  = A(2048 * 512);
    float* l2wT  = A(512 * 256);
    float* l3wT  = A(256 * 40);
    // converted vectors (fp32)
    float* g1f = A(64);   float* b1f = A(64);
    float* g2f = A(64);   float* b2f = A(64);
    float* g3f = A(128);  float* b3f = A(128);
    float* g4f = A(256);  float* b4f = A(256);
    float* bi1 = A(192);  float* bo1 = A(64);
    float* bi2 = A(192);  float* bo2 = A(64);
    float* bi3 = A(384);  float* bo3 = A(128);
    float* bi4 = A(768);  float* bo4 = A(256);
    float* g5f = A(1024); float* b5f = A(1024);
    float* g6f = A(512);  float* b6f = A(512);
    float* l2bf = A(256);
    float* g7f = A(256);  float* b7f = A(256);
    float* l3bf = A(40);

    float* xx1 = xx;              float* xx2 = xx + BN_;
    float* xx3 = xx + 2 * BN_;    float* xx4 = xx + 3 * BN_;

    // knn split buffers alias qkvw (dead during the kNN phase of each layer);
    // 3-seg split: max KP = 384 -> xa/xb each BN_*384 u16 (12.6 MB < 25 MB).
    unsigned short* xa = (unsigned short*)qkvw;
    unsigned short* xb = (unsigned short*)qkvw + (size_t)BN_ * 384;
    // y/z edge-feature arrays (written by selyz gemm AFTER pdm consumed xa/xb;
    // consumed by edgemax; overwritten later by the qkv gemm)
    float* yy = qkvw;
    float* zz = qkvw + (size_t)BN_ * 256;

    DetP dp{{us(2), us(5), us(8), us(11), us(30), us(33), us(37)}};

    TList tl; int nb = 0; int k = 0;
    auto add = [&](int i, void* dst, int O, int I, int mode) {
        tl.p[k].src = d_in[i]; tl.p[k].dst = dst; tl.p[k].O = O; tl.p[k].I = I;
        tl.p[k].blk0 = nb; tl.p[k].mode = mode;
        nb += (O * I + 255) / 256; k++;
    };
    add(0,  xf0b,  BN_ * 3, 1, 2);
    add(0,  pmaxu, 16384, 1, 4);      // zero pmaxu+psum (contiguous)
    add(0,  xx2,   3 * BN_, 1, 4);    // zero xx2..xx4 (atomic targets)
    add(1,  w1yzb, 64, 6, 3);
    add(4,  w2yzb, 64, 128, 3);
    add(7,  w3yzb, 128, 128, 3);
    add(10, w4yzb, 256, 256, 3);
    add(13, a1wib, 192, 64, 2);
    add(15, a1wob, 64, 64, 2);
    add(17, a2wib, 192, 64, 2);
    add(19, a2wob, 64, 64, 2);
    add(21, a3wib, 384, 128, 2);
    add(23, a3wob, 128, 128, 2);
    add(25, a4wib, 768, 256, 2);
    add(27, a4wob, 256, 256, 2);
    add(29, w5b,   1024, 512, 2);
    add(2,  g1f, 64, 1, 0);   add(3,  b1f, 64, 1, 0);
    add(5,  g2f, 64, 1, 0);   add(6,  b2f, 64, 1, 0);
    add(8,  g3f, 128, 1, 0);  add(9,  b3f, 128, 1, 0);
    add(11, g4f, 256, 1, 0);  add(12, b4f, 256, 1, 0);
    add(14, bi1, 192, 1, 0);  add(16, bo1, 64, 1, 0);
    add(18, bi2, 192, 1, 0);  add(20, bo2, 64, 1, 0);
    add(22, bi3, 384, 1, 0);  add(24, bo3, 128, 1, 0);
    add(26, bi4, 768, 1, 0);  add(28, bo4, 256, 1, 0);
    add(30, g5f, 1024, 1, 0); add(31, b5f, 1024, 1, 0);
    add(33, g6f, 512, 1, 0);  add(34, b6f, 512, 1, 0);
    add(36, l2bf, 256, 1, 0);
    add(37, g7f, 256, 1, 0);  add(38, b7f, 256, 1, 0);
    add(40, l3bf, 40, 1, 0);

    // FC-weight transposes + layer-1 split/norms fused into k_prep tail blocks
    TrP tp1{d_in[32], l1wT, 512, 2048, 2048 / 32, 0};
    TrP tp2{d_in[35], l2wT, 256, 512,  512 / 32,  (2048 / 32) * (512 / 32)};
    TrP tp3{d_in[39], l3wT, 40,  256,  256 / 32,  tp2.blk0 + (512 / 32) * (256 / 32)};
    const int trblocks = tp3.blk0 + (256 / 32) * ((40 + 31) / 32);
    const int splblocks = (BN_ * 32) / 256 + 32;   // split + norms
    k_prep<<<nb + trblocks + splblocks, 256, 0, stream>>>(
        tl, k, tp1, tp2, tp3, nb, trblocks, d_in[0], dp, xa, xb, xx1);

    const unsigned short* N0 = nullptr;
    unsigned short* U0 = nullptr;
    unsigned* NU = nullptr; float* NF = nullptr;

    // layer 1  (C=3 -> 64)
    k_pdm<32, 128, 128><<<512, 256, 0, stream>>>(xa, xb, xx1, pd);
    k_selyz<3, 128, 64, 64><<<2048 + 256, 256, 0, stream>>>(pd, idx, 2048, 128, xf0b, w1yzb, yy, zz, 64);
    k_edgemax<64><<<BN_ / 16, 256, 0, stream>>>(yy, zz, idx, g1f, b1f, x1, x1b);
    k_gemmb<64, 192, 64, 64, false, false, 0, true><<<dim3(128, 3), 256, 0, stream>>>(x1b, N0, N0, N0, a1wib, bi1, nullptr, qkvw, 64, 0.25f, nullptr, nullptr, nullptr, NU, NF, U0, U0, NF);
    k_attn<64><<<N_, 256, 0, stream>>>(qkvw, owb);
    k_gemmb<64, 64, 64, 64, false, false, 64, true><<<dim3(128, 1), 256, 0, stream>>>(owb, N0, N0, N0, a1wob, bo1, x1, x1, 0, 1.f, nullptr, nullptr, x1b, NU, NF, xa, xb, xx2);

    // layer 2  (C=64 -> 64, KP=192)
    k_pdm<192, 128, 128><<<512, 256, 0, stream>>>(xa, xb, xx2, pd);
    k_selyz<64, 128, 64, 64><<<2048 + 256, 256, 0, stream>>>(pd, idx, 2048, 128, x1b, w2yzb, yy, zz, 64);
    k_edgemax<64><<<BN_ / 16, 256, 0, stream>>>(yy, zz, idx, g2f, b2f, x2, x2b);
    k_gemmb<64, 192, 64, 64, false, false, 0, true><<<dim3(128, 3), 256, 0, stream>>>(x2b, N0, N0, N0, a2wib, bi2, nullptr, qkvw, 64, 0.25f, nullptr, nullptr, nullptr, NU, NF, U0, U0, NF);
    k_attn<64><<<N_, 256, 0, stream>>>(qkvw, owb);
    k_gemmb<64, 64, 64, 64, false, false, 64, true><<<dim3(128, 1), 256, 0, stream>>>(owb, N0, N0, N0, a2wob, bo2, x2, x2, 0, 1.f, nullptr, nullptr, x2b, NU, NF, xa, xb, xx3);

    // layer 3  (C=64 -> 128, KP=192)
    k_pdm<192, 128, 128><<<512, 256, 0, stream>>>(xa, xb, xx3, pd);
    k_selyz<64, 256, 64, 64><<<2048 + 512, 256, 0, stream>>>(pd, idx, 2048, 128, x2b, w3yzb, yy, zz, 128);
    k_edgemax<128><<<BN_ / 8, 256, 0, stream>>>(yy, zz, idx, g3f, b3f, x3, x3b);
    k_gemmb<128, 384, 64, 128, false, false, 0, true><<<dim3(128, 3), 256, 0, stream>>>(x3b, N0, N0, N0, a3wib, bi3, nullptr, qkvw, 128, 0.17677669529663687f, nullptr, nullptr, nullptr, NU, NF, U0, U0, NF);
    k_attn<128><<<N_, 256, 0, stream>>>(qkvw, owb);
    k_gemmb<128, 128, 64, 64, false, false, 128, true><<<dim3(128, 2), 256, 0, stream>>>(owb, N0, N0, N0, a3wob, bo3, x3, x3, 0, 1.f, nullptr, nullptr, x3b, NU, NF, xa, xb, xx4);

    // layer 4  (C=128 -> 256, KP=384)
    k_pdm<384, 128, 128><<<512, 256, 0, stream>>>(xa, xb, xx4, pd);
    k_selyz<128, 512, 128, 128><<<2048 + 256, 256, 0, stream>>>(pd, idx, 2048, 64, x3b, w4yzb, yy, zz, 256);
    k_edgemax<256><<<BN_ / 4, 256, 0, stream>>>(yy, zz, idx, g4f, b4f, x4, x4b);
    k_gemmb<256, 768, 64, 128, false, false, 0, true><<<dim3(128, 6), 256, 0, stream>>>(x4b, N0, N0, N0, a4wib, bi4, nullptr, qkvw, 256, 0.125f, nullptr, nullptr, nullptr, NU, NF, U0, U0, NF);
    k_attn<256><<<N_, 256, 0, stream>>>(qkvw, owb);
    k_gemmb<256, 256, 64, 128, false, false, 0, true><<<dim3(128, 2), 256, 0, stream>>>(owb, N0, N0, N0, a4wob, bo4, x4, x4, 0, 1.f, nullptr, nullptr, x4b, NU, NF, U0, U0, NF);

    // head: conv5 with fused concat-A and fused pooling epilogue (batch-affine)
    k_gemmb<512, 1024, 128, 128, true, true, 0, true><<<dim3(64, 8), 256, 0, stream>>>(
        x1b, x2b, x3b, x4b, w5b, nullptr, nullptr, nullptr, 0, 1.f, g5f, b5f, nullptr, pmaxu, psum, U0, U0, NF);
    k_fc1<<<dim3(8, 8), 256, 0, stream>>>(pmaxu, psum, l1wT, g6f, b6f, f1);
    k_fc23<<<8, 256, 0, stream>>>(f1, l2wT, l2bf, g7f, b7f, l3wT, l3bf, d_out, dp);
}

// Round 12
// 486.395 us; speedup vs baseline: 1.3841x; 1.0315x over previous
//
#include <hip/hip_runtime.h>
#include <hip/hip_bf16.h>

#define B_ 8
#define N_ 1024
#define K_ 20
#define BN_ (B_*N_)

#define BN_SCALE 0.9999950000374997f

typedef __attribute__((ext_vector_type(8))) short short8;
typedef __attribute__((ext_vector_type(4))) float f32x4;

__device__ __forceinline__ float US2F(unsigned short u) {
    union { unsigned u; float f; } c; c.u = ((unsigned)u) << 16; return c.f;
}
__device__ __forceinline__ unsigned short F2BF(float f) {   // RNE fp32->bf16
    union { float f; unsigned u; } c; c.f = f;
    unsigned r = c.u + 0x7FFF + ((c.u >> 16) & 1);
    return (unsigned short)(r >> 16);
}

// async global->LDS 16B DMA: LDS dest = wave-uniform base + lane*16 (linear);
// global source is per-lane (pre-swizzled there when a swizzled layout is wanted).
__device__ __forceinline__ void ldsld16(const unsigned short* g, unsigned short* l) {
    __builtin_amdgcn_global_load_lds(
        (const __attribute__((address_space(1))) void*)g,
        (__attribute__((address_space(3))) void*)l, 16, 0, 0);
}

// dtype-detect data: first element of 7 gamma vectors (bf16 gammas ~1.0)
struct DetP { const unsigned short* g[7]; };
__device__ __forceinline__ int det_isbf(const DetP& dp) {
    int cnt = 0;
    #pragma unroll
    for (int i = 0; i < 7; i++) {
        float v = US2F(dp.g[i][0]);
        if (v > 0.5f && v < 1.5f) cnt++;
    }
    return cnt >= 4;
}

// ---------------------------------------------------------------- prep (+ transposes + L1 split)
struct TPar { const void* src; void* dst; int O, I, blk0, mode; };
struct TList { TPar p[44]; };
struct TrP { const void* src; float* dst; int O, I, bx, blk0; };

__global__ __launch_bounds__(256) void k_prep(TList tl, int nent,
                                              TrP q0, TrP q1, TrP q2,
                                              int nbp, int nbtr,
                                              const void* x0, DetP dp,
                                              unsigned short* __restrict__ xa,
                                              unsigned short* __restrict__ xb,
                                              float* __restrict__ xx1) {
    __shared__ int sbf;
    if (threadIdx.x == 0) sbf = det_isbf(dp);
    __syncthreads();
    const int isbf = sbf;
    auto ld0 = [&](int idx) {
        return isbf ? US2F(((const unsigned short*)x0)[idx])
                    : ((const float*)x0)[idx];
    };
    const int bid = blockIdx.x;
    if (bid >= nbp + nbtr) {               // ---- region 3: L1 split + norms
        int blk = bid - nbp - nbtr;
        if (blk >= (BN_ * 32) / 256) {     // norms (32 blocks)
            int i = (blk - (BN_ * 32) / 256) * 256 + threadIdx.x;
            if (i >= BN_) return;
            float s = 0.f;
            #pragma unroll
            for (int c = 0; c < 3; c++) { float v = ld0(i * 3 + c); s += v * v; }
            xx1[i] = s;
            return;
        }
        const int e = blk * 256 + threadIdx.x;   // e < BN_*32
        const int i = e >> 5, p = e & 31;
        unsigned short va = 0, vb = 0;
        if (p < 9) {                        // 3 segs x C=3
            const int seg = p / 3, c = p - seg * 3;
            const float v = ld0(i * 3 + c);
            const unsigned short h = F2BF(v);
            const unsigned short l = F2BF(v - US2F(h));
            va = (seg == 1) ? l : h;        // hi,lo,hi
            vb = (seg < 2) ? h : l;         // hi,hi,lo
        }
        xa[e] = va; xb[e] = vb;
        return;
    }
    if (bid >= nbp) {                      // ---- region 2: transposes
        int blk = bid - nbp;
        TrP p = q0;
        if (blk >= q2.blk0) p = q2; else if (blk >= q1.blk0) p = q1;
        blk -= p.blk0;
        const int tx = threadIdx.x & 31, ty = threadIdx.x >> 5;   // 32 x 8
        const int bi = blk % p.bx, bo = blk / p.bx;
        const int i0 = bi * 32, o0 = bo * 32;
        __shared__ float s[32][33];
        #pragma unroll
        for (int r = 0; r < 4; r++) {
            const int o = o0 + ty + r * 8, i = i0 + tx;
            if (o < p.O && i < p.I) {
                const size_t e = (size_t)o * p.I + i;
                s[ty + r * 8][tx] = isbf ? US2F(((const unsigned short*)p.src)[e])
                                         : ((const float*)p.src)[e];
            }
        }
        __syncthreads();
        #pragma unroll
        for (int r = 0; r < 4; r++) {
            const int i = i0 + ty + r * 8, o = o0 + tx;
            if (i < p.I && o < p.O) p.dst[(size_t)i * p.O + o] = s[tx][ty + r * 8];
        }
        return;
    }
    int blk = bid;                          // ---- region 1: entries
    int wi = 0;
    for (int j = nent - 1; j >= 0; j--) { if (blk >= tl.p[j].blk0) { wi = j; break; } }
    const TPar p = tl.p[wi];
    int e = (blk - p.blk0) * 256 + threadIdx.x;
    int n = p.O * p.I;
    if (e >= n) return;
    if (p.mode == 4) { ((float*)p.dst)[e] = 0.f; return; }
    int o = e / p.I, i = e - o * p.I;
    float v = isbf ? US2F(((const unsigned short*)p.src)[e])
                   : ((const float*)p.src)[e];
    if (p.mode == 0) {
        ((float*)p.dst)[(size_t)i * p.O + o] = v;
    } else if (p.mode == 2) {
        ((unsigned short*)p.dst)[e] = F2BF(v);
    } else {
        const int C = p.I >> 1;
        if (i < C) ((unsigned short*)p.dst)[(size_t)o * C + i] = F2BF(v);
        else       ((unsigned short*)p.dst)[(size_t)(p.O + o) * C + (i - C)] = F2BF(v);
    }
}

// ---------------------------------------------------------------- kNN phase 1 (MFMA):
// pd[b][i][j] = 2*dot(xa_i, xb_j) - xx_j.  3-seg exact-split over KP=3C.
// Batch-affine 1D grid (batch = bid&7 -> XCD = batch; pd stays in local L2).
template<int KP, int TM, int TN>
__global__ __launch_bounds__(256) void k_pdm(const unsigned short* __restrict__ xa,
                                             const unsigned short* __restrict__ xb,
                                             const float* __restrict__ xx,
                                             float* __restrict__ pd) {
    const int bid = blockIdx.x;
    const int b = bid & 7;
    const int tt = bid >> 3;                 // 0..63 tile index within batch
    const int rb = (tt >> 3) * TM, cb = (tt & 7) * TN;
    const unsigned short* Ab = xa + (size_t)b * N_ * KP;
    const unsigned short* Bb = xb + (size_t)b * N_ * KP;
    const float* xxb = xx + (size_t)b * N_;
    const int t = threadIdx.x;
    __shared__ __align__(16) unsigned short As[2][TM * 32];
    __shared__ __align__(16) unsigned short Bs[2][TN * 32];
    const int w = t >> 6, lane = t & 63;
    constexpr int QR = TM / 2, QC = TN / 2;
    constexpr int MR = QR / 16, NR = QC / 16;
    const int wr = (w & 1) * QR, wc = (w >> 1) * QC;
    const int fr = lane & 15, q = lane >> 4;
    f32x4 acc[MR][NR] = {};

    auto STAGE = [&](int buf, int k0) {
        constexpr int AT = TM * 4;
        #pragma unroll
        for (int R = 0; R < (AT + 255) / 256; R++) {
            const int G = t + R * 256;
            if (AT >= (R + 1) * 256 || G < AT) {
                const int m = G >> 2, gs = (G & 3) ^ ((m >> 1) & 3);
                ldsld16(&Ab[(size_t)(rb + m) * KP + k0 + gs * 8], &As[buf][w * 512 + R * 2048]);
            }
        }
        constexpr int BT = TN * 4;
        #pragma unroll
        for (int R = 0; R < (BT + 255) / 256; R++) {
            const int G = t + R * 256;
            if (BT >= (R + 1) * 256 || G < BT) {
                const int n = G >> 2, gs = (G & 3) ^ ((n >> 1) & 3);
                ldsld16(&Bb[(size_t)(cb + n) * KP + k0 + gs * 8], &Bs[buf][w * 512 + R * 2048]);
            }
        }
    };

    constexpr int NT = KP / 32;
    STAGE(0, 0);
    asm volatile("s_waitcnt vmcnt(0)" ::: "memory");
    __builtin_amdgcn_s_barrier();
    int cur = 0;
    for (int ts = 0; ts < NT; ++ts) {
        if (ts + 1 < NT) STAGE(cur ^ 1, (ts + 1) * 32);
        short8 af[MR], bfr[NR];
        #pragma unroll
        for (int mi = 0; mi < MR; mi++) {
            const int r = wr + mi * 16 + fr;
            af[mi] = *reinterpret_cast<const short8*>(&As[cur][r * 32 + ((q ^ ((r >> 1) & 3)) << 3)]);
        }
        #pragma unroll
        for (int ni = 0; ni < NR; ni++) {
            const int r = wc + ni * 16 + fr;
            bfr[ni] = *reinterpret_cast<const short8*>(&Bs[cur][r * 32 + ((q ^ ((r >> 1) & 3)) << 3)]);
        }
        #pragma unroll
        for (int mi = 0; mi < MR; mi++) {
            #pragma unroll
            for (int ni = 0; ni < NR; ni++)
                acc[mi][ni] = __builtin_amdgcn_mfma_f32_16x16x32_bf16(af[mi], bfr[ni], acc[mi][ni], 0, 0, 0);
        }
        asm volatile("s_waitcnt vmcnt(0)" ::: "memory");
        __builtin_amdgcn_s_barrier();
        cur ^= 1;
    }
    float* pdb = pd + (size_t)b * N_ * N_;
    const int cr = (lane >> 4) * 4, cc = lane & 15;
    #pragma unroll
    for (int mi = 0; mi < MR; mi++) {
        #pragma unroll
        for (int ni = 0; ni < NR; ni++) {
            #pragma unroll
            for (int r = 0; r < 4; r++) {
                const int row = rb + wr + mi * 16 + cr + r;
                const int col = cb + wc + ni * 16 + cc;
                pdb[(size_t)row * N_ + col] = 2.f * acc[mi][ni][r] - xxb[col];
            }
        }
    }
}

// ---------------------------------------------------------------- kNN phase 2 (device body)
// 2048 sel blocks -> 32 waves/CU hides the serial 20-round chain (R5/R6).
// Batch-affine: batch = blk&7 reads pd from the local XCD L2.
__device__ __forceinline__ void sel_dev(const float* __restrict__ pd,
                                        int* __restrict__ idx, int blk) {
    const int w = threadIdx.x >> 6, lane = threadIdx.x & 63;
    const int b = blk & 7;
    const int i = (b << 10) + ((blk >> 3) << 2) + w;   // 4 rows per block
    const float* row = pd + (size_t)b * N_ * N_ + (size_t)(i & 1023) * N_;
    unsigned key[16];
    #pragma unroll
    for (int q = 0; q < 16; q++) {
        const int j = q * 64 + lane;
        unsigned bits = __float_as_uint(row[j]);
        bits = (bits & 0x80000000u) ? ~bits : (bits | 0x80000000u);
        key[q] = (bits & 0xFFFFFC00u) | (unsigned)(N_ - 1 - j);
    }
    int myj = 0;
    for (int kk = 0; kk < K_; kk++) {
        unsigned m = key[0];
        #pragma unroll
        for (int u = 1; u < 16; u++) m = key[u] > m ? key[u] : m;
        #pragma unroll
        for (int s = 1; s < 64; s <<= 1) {
            unsigned o = (unsigned)__shfl_xor((int)m, s, 64);
            m = o > m ? o : m;
        }
        const int j = N_ - 1 - (int)(m & 1023u);
        if (lane == kk) myj = j;
        #pragma unroll
        for (int u = 0; u < 16; u++)
            if (key[u] == m) key[u] = 0u;      // below any plausible real key
    }
    if (lane < K_) idx[(size_t)i * K_ + lane] = myj;
}

// ---------------------------------------------------------------- MFMA bf16 GEMM (device body)
template<int KD, int NC, int TM, int TN, bool CATA, bool POOL, int SPLIT>
__device__ __forceinline__ void gemm_dev(int bx, int by,
                                         const unsigned short* __restrict__ A,
                                         const unsigned short* __restrict__ A2,
                                         const unsigned short* __restrict__ A3,
                                         const unsigned short* __restrict__ A4,
                                         const unsigned short* __restrict__ Bw,
                                         const float* __restrict__ bias,
                                         const float* __restrict__ resid,
                                         float* __restrict__ Cout,
                                         float* __restrict__ Cz, int yco,
                                         int scale_cols, float qs,
                                         const float* __restrict__ gamma,
                                         const float* __restrict__ beta,
                                         unsigned short* __restrict__ obf,
                                         unsigned* __restrict__ pmaxu,
                                         float* __restrict__ psum,
                                         unsigned short* __restrict__ sxa,
                                         unsigned short* __restrict__ sxb,
                                         float* __restrict__ xxo) {
    const int t = threadIdx.x;
    const int rb = bx * TM, cb = by * TN;
    const int w = t >> 6, lane = t & 63;
    constexpr int QR = TM / 2, QC = TN / 2;
    constexpr int MR = QR / 16, NR = QC / 16;
    const int wr = (w & 1) * QR, wc = (w >> 1) * QC;
    const int fr = lane & 15, q = lane >> 4, fq = q * 8;
    f32x4 acc[MR][NR] = {};
    if constexpr (KD % 32 == 0) {
        __shared__ __align__(16) unsigned short As[2][TM * 32];
        __shared__ __align__(16) unsigned short Bs[2][TN * 32];
        auto STAGE = [&](int buf, int k0) {
            const unsigned short* Asrc = A; int AC = KD, ac0 = k0;
            if constexpr (CATA) {
                if (k0 >= 256)      { Asrc = A4; AC = 256; ac0 = k0 - 256; }
                else if (k0 >= 128) { Asrc = A3; AC = 128; ac0 = k0 - 128; }
                else if (k0 >= 64)  { Asrc = A2; AC = 64;  ac0 = k0 - 64; }
                else                { Asrc = A;  AC = 64;  ac0 = k0; }
            }
            constexpr int AT = TM * 4;
            #pragma unroll
            for (int R = 0; R < (AT + 255) / 256; R++) {
                const int G = t + R * 256;
                if (AT >= (R + 1) * 256 || G < AT) {
                    const int m = G >> 2, gs = (G & 3) ^ ((m >> 1) & 3);
                    ldsld16(&Asrc[(size_t)(rb + m) * AC + ac0 + gs * 8], &As[buf][w * 512 + R * 2048]);
                }
            }
            constexpr int BT = TN * 4;
            #pragma unroll
            for (int R = 0; R < (BT + 255) / 256; R++) {
                const int G = t + R * 256;
                if (BT >= (R + 1) * 256 || G < BT) {
                    const int n = G >> 2, gs = (G & 3) ^ ((n >> 1) & 3);
                    ldsld16(&Bw[(size_t)(cb + n) * KD + k0 + gs * 8], &Bs[buf][w * 512 + R * 2048]);
                }
            }
        };
        constexpr int NT = KD / 32;
        STAGE(0, 0);
        asm volatile("s_waitcnt vmcnt(0)" ::: "memory");
        __builtin_amdgcn_s_barrier();
        int cur = 0;
        for (int ts = 0; ts < NT; ++ts) {
            if (ts + 1 < NT) STAGE(cur ^ 1, (ts + 1) * 32);
            short8 af[MR], bfr[NR];
            #pragma unroll
            for (int mi = 0; mi < MR; mi++) {
                const int r = wr + mi * 16 + fr;
                af[mi] = *reinterpret_cast<const short8*>(&As[cur][r * 32 + ((q ^ ((r >> 1) & 3)) << 3)]);
            }
            #pragma unroll
            for (int ni = 0; ni < NR; ni++) {
                const int r = wc + ni * 16 + fr;
                bfr[ni] = *reinterpret_cast<const short8*>(&Bs[cur][r * 32 + ((q ^ ((r >> 1) & 3)) << 3)]);
            }
            #pragma unroll
            for (int mi = 0; mi < MR; mi++) {
                #pragma unroll
                for (int ni = 0; ni < NR; ni++)
                    acc[mi][ni] = __builtin_amdgcn_mfma_f32_16x16x32_bf16(af[mi], bfr[ni], acc[mi][ni], 0, 0, 0);
            }
            asm volatile("s_waitcnt vmcnt(0)" ::: "memory");
            __builtin_amdgcn_s_barrier();
            cur ^= 1;
        }
    } else {
        // fallback (KD=3): reg-staged, padded LDS, scalar guarded loads
        __shared__ __align__(16) unsigned short As[TM * 40];
        __shared__ __align__(16) unsigned short Bs[TN * 40];
        for (int k0 = 0; k0 < KD; k0 += 32) {
            __syncthreads();
            #pragma unroll
            for (int u = t; u < TM * 4; u += 256) {
                const int m = u >> 2, c = (u & 3) * 8;
                #pragma unroll
                for (int j = 0; j < 8; j++) {
                    const int kk = k0 + c + j;
                    As[m * 40 + c + j] = (kk < KD) ? A[(size_t)(rb + m) * KD + kk] : (unsigned short)0;
                }
            }
            #pragma unroll
            for (int u = t; u < TN * 4; u += 256) {
                const int n = u >> 2, c = (u & 3) * 8;
                const int gn = cb + n;
                if (gn < NC) {
                    #pragma unroll
                    for (int j = 0; j < 8; j++) {
                        const int kk = k0 + c + j;
                        Bs[n * 40 + c + j] = (kk < KD) ? Bw[(size_t)gn * KD + kk] : (unsigned short)0;
                    }
                } else {
                    short8 z = {};
                    *reinterpret_cast<short8*>(&Bs[n * 40 + c]) = z;
                }
            }
            __syncthreads();
            short8 af[MR], bfr[NR];
            #pragma unroll
            for (int mi = 0; mi < MR; mi++)
                af[mi] = *reinterpret_cast<const short8*>(&As[(wr + mi * 16 + fr) * 40 + fq]);
            #pragma unroll
            for (int ni = 0; ni < NR; ni++)
                bfr[ni] = *reinterpret_cast<const short8*>(&Bs[(wc + ni * 16 + fr) * 40 + fq]);
            #pragma unroll
            for (int mi = 0; mi < MR; mi++) {
                #pragma unroll
                for (int ni = 0; ni < NR; ni++)
                    acc[mi][ni] = __builtin_amdgcn_mfma_f32_16x16x32_bf16(af[mi], bfr[ni], acc[mi][ni], 0, 0, 0);
            }
        }
    }
    const int cr = (lane >> 4) * 4, cc = lane & 15;
    if constexpr (POOL) {
        const int bidx = rb >> 10;
        #pragma unroll
        for (int ni = 0; ni < NR; ni++) {
            const int col = cb + wc + ni * 16 + cc;
            const float gm = gamma[col] * BN_SCALE, bt = beta[col];
            float sm = 0.f, mxv = -3e38f;
            #pragma unroll
            for (int mi = 0; mi < MR; mi++) {
                #pragma unroll
                for (int r = 0; r < 4; r++) {
                    float v = acc[mi][ni][r] * gm + bt;
                    v = v >= 0.f ? v : 0.2f * v;
                    sm += v; mxv = fmaxf(mxv, v);
                }
            }
            sm += __shfl_xor(sm, 16, 64);
            sm += __shfl_xor(sm, 32, 64);
            mxv = fmaxf(mxv, __shfl_xor(mxv, 16, 64));
            mxv = fmaxf(mxv, __shfl_xor(mxv, 32, 64));
            if (lane < 16) {
                atomicAdd(&psum[bidx * 1024 + col], sm);
                unsigned tb = __float_as_uint(mxv);
                tb = (tb & 0x80000000u) ? ~tb : (tb | 0x80000000u);
                atomicMax(&pmaxu[bidx * 1024 + col], tb);
            }
        }
    } else {
        float sx[MR][4] = {};
        #pragma unroll
        for (int mi = 0; mi < MR; mi++) {
            #pragma unroll
            for (int ni = 0; ni < NR; ni++) {
                #pragma unroll
                for (int r = 0; r < 4; r++) {
                    const int row = rb + wr + mi * 16 + cr + r;
                    const int col = cb + wc + ni * 16 + cc;
                    if (col < NC) {
                        float v = acc[mi][ni][r] + (bias ? bias[col] : 0.f);
                        if (col < scale_cols) v *= qs;
                        if (resid) v += resid[(size_t)row * NC + col];
                        if (gamma) {
                            v = v * (gamma[col] * BN_SCALE) + beta[col];
                            v = v >= 0.f ? v : 0.2f * v;
                        }
                        if (yco > 0) {
                            if (col < yco) Cout[(size_t)row * yco + col] = v;
                            else           Cz[(size_t)row * yco + (col - yco)] = v;
                        } else {
                            Cout[(size_t)row * NC + col] = v;
                        }
                        if (obf) obf[(size_t)row * NC + col] = F2BF(v);
                        if constexpr (SPLIT > 0) {
                            constexpr int KP2 = 3 * SPLIT;
                            const unsigned short h = F2BF(v);
                            const unsigned short l = F2BF(v - US2F(h));
                            sxa[(size_t)row * KP2 + 0 * SPLIT + col] = h;
                            sxa[(size_t)row * KP2 + 1 * SPLIT + col] = l;
                            sxa[(size_t)row * KP2 + 2 * SPLIT + col] = h;
                            sxb[(size_t)row * KP2 + 0 * SPLIT + col] = h;
                            sxb[(size_t)row * KP2 + 1 * SPLIT + col] = h;
                            sxb[(size_t)row * KP2 + 2 * SPLIT + col] = l;
                            sx[mi][r] += v * v;
                        }
                    }
                }
            }
        }
        if constexpr (SPLIT > 0) {
            #pragma unroll
            for (int mi = 0; mi < MR; mi++) {
                #pragma unroll
                for (int r = 0; r < 4; r++) {
                    float s = sx[mi][r];
                    s += __shfl_xor(s, 1, 64);
                    s += __shfl_xor(s, 2, 64);
                    s += __shfl_xor(s, 4, 64);
                    s += __shfl_xor(s, 8, 64);
                    if ((lane & 15) == 0)
                        atomicAdd(&xxo[rb + wr + mi * 16 + cr + r], s);
                }
            }
        }
    }
}

// AFF: remap blockIdx.x so row-block batch == XCD (linear id % 8).
template<int KD, int NC, int TM, int TN, bool CATA = false, bool POOL = false, int SPLIT = 0, bool AFF = false>
__global__ __launch_bounds__(256) void k_gemmb(const unsigned short* __restrict__ A,
                                               const unsigned short* __restrict__ A2,
                                               const unsigned short* __restrict__ A3,
                                               const unsigned short* __restrict__ A4,
                                               const unsigned short* __restrict__ Bw,
                                               const float* __restrict__ bias,
                                               const float* __restrict__ resid,
                                               float* __restrict__ Cout,
                                               int scale_cols, float qs,
                                               const float* __restrict__ gamma,
                                               const float* __restrict__ beta,
                                               unsigned short* __restrict__ obf,
                                               unsigned* __restrict__ pmaxu,
                                               float* __restrict__ psum,
                                               unsigned short* __restrict__ sxa,
                                               unsigned short* __restrict__ sxb,
                                               float* __restrict__ xxo) {
    int bx = blockIdx.x;
    if constexpr (AFF) bx = (bx & 7) * (gridDim.x >> 3) + (bx >> 3);
    gemm_dev<KD, NC, TM, TN, CATA, POOL, SPLIT>(bx, blockIdx.y,
        A, A2, A3, A4, Bw, bias, resid, Cout, nullptr, 0, scale_cols, qs, gamma, beta,
        obf, pmaxu, psum, sxa, sxb, xxo);
}

// ---------------------------------------------------------------- combined sel || yz-GEMM
template<int KD, int NC, int TM, int TN>
__global__ __launch_bounds__(256) void k_selyz(const float* __restrict__ pd,
                                               int* __restrict__ idx, int selb, int gx,
                                               const unsigned short* __restrict__ A,
                                               const unsigned short* __restrict__ Bw,
                                               float* __restrict__ Cy,
                                               float* __restrict__ Cz, int yco) {
    if ((int)blockIdx.x < selb) { sel_dev(pd, idx, blockIdx.x); return; }
    const int g = blockIdx.x - selb;          // selb = 2048 ≡ 0 mod 8 -> XCD = g&7
    const int batch = g & 7, rem = g >> 3;
    const int rpb = gx >> 3;                  // row-blocks per batch
    const int bx = batch * rpb + rem % rpb;
    const int by = rem / rpb;
    gemm_dev<KD, NC, TM, TN, false, false, 0>(bx, by,
        A, nullptr, nullptr, nullptr, Bw, nullptr, nullptr, Cy, Cz, yco, 0, 1.f,
        nullptr, nullptr, nullptr, nullptr, nullptr, nullptr, nullptr, nullptr);
}

// ---------------------------------------------------------------- EdgeConv epilogue (fp32 out + bf16 copy)
// y/z separate dense [BN][CO] arrays; batch = blockIdx.x & 7 (XCD-affine).
template<int CO>
__global__ __launch_bounds__(256) void k_edgemax(const float* __restrict__ y,
                                                 const float* __restrict__ z,
                                                 const int* __restrict__ idx,
                                                 const float* __restrict__ g,
                                                 const float* __restrict__ bb,
                                                 float* __restrict__ out,
                                                 unsigned short* __restrict__ outb) {
    constexpr int TPP = CO / 4;
    constexpr int PPB = 256 / TPP;
    const int t = threadIdx.x;
    const int p = t / TPP;
    const int cw = (t % TPP) * 4;
    const int batch = blockIdx.x & 7;
    const int within = blockIdx.x >> 3;
    const int i0 = batch * N_ + within * PPB;
    const int bbase = batch << 10;
    __shared__ int sidx[PPB][K_];
    for (int u = t; u < PPB * K_; u += 256) {
        int pp = u / K_, kk = u - pp * K_;
        sidx[pp][kk] = idx[(size_t)(i0 + pp) * K_ + kk];
    }
    __syncthreads();
    const int ig = i0 + p;
    float4 m = {-3e38f, -3e38f, -3e38f, -3e38f};
    #pragma unroll 4
    for (int k = 0; k < K_; k++) {
        const int jg = bbase + sidx[p][k];
        const float4 yv = *reinterpret_cast<const float4*>(&y[(size_t)jg * CO + cw]);
        m.x = fmaxf(m.x, yv.x); m.y = fmaxf(m.y, yv.y);
        m.z = fmaxf(m.z, yv.z); m.w = fmaxf(m.w, yv.w);
    }
    const float4 yi = *reinterpret_cast<const float4*>(&y[(size_t)ig * CO + cw]);
    const float4 zi = *reinterpret_cast<const float4*>(&z[(size_t)ig * CO + cw]);
    const float4 gv = *reinterpret_cast<const float4*>(&g[cw]);
    const float4 bv = *reinterpret_cast<const float4*>(&bb[cw]);
    float vals[4] = {m.x - yi.x + zi.x, m.y - yi.y + zi.y,
                     m.z - yi.z + zi.z, m.w - yi.w + zi.w};
    float gs[4] = {gv.x, gv.y, gv.z, gv.w};
    float bs[4] = {bv.x, bv.y, bv.z, bv.w};
    float4 o;
    float* op = &o.x;
    #pragma unroll
    for (int j = 0; j < 4; j++) {
        float h = vals[j] * (gs[j] * BN_SCALE) + bs[j];
        op[j] = h >= 0.f ? h : 0.2f * h;
    }
    *reinterpret_cast<float4*>(&out[(size_t)ig * CO + cw]) = o;
    #pragma unroll
    for (int j = 0; j < 4; j++) outb[(size_t)ig * CO + cw + j] = F2BF(op[j]);
}

// ---------------------------------------------------------------- attention (layer 4 only)
template<int E>
__global__ __launch_bounds__(256) void k_attn(const float* __restrict__ qkv,
                                              unsigned short* __restrict__ o) {
    constexpr int H = 4, D = E / H, L = 8;
    const int n = blockIdx.x;
    const int t = threadIdx.x;
    const int h = t >> 6, lane = t & 63;
    __shared__ float sq[L][3 * E];
    __shared__ float so[L][E];
    for (int u = t; u < L * 3 * E; u += 256) {
        int l = u / (3 * E), r = u - l * (3 * E);
        sq[l][r] = qkv[(size_t)(l * N_ + n) * (3 * E) + r];
    }
    __syncthreads();
    const int l = lane >> 3, m = lane & 7;
    float s = 0.f;
    #pragma unroll 8
    for (int dd = 0; dd < D; dd++)
        s += sq[l][h * D + dd] * sq[m][E + h * D + dd];
    float mx = s;
    #pragma unroll
    for (int st = 1; st < 8; st <<= 1) mx = fmaxf(mx, __shfl_xor(mx, st, 64));
    float e = expf(s - mx);
    float sum = e;
    #pragma unroll
    for (int st = 1; st < 8; st <<= 1) sum += __shfl_xor(sum, st, 64);
    const float p = e / sum;
    float pm[8];
    #pragma unroll
    for (int mm = 0; mm < 8; mm++) pm[mm] = __shfl(p, (lane & 56) | mm, 64);
    #pragma unroll
    for (int j = 0; j < D / 8; j++) {
        const int dd = m + 8 * j;
        float a = 0.f;
        #pragma unroll
        for (int mm = 0; mm < 8; mm++) a += pm[mm] * sq[mm][2 * E + h * D + dd];
        so[l][h * D + dd] = a;
    }
    __syncthreads();
    for (int u = t; u < L * E; u += 256) {
        int l2 = u / E, e2 = u - l2 * E;
        o[(size_t)(l2 * N_ + n) * E + e2] = F2BF(so[l2][e2]);
    }
}

// ---------------------------------------------------------------- fused attention + out-proj (layers 1-3)
// Block n holds the COMPLETE attn-output rows {l*N+n}: the out-projection is a
// per-block 8xE @ ExE dot.  so is bf16-rounded first (matches the old MFMA's
// bf16 A-operand); wo staged in LDS padded [E][E+8] (row stride 144/272 B
// breaks 32-bank alignment -> <=2-way).  Epilogue = bias + residual + x/x_ib
// + 3-seg kNN split + row norms (full rows in-block -> wave reduce + LDS).
template<int E, int SPLIT>
__global__ __launch_bounds__(256) void k_attnout(const float* __restrict__ qkv,
                                                 const unsigned short* __restrict__ wo,
                                                 const float* __restrict__ bo,
                                                 float* __restrict__ x,
                                                 unsigned short* __restrict__ xob,
                                                 unsigned short* __restrict__ sxa,
                                                 unsigned short* __restrict__ sxb,
                                                 float* __restrict__ xxo) {
    constexpr int H = 4, D = E / H, L = 8;
    const int n = blockIdx.x;
    const int t = threadIdx.x;
    const int h = t >> 6, lane = t & 63;
    __shared__ float sq[L][3 * E];
    __shared__ float so[L][E];
    __shared__ unsigned short swo[E][E + 8];
    __shared__ float sxx[L];
    for (int u = t; u < L * 3 * E; u += 256) {
        int l = u / (3 * E), r = u - l * (3 * E);
        sq[l][r] = qkv[(size_t)(l * N_ + n) * (3 * E) + r];
    }
    for (int u = t; u < E * E; u += 256) swo[u / E][u % E] = wo[u];
    if (t < L) sxx[t] = 0.f;
    __syncthreads();
    // attention (identical math to k_attn)
    const int l = lane >> 3, m = lane & 7;
    float s = 0.f;
    #pragma unroll 8
    for (int dd = 0; dd < D; dd++)
        s += sq[l][h * D + dd] * sq[m][E + h * D + dd];
    float mx = s;
    #pragma unroll
    for (int st = 1; st < 8; st <<= 1) mx = fmaxf(mx, __shfl_xor(mx, st, 64));
    float e = expf(s - mx);
    float sum = e;
    #pragma unroll
    for (int st = 1; st < 8; st <<= 1) sum += __shfl_xor(sum, st, 64);
    const float p = e / sum;
    float pm[8];
    #pragma unroll
    for (int mm = 0; mm < 8; mm++) pm[mm] = __shfl(p, (lane & 56) | mm, 64);
    #pragma unroll
    for (int j = 0; j < D / 8; j++) {
        const int dd = m + 8 * j;
        float a = 0.f;
        #pragma unroll
        for (int mm = 0; mm < 8; mm++) a += pm[mm] * sq[mm][2 * E + h * D + dd];
        so[l][h * D + dd] = a;
    }
    __syncthreads();
    // bf16-round so (the old path quantized attn output to owb before MFMA)
    for (int u = t; u < L * E; u += 256)
        so[u / E][u % E] = US2F(F2BF(so[u / E][u % E]));
    __syncthreads();
    // out-proj + residual + epilogue.  item = t + it*256: within any wave+it
    // the 64 items are 64 consecutive -> same row ll (E | 64*groups), so[ll][c]
    // is a broadcast read and swo rows are distinct lanes (padded, <=2-way).
    constexpr int PT = (L * E) / 256;
    #pragma unroll
    for (int it = 0; it < PT; it++) {
        const int item = t + it * 256;
        const int ll = item / E, ee = item % E;
        float acc = 0.f;
        #pragma unroll 16
        for (int c = 0; c < E; c++)
            acc += so[ll][c] * US2F(swo[ee][c]);
        const int row = ll * N_ + n;
        const float v = acc + bo[ee] + x[(size_t)row * E + ee];
        x[(size_t)row * E + ee] = v;
        xob[(size_t)row * E + ee] = F2BF(v);
        if constexpr (SPLIT > 0) {
            constexpr int KP2 = 3 * SPLIT;
            const unsigned short hh = F2BF(v);
            const unsigned short lo = F2BF(v - US2F(hh));
            sxa[(size_t)row * KP2 + 0 * SPLIT + ee] = hh;
            sxa[(size_t)row * KP2 + 1 * SPLIT + ee] = lo;
            sxa[(size_t)row * KP2 + 2 * SPLIT + ee] = hh;
            sxb[(size_t)row * KP2 + 0 * SPLIT + ee] = hh;
            sxb[(size_t)row * KP2 + 1 * SPLIT + ee] = hh;
            sxb[(size_t)row * KP2 + 2 * SPLIT + ee] = lo;
            float vs = v * v;
            #pragma unroll
            for (int st = 1; st < 64; st <<= 1) vs += __shfl_xor(vs, st, 64);
            if (lane == 0) atomicAdd(&sxx[ll], vs);
        }
    }
    if constexpr (SPLIT > 0) {
        __syncthreads();
        if (t < L) xxo[t * N_ + n] = sxx[t];
    }
}

// ---------------------------------------------------------------- FC head
__global__ __launch_bounds__(256) void k_fc1(const unsigned* __restrict__ pmaxu,
                                             const float* __restrict__ psum,
                                             const float* __restrict__ l1wT,
                                             const float* __restrict__ g6, const float* __restrict__ b6,
                                             float* __restrict__ f1) {
    int oc = blockIdx.x, b = blockIdx.y, t = threadIdx.x;
    __shared__ float fin[2048];
    __shared__ float ps[4][64];
    for (int u = t; u < 2048; u += 256) {
        float v;
        if (u < 1024) {
            unsigned tb = pmaxu[b * 1024 + u];
            unsigned bits = (tb & 0x80000000u) ? (tb & 0x7FFFFFFFu) : ~tb;
            v = __uint_as_float(bits);
        } else {
            v = psum[b * 1024 + (u - 1024)] * (1.f / 1024.f);
        }
        fin[u] = v;
    }
    __syncthreads();
    int ol = t & 63, kc = t >> 6;
    int o = oc * 64 + ol;
    float acc = 0.f;
    for (int c = kc * 512; c < kc * 512 + 512; c++) acc += fin[c] * l1wT[(size_t)c * 512 + o];
    ps[kc][ol] = acc;
    __syncthreads();
    if (t < 64) {
        int oo = oc * 64 + t;
        float a = ps[0][t] + ps[1][t] + ps[2][t] + ps[3][t];
        float h = a * (g6[oo] * BN_SCALE) + b6[oo];
        f1[b * 512 + oo] = h >= 0.f ? h : 0.2f * h;
    }
}

__global__ __launch_bounds__(256) void k_fc23(const float* __restrict__ f1, const float* __restrict__ l2wT,
                                              const float* __restrict__ l2b,
                                              const float* __restrict__ g7, const float* __restrict__ b7,
                                              const float* __restrict__ l3wT, const float* __restrict__ l3b,
                                              void* __restrict__ out, DetP dp) {
    int b = blockIdx.x, t = threadIdx.x;
    __shared__ float fin[512];
    __shared__ float f2s[256];
    __shared__ int sbf;
    if (t == 0) sbf = det_isbf(dp);
    for (int u = t; u < 512; u += 256) fin[u] = f1[b * 512 + u];
    __syncthreads();
    {
        float acc = 0.f;
        for (int c = 0; c < 512; c++) acc += fin[c] * l2wT[(size_t)c * 256 + t];
        acc += l2b[t];
        float h = acc * (g7[t] * BN_SCALE) + b7[t];
        f2s[t] = h >= 0.f ? h : 0.2f * h;
    }
    __syncthreads();
    if (t < 40) {
        float acc = 0.f;
        for (int c = 0; c < 256; c++) acc += f2s[c] * l3wT[(size_t)c * 40 + t];
        acc += l3b[t];
        if (sbf) ((__hip_bfloat16*)out)[b * 40 + t] = __float2bfloat16(acc);
        else     ((float*)out)[b * 40 + t] = acc;
    }
}

// ================================================================ host
extern "C" void kernel_launch(void* const* d_in, const int* in_sizes, int n_in,
                              void* d_out, int out_size, void* d_ws, size_t ws_size,
                              hipStream_t stream) {
    auto us = [&](int i) { return (const unsigned short*)d_in[i]; };

    float* ws = (float*)d_ws;
    size_t off = 0;
    auto A = [&](size_t n) { float* p = ws + off; off += (n + 3) & ~(size_t)3; return p; };
    auto AU = [&](size_t n) { return (unsigned short*)A((n + 1) / 2); };
    float* x1   = A((size_t)BN_ * 64);
    float* x2   = A((size_t)BN_ * 64);
    float* x3   = A((size_t)BN_ * 128);
    float* x4   = A((size_t)BN_ * 256);
    float* pd   = A((size_t)BN_ * 1024);   // pd scratch
    float* f1   = A(8 * 512);
    float* xx   = A(4 * BN_);              // per-layer row norms
    int*   idx  = (int*)A((size_t)BN_ * K_);
    float* qkvw = A((size_t)BN_ * 768);    // qkv / y,z scratch
    // DEDICATED kNN split buffers (no longer aliasing qkvw: k_attnout reads
    // qkvw while writing the split -> must not overlap).  Max KP=384.
    unsigned short* xa = AU((size_t)BN_ * 384);
    unsigned short* xb = AU((size_t)BN_ * 384);
    // bf16 activation copies
    unsigned short* xf0b = AU((size_t)BN_ * 3);
    unsigned short* x1b  = AU((size_t)BN_ * 64);
    unsigned short* x2b  = AU((size_t)BN_ * 64);
    unsigned short* x3b  = AU((size_t)BN_ * 128);
    unsigned short* x4b  = AU((size_t)BN_ * 256);
    unsigned short* owb  = AU((size_t)BN_ * 256);   // layer-4 attn output
    // pooled reductions (conv5 fused epilogue) -- contiguous, zeroed by k_prep
    unsigned* pmaxu = (unsigned*)A(8 * 1024);
    float*    psum  = A(8 * 1024);
    // bf16 weights (n,k) layouts
    unsigned short* w1yzb = AU(128 * 3);
    unsigned short* w2yzb = AU(128 * 64);
    unsigned short* w3yzb = AU(256 * 64);
    unsigned short* w4yzb = AU(512 * 128);
    unsigned short* a1wib = AU(192 * 64);  unsigned short* a1wob = AU(64 * 64);
    unsigned short* a2wib = AU(192 * 64);  unsigned short* a2wob = AU(64 * 64);
    unsigned short* a3wib = AU(384 * 128); unsigned short* a3wob = AU(128 * 128);
    unsigned short* a4wib = AU(768 * 256); unsigned short* a4wob = AU(256 * 256);
    unsigned short* w5b   = AU(1024 * 512);
    // fp32 fc weights (transposed)
    float* l1wT  = A(2048 * 512);
    float* l2wT  = A(512 * 256);
    float* l3wT  = A(256 * 40);
    // converted vectors (fp32)
    float* g1f = A(64);   float* b1f = A(64);
    float* g2f = A(64);   float* b2f = A(64);
    float* g3f = A(128);  float* b3f = A(128);
    float* g4f = A(256);  float* b4f = A(256);
    float* bi1 = A(192);  float* bo1 = A(64);
    float* bi2 = A(192);  float* bo2 = A(64);
    float* bi3 = A(384);  float* bo3 = A(128);
    float* bi4 = A(768);  float* bo4 = A(256);
    float* g5f = A(1024); float* b5f = A(1024);
    float* g6f = A(512);  float* b6f = A(512);
    float* l2bf = A(256);
    float* g7f = A(256);  float* b7f = A(256);
    float* l3bf = A(40);

    float* xx1 = xx;              float* xx2 = xx + BN_;
    float* xx3 = xx + 2 * BN_;    float* xx4 = xx + 3 * BN_;

    // y/z edge-feature arrays alias qkvw (qkv gemm later overwrites)
    float* yy = qkvw;
    float* zz = qkvw + (size_t)BN_ * 256;

    DetP dp{{us(2), us(5), us(8), us(11), us(30), us(33), us(37)}};

    TList tl; int nb = 0; int k = 0;
    auto add = [&](int i, void* dst, int O, int I, int mode) {
        tl.p[k].src = d_in[i]; tl.p[k].dst = dst; tl.p[k].O = O; tl.p[k].I = I;
        tl.p[k].blk0 = nb; tl.p[k].mode = mode;
        nb += (O * I + 255) / 256; k++;
    };
    add(0,  xf0b,  BN_ * 3, 1, 2);
    add(0,  pmaxu, 16384, 1, 4);      // zero pmaxu+psum (contiguous)
    add(1,  w1yzb, 64, 6, 3);
    add(4,  w2yzb, 64, 128, 3);
    add(7,  w3yzb, 128, 128, 3);
    add(10, w4yzb, 256, 256, 3);
    add(13, a1wib, 192, 64, 2);
    add(15, a1wob, 64, 64, 2);
    add(17, a2wib, 192, 64, 2);
    add(19, a2wob, 64, 64, 2);
    add(21, a3wib, 384, 128, 2);
    add(23, a3wob, 128, 128, 2);
    add(25, a4wib, 768, 256, 2);
    add(27, a4wob, 256, 256, 2);
    add(29, w5b,   1024, 512, 2);
    add(2,  g1f, 64, 1, 0);   add(3,  b1f, 64, 1, 0);
    add(5,  g2f, 64, 1, 0);   add(6,  b2f, 64, 1, 0);
    add(8,  g3f, 128, 1, 0);  add(9,  b3f, 128, 1, 0);
    add(11, g4f, 256, 1, 0);  add(12, b4f, 256, 1, 0);
    add(14, bi1, 192, 1, 0);  add(16, bo1, 64, 1, 0);
    add(18, bi2, 192, 1, 0);  add(20, bo2, 64, 1, 0);
    add(22, bi3, 384, 1, 0);  add(24, bo3, 128, 1, 0);
    add(26, bi4, 768, 1, 0);  add(28, bo4, 256, 1, 0);
    add(30, g5f, 1024, 1, 0); add(31, b5f, 1024, 1, 0);
    add(33, g6f, 512, 1, 0);  add(34, b6f, 512, 1, 0);
    add(36, l2bf, 256, 1, 0);
    add(37, g7f, 256, 1, 0);  add(38, b7f, 256, 1, 0);
    add(40, l3bf, 40, 1, 0);

    // FC-weight transposes + layer-1 split/norms fused into k_prep tail blocks
    TrP tp1{d_in[32], l1wT, 512, 2048, 2048 / 32, 0};
    TrP tp2{d_in[35], l2wT, 256, 512,  512 / 32,  (2048 / 32) * (512 / 32)};
    TrP tp3{d_in[39], l3wT, 40,  256,  256 / 32,  tp2.blk0 + (512 / 32) * (256 / 32)};
    const int trblocks = tp3.blk0 + (256 / 32) * ((40 + 31) / 32);
    const int splblocks = (BN_ * 32) / 256 + 32;   // split + norms
    k_prep<<<nb + trblocks + splblocks, 256, 0, stream>>>(
        tl, k, tp1, tp2, tp3, nb, trblocks, d_in[0], dp, xa, xb, xx1);

    const unsigned short* N0 = nullptr;
    unsigned short* U0 = nullptr;
    unsigned* NU = nullptr; float* NF = nullptr;

    // layer 1  (C=3 -> 64)
    k_pdm<32, 128, 128><<<512, 256, 0, stream>>>(xa, xb, xx1, pd);
    k_selyz<3, 128, 64, 64><<<2048 + 256, 256, 0, stream>>>(pd, idx, 2048, 128, xf0b, w1yzb, yy, zz, 64);
    k_edgemax<64><<<BN_ / 16, 256, 0, stream>>>(yy, zz, idx, g1f, b1f, x1, x1b);
    k_gemmb<64, 192, 64, 64, false, false, 0, true><<<dim3(128, 3), 256, 0, stream>>>(x1b, N0, N0, N0, a1wib, bi1, nullptr, qkvw, 64, 0.25f, nullptr, nullptr, nullptr, NU, NF, U0, U0, NF);
    k_attnout<64, 64><<<N_, 256, 0, stream>>>(qkvw, a1wob, bo1, x1, x1b, xa, xb, xx2);

    // layer 2  (C=64 -> 64, KP=192)
    k_pdm<192, 128, 128><<<512, 256, 0, stream>>>(xa, xb, xx2, pd);
    k_selyz<64, 128, 64, 64><<<2048 + 256, 256, 0, stream>>>(pd, idx, 2048, 128, x1b, w2yzb, yy, zz, 64);
    k_edgemax<64><<<BN_ / 16, 256, 0, stream>>>(yy, zz, idx, g2f, b2f, x2, x2b);
    k_gemmb<64, 192, 64, 64, false, false, 0, true><<<dim3(128, 3), 256, 0, stream>>>(x2b, N0, N0, N0, a2wib, bi2, nullptr, qkvw, 64, 0.25f, nullptr, nullptr, nullptr, NU, NF, U0, U0, NF);
    k_attnout<64, 64><<<N_, 256, 0, stream>>>(qkvw, a2wob, bo2, x2, x2b, xa, xb, xx3);

    // layer 3  (C=64 -> 128, KP=192)
    k_pdm<192, 128, 128><<<512, 256, 0, stream>>>(xa, xb, xx3, pd);
    k_selyz<64, 256, 64, 64><<<2048 + 512, 256, 0, stream>>>(pd, idx, 2048, 128, x2b, w3yzb, yy, zz, 128);
    k_edgemax<128><<<BN_ / 8, 256, 0, stream>>>(yy, zz, idx, g3f, b3f, x3, x3b);
    k_gemmb<128, 384, 64, 128, false, false, 0, true><<<dim3(128, 3), 256, 0, stream>>>(x3b, N0, N0, N0, a3wib, bi3, nullptr, qkvw, 128, 0.17677669529663687f, nullptr, nullptr, nullptr, NU, NF, U0, U0, NF);
    k_attnout<128, 128><<<N_, 256, 0, stream>>>(qkvw, a3wob, bo3, x3, x3b, xa, xb, xx4);

    // layer 4  (C=128 -> 256, KP=384; E=256 keeps the MFMA out-proj path)
    k_pdm<384, 128, 128><<<512, 256, 0, stream>>>(xa, xb, xx4, pd);
    k_selyz<128, 512, 128, 128><<<2048 + 256, 256, 0, stream>>>(pd, idx, 2048, 64, x3b, w4yzb, yy, zz, 256);
    k_edgemax<256><<<BN_ / 4, 256, 0, stream>>>(yy, zz, idx, g4f, b4f, x4, x4b);
    k_gemmb<256, 768, 64, 128, false, false, 0, true><<<dim3(128, 6), 256, 0, stream>>>(x4b, N0, N0, N0, a4wib, bi4, nullptr, qkvw, 256, 0.125f, nullptr, nullptr, nullptr, NU, NF, U0, U0, NF);
    k_attn<256><<<N_, 256, 0, stream>>>(qkvw, owb);
    k_gemmb<256, 256, 64, 128, false, false, 0, true><<<dim3(128, 2), 256, 0, stream>>>(owb, N0, N0, N0, a4wob, bo4, x4, x4, 0, 1.f, nullptr, nullptr, x4b, NU, NF, U0, U0, NF);

    // head: conv5 with fused concat-A and fused pooling epilogue (batch-affine)
    k_gemmb<512, 1024, 128, 128, true, true, 0, true><<<dim3(64, 8), 256, 0, stream>>>(
        x1b, x2b, x3b, x4b, w5b, nullptr, nullptr, nullptr, 0, 1.f, g5f, b5f, nullptr, pmaxu, psum, U0, U0, NF);
    k_fc1<<<dim3(8, 8), 256, 0, stream>>>(pmaxu, psum, l1wT, g6f, b6f, f1);
    k_fc23<<<8, 256, 0, stream>>>(f1, l2wT, l2bf, g7f, b7f, l3wT, l3bf, d_out, dp);
}